// Round 1
// baseline (3800.034 us; speedup 1.0000x reference)
//
#include <hip/hip_runtime.h>
#include <math.h>

// FNO3d forward. B=8,T=10,H=128,W=128, C=64, NL=4, modes: kt 8, kh 16, kw 8.
// All fp32. Partial DFTs instead of full FFTs.

#define NB 8
#define NT 10
#define NH 128
#define NW 128
#define NC 64
#define KT 8
#define KH 16
#define KWM 8
#define TWO_PI 6.2831853071795864769f
#define ORTHO_SC 2.4705294220065465e-3f  // 1/sqrt(10*128*128)

// ---------------- lift ----------------
__global__ __launch_bounds__(128) void k_lift(const float* __restrict__ frames,
                                              const float* __restrict__ times,
                                              const float* __restrict__ lift_w,
                                              const float* __restrict__ lift_b,
                                              float* __restrict__ x) {
  int row = blockIdx.x;           // b*T*H + t*H + h
  int h = row & 127;
  int bt = row >> 7;
  int t = bt % NT, b = bt / NT;
  int w = threadIdx.x;
  float f = frames[((size_t)(b*NT + t)*NH + h)*NW + w];
  float tv = times[b*NT + t];
  #pragma unroll 4
  for (int c = 0; c < NC; ++c) {
    float val = f*lift_w[2*c] + tv*lift_w[2*c+1] + lift_b[c];
    x[(((size_t)(b*NC + c)*NT + t)*NH + h)*NW + w] = val;
  }
}

// ---------------- prep: transpose skip_w and agg_w ----------------
__global__ __launch_bounds__(256) void k_prep(const float* __restrict__ skip_w,
                                              const float* __restrict__ agg_w,
                                              float* __restrict__ sw_t,   // [4][64 i][64 o]
                                              float* __restrict__ aw_t) { // [640 k][64 o]
  int tid = blockIdx.x*256 + threadIdx.x;
  if (tid < 4*64*64) {
    int l = tid >> 12, r = tid & 4095, o = r >> 6, i = r & 63;
    sw_t[((size_t)l*64 + i)*64 + o] = skip_w[tid];
  }
  if (tid < 64*640) {
    int o = tid / 640, k = tid % 640;
    aw_t[(size_t)k*64 + o] = agg_w[tid];
  }
}

// ---------------- forward W-stage: x(.,128w) -> 8 complex modes ----------------
// thread per row (b,c,t,h); 655360 rows.
__global__ __launch_bounds__(256) void k_fwdW(const float* __restrict__ x,
                                              float2* __restrict__ xw) {
  size_t row = (size_t)blockIdx.x*256 + threadIdx.x;
  const float* src = x + row*128;
  float ar[8], ai[8];
  #pragma unroll
  for (int k = 0; k < 8; ++k) { ar[k] = 0.f; ai[k] = 0.f; }
  const float cb = 0.9987954562051724f;     // cos(2pi/128)
  const float sbn = -0.04906767432741801f;  // -sin(2pi/128)
  float pr = 1.f, pi = 0.f;  // e^{-2pi i w/128}
  for (int w4 = 0; w4 < 32; ++w4) {
    float4 xv = ((const float4*)src)[w4];
    auto body = [&](float xu) {
      ar[0] += xu;
      float qr = pr, qi = pi;
      #pragma unroll
      for (int k = 1; k < 8; ++k) {
        ar[k] += xu*qr; ai[k] += xu*qi;
        float nr = qr*pr - qi*pi; qi = qr*pi + qi*pr; qr = nr;
      }
      float npr = pr*cb - pi*sbn; pi = pr*sbn + pi*cb; pr = npr;
    };
    body(xv.x); body(xv.y); body(xv.z); body(xv.w);
  }
  float4* dst = (float4*)(xw + row*8);
  #pragma unroll
  for (int q = 0; q < 4; ++q)
    dst[q] = make_float4(ar[2*q], ai[2*q], ar[2*q+1], ai[2*q+1]);
}

// ---------------- forward H-stage: 128h -> 16 modes ----------------
// block per (b,c,t); 128 threads (khi*8+kwi)
__global__ __launch_bounds__(128) void k_fwdH(const float2* __restrict__ xw,
                                              float2* __restrict__ xh) {
  __shared__ float2 tile[1024];  // [h][kw]
  int bct = blockIdx.x;
  const float2* src = xw + (size_t)bct*1024;
  for (int i = threadIdx.x; i < 1024; i += 128) tile[i] = src[i];
  __syncthreads();
  int j = threadIdx.x;
  int khi = j >> 3, kwi = j & 7;
  int kh = (khi < 8) ? khi : (112 + khi);   // 8..15 -> 120..127
  float th = -TWO_PI * (float)kh / 128.0f;
  float c, s; sincosf(th, &s, &c);
  float tr = 1.f, ti = 0.f, accr = 0.f, acci = 0.f;
  for (int h = 0; h < 128; ++h) {
    float2 v = tile[h*8 + kwi];
    accr += v.x*tr - v.y*ti;
    acci += v.x*ti + v.y*tr;
    float nr = tr*c - ti*s; ti = tr*s + ti*c; tr = nr;
  }
  xh[(size_t)bct*128 + j] = make_float2(accr, acci);
}

// ---------------- forward T-stage: 10t -> 8 modes (scaled) ----------------
// o = ((b*64+c)*8 + kti)*128 + kmode  (coalesced reads)
__global__ __launch_bounds__(256) void k_fwdT(const float2* __restrict__ xh,
                                              float2* __restrict__ xf) {
  int o = blockIdx.x*256 + threadIdx.x;
  int kmode = o & 127;
  int kti = (o >> 7) & 7;
  int c = (o >> 10) & 63;
  int b = o >> 16;
  int kt = (kti < 4) ? kti : (kti + 2);
  const float2* src = xh + (size_t)(b*64 + c)*1280 + kmode;
  float th = -TWO_PI * (float)kt / 10.0f;
  float cc, ss; sincosf(th, &ss, &cc);
  float tr = 1.f, ti = 0.f, accr = 0.f, acci = 0.f;
  #pragma unroll
  for (int t = 0; t < 10; ++t) {
    float2 v = src[t*128];
    accr += v.x*tr - v.y*ti;
    acci += v.x*ti + v.y*tr;
    float nr = tr*cc - ti*ss; ti = tr*ss + ti*cc; tr = nr;
  }
  // layout xf[b][m][ci], m = kti*128 + kmode
  xf[((size_t)b*1024 + kti*128 + kmode)*64 + c] = make_float2(accr*ORTHO_SC, acci*ORTHO_SC);
}

// ---------------- channel mix in mode space ----------------
// block per 8 modes; 256 threads = 8 mi x 32 co(x2 passes)
__global__ __launch_bounds__(256) void k_mix(const float2* __restrict__ xf,
                                             const float* __restrict__ spec_w_l,
                                             float2* __restrict__ yf) {
  __shared__ float2 xfs[8][8][65];  // [b][mi][ci] padded
  int m0 = blockIdx.x * 8;
  for (int i = threadIdx.x; i < 4096; i += 256) {
    int bb = i >> 9, mi = (i >> 6) & 7, ci = i & 63;
    xfs[bb][mi][ci] = xf[((size_t)bb*1024 + m0 + mi)*64 + ci];
  }
  __syncthreads();
  int mi = threadIdx.x & 7;
  int co_half = threadIdx.x >> 3;
  int m = m0 + mi;
  int kti = m >> 7, khi = (m >> 3) & 15, kwi = m & 7;
  int q = ((kti >= 4) ? 2 : 0) + ((khi >= 8) ? 1 : 0);
  int modeidx = ((kti & 3)*8 + (khi & 7))*8 + kwi;
  const float2* wq = (const float2*)spec_w_l + (size_t)q*64*64*256 + modeidx;
  #pragma unroll
  for (int p = 0; p < 2; ++p) {
    int co = co_half + 32*p;
    float accr[8], acci[8];
    #pragma unroll
    for (int bb = 0; bb < 8; ++bb) { accr[bb] = 0.f; acci[bb] = 0.f; }
    for (int ci = 0; ci < 64; ++ci) {
      float2 wv = wq[((size_t)ci*64 + co)*256];
      #pragma unroll
      for (int bb = 0; bb < 8; ++bb) {
        float2 xv = xfs[bb][mi][ci];
        accr[bb] += xv.x*wv.x - xv.y*wv.y;
        acci[bb] += xv.x*wv.y + xv.y*wv.x;
      }
    }
    #pragma unroll
    for (int bb = 0; bb < 8; ++bb)
      yf[((size_t)bb*64 + co)*1024 + m] = make_float2(accr[bb], acci[bb]);
  }
}

// ---------------- inverse T-stage (scaled) ----------------
// o = ((b*64+c)*10 + t)*128 + kmode
__global__ __launch_bounds__(256) void k_invT(const float2* __restrict__ yf,
                                              float2* __restrict__ zt) {
  int o = blockIdx.x*256 + threadIdx.x;
  int kmode = o & 127;
  int t = (o >> 7) % 10;
  int bc = o / 1280;
  const float2* src = yf + (size_t)bc*1024 + kmode;
  float th = TWO_PI * (float)t / 10.0f;
  float cc, ss; sincosf(th, &ss, &cc);
  float tr = 1.f, ti = 0.f, accr = 0.f, acci = 0.f;
  #pragma unroll
  for (int k = 0; k < 10; ++k) {
    if (k < 4 || k >= 6) {
      int kti = (k < 4) ? k : (k - 2);
      float2 v = src[kti*128];
      accr += v.x*tr - v.y*ti;
      acci += v.x*ti + v.y*tr;
    }
    float nr = tr*cc - ti*ss; ti = tr*ss + ti*cc; tr = nr;
  }
  zt[o] = make_float2(accr*ORTHO_SC, acci*ORTHO_SC);
}

// ---------------- inverse H-stage ----------------
// block per (b,c,t); output zh layout [b][t][h][c][kw]
__global__ __launch_bounds__(256) void k_invH(const float2* __restrict__ zt,
                                              float2* __restrict__ zh) {
  __shared__ float2 zs[128];  // [khi][kwi]
  int bct = blockIdx.x;
  int t = bct % 10;
  int c = (bct / 10) & 63;
  int b = bct / 640;
  if (threadIdx.x < 128) zs[threadIdx.x] = zt[(size_t)bct*128 + threadIdx.x];
  __syncthreads();
  int h = threadIdx.x & 127;
  int half = threadIdx.x >> 7;
  float th = TWO_PI * (float)h / 128.0f;
  float cc, ss; sincosf(th, &ss, &cc);
  float pwr[9], pwi[9];
  pwr[0] = 1.f; pwi[0] = 0.f;
  #pragma unroll
  for (int k = 1; k < 9; ++k) {
    pwr[k] = pwr[k-1]*cc - pwi[k-1]*ss;
    pwi[k] = pwr[k-1]*ss + pwi[k-1]*cc;
  }
  float ar[4] = {0,0,0,0}, ai[4] = {0,0,0,0};
  #pragma unroll
  for (int khi = 0; khi < 16; ++khi) {
    float tr = (khi < 8) ? pwr[khi] : pwr[16-khi];
    float ti = (khi < 8) ? pwi[khi] : -pwi[16-khi];
    #pragma unroll
    for (int kk = 0; kk < 4; ++kk) {
      float2 v = zs[khi*8 + half*4 + kk];
      ar[kk] += v.x*tr - v.y*ti;
      ai[kk] += v.x*ti + v.y*tr;
    }
  }
  float2* dst = zh + ((((size_t)(b*10 + t)*128 + h)*64 + c)*8 + half*4);
  #pragma unroll
  for (int kk = 0; kk < 4; ++kk) dst[kk] = make_float2(ar[kk], ai[kk]);
}

// ---------------- inverse W + skip + bias + GELU (in-place on x) ----------------
// block per (b,t,h); 128 threads; tile 8co x 8w per thread
__global__ __launch_bounds__(128) void k_invW_skip(const float2* __restrict__ zh,
                                                   const float* __restrict__ sw_t,  // [ci][co]
                                                   const float* __restrict__ skb,
                                                   float* __restrict__ x) {
  __shared__ float xs[64][128];
  __shared__ float2 zsh[64][9];
  __shared__ float swl[64][64];
  int bid = blockIdx.x;
  int h = bid & 127;
  int bt = bid >> 7;
  int t = bt % 10, b = bt / 10;
  // stage x rows (all input channels at this (b,t,h))
  for (int i = threadIdx.x; i < 2048; i += 128) {
    int ci = i >> 5, w4 = i & 31;
    const float* rowp = x + (((size_t)(b*64 + ci)*10 + t)*16384) + (size_t)h*128;
    ((float4*)&xs[ci][0])[w4] = ((const float4*)rowp)[w4];
  }
  {
    const float2* zsrc = zh + (size_t)bid*512;
    for (int i = threadIdx.x; i < 512; i += 128)
      zsh[i >> 3][i & 7] = zsrc[i];
  }
  for (int i = threadIdx.x; i < 1024; i += 128)
    ((float4*)swl)[i] = ((const float4*)sw_t)[i];
  __syncthreads();

  int wq = threadIdx.x & 15, cg = threadIdx.x >> 4;
  int w0 = wq*8, co0 = cg*8;

  float acc[8][8];
  // Phase A: inverse rfft over w from 8 modes
  {
    float cks[8][7], sks[8][7];
    #pragma unroll
    for (int u = 0; u < 8; ++u) {
      float th = TWO_PI * (float)(w0 + u) / 128.0f;
      float c, s; sincosf(th, &s, &c);
      float tr = c, ti = s;
      #pragma unroll
      for (int k = 0; k < 7; ++k) {
        cks[u][k] = tr; sks[u][k] = ti;
        float nr = tr*c - ti*s; ti = tr*s + ti*c; tr = nr;
      }
    }
    #pragma unroll
    for (int j = 0; j < 8; ++j) {
      float2 z[8];
      #pragma unroll
      for (int k = 0; k < 8; ++k) z[k] = zsh[co0 + j][k];
      #pragma unroll
      for (int u = 0; u < 8; ++u) {
        float sx = z[0].x;
        #pragma unroll
        for (int k = 1; k < 8; ++k)
          sx += 2.f*(z[k].x*cks[u][k-1] - z[k].y*sks[u][k-1]);
        acc[j][u] = sx;
      }
    }
  }
  // Phase B: skip matmul
  for (int ci = 0; ci < 64; ++ci) {
    float4 xv0 = *(const float4*)&xs[ci][w0];
    float4 xv1 = *(const float4*)&xs[ci][w0 + 4];
    float4 wv0 = *(const float4*)&swl[ci][co0];
    float4 wv1 = *(const float4*)&swl[ci][co0 + 4];
    float xv[8] = {xv0.x, xv0.y, xv0.z, xv0.w, xv1.x, xv1.y, xv1.z, xv1.w};
    float wv[8] = {wv0.x, wv0.y, wv0.z, wv0.w, wv1.x, wv1.y, wv1.z, wv1.w};
    #pragma unroll
    for (int j = 0; j < 8; ++j)
      #pragma unroll
      for (int u = 0; u < 8; ++u)
        acc[j][u] += wv[j]*xv[u];
  }
  // Phase C: bias + GELU(exact) + store in place
  #pragma unroll
  for (int j = 0; j < 8; ++j) {
    float bias = skb[co0 + j];
    float res[8];
    #pragma unroll
    for (int u = 0; u < 8; ++u) {
      float val = acc[j][u] + bias;
      res[u] = 0.5f*val*(1.0f + erff(val*0.70710678118654752f));
    }
    float* dst = x + (((size_t)(b*64 + co0 + j)*10 + t)*16384) + (size_t)h*128 + w0;
    *(float4*)dst = make_float4(res[0], res[1], res[2], res[3]);
    *(float4*)(dst + 4) = make_float4(res[4], res[5], res[6], res[7]);
  }
}

// ---------------- aggregation over (ci,t): K=640 GEMM ----------------
// block per (b,h); 128 threads; tile 8co x 8w
__global__ __launch_bounds__(128) void k_agg(const float* __restrict__ x,
                                             const float* __restrict__ aw_t,  // [k][o]
                                             const float* __restrict__ agg_b,
                                             float* __restrict__ xa) {
  __shared__ float xs[64][128];
  __shared__ float ws[64][64];
  int bid = blockIdx.x;
  int h = bid & 127;
  int b = bid >> 7;
  int wq = threadIdx.x & 15, cg = threadIdx.x >> 4;
  int w0 = wq*8, co0 = cg*8;
  float acc[8][8];
  #pragma unroll
  for (int j = 0; j < 8; ++j)
    #pragma unroll
    for (int u = 0; u < 8; ++u) acc[j][u] = 0.f;
  for (int chunk = 0; chunk < 10; ++chunk) {
    __syncthreads();
    for (int i = threadIdx.x; i < 2048; i += 128) {
      int j = i >> 5, w4 = i & 31;
      int k = chunk*64 + j;
      int ci = k / 10, t = k % 10;
      const float* rowp = x + (((size_t)(b*64 + ci)*10 + t)*16384) + (size_t)h*128;
      ((float4*)&xs[j][0])[w4] = ((const float4*)rowp)[w4];
    }
    for (int i = threadIdx.x; i < 1024; i += 128)
      ((float4*)ws)[i] = ((const float4*)(aw_t + (size_t)chunk*4096))[i];
    __syncthreads();
    #pragma unroll 4
    for (int j = 0; j < 64; ++j) {
      float4 xv0 = *(const float4*)&xs[j][w0];
      float4 xv1 = *(const float4*)&xs[j][w0 + 4];
      float4 wv0 = *(const float4*)&ws[j][co0];
      float4 wv1 = *(const float4*)&ws[j][co0 + 4];
      float xv[8] = {xv0.x, xv0.y, xv0.z, xv0.w, xv1.x, xv1.y, xv1.z, xv1.w};
      float wv[8] = {wv0.x, wv0.y, wv0.z, wv0.w, wv1.x, wv1.y, wv1.z, wv1.w};
      #pragma unroll
      for (int jj = 0; jj < 8; ++jj)
        #pragma unroll
        for (int u = 0; u < 8; ++u)
          acc[jj][u] += wv[jj]*xv[u];
    }
  }
  #pragma unroll
  for (int j = 0; j < 8; ++j) {
    float bias = agg_b[co0 + j];
    float* dst = xa + ((size_t)(b*64 + co0 + j)*128 + h)*128 + w0;
    *(float4*)dst = make_float4(acc[j][0]+bias, acc[j][1]+bias, acc[j][2]+bias, acc[j][3]+bias);
    *(float4*)(dst+4) = make_float4(acc[j][4]+bias, acc[j][5]+bias, acc[j][6]+bias, acc[j][7]+bias);
  }
}

// ---------------- MLP head ----------------
// block per (b,h); thread per w
__global__ __launch_bounds__(128) void k_head(const float* __restrict__ xa,
                                              const float* __restrict__ fc1_w,
                                              const float* __restrict__ fc1_b,
                                              const float* __restrict__ fc2_w,
                                              const float* __restrict__ fc2_b,
                                              float* __restrict__ out) {
  int bid = blockIdx.x;
  int h = bid & 127, b = bid >> 7;
  int w = threadIdx.x;
  float v[64];
  #pragma unroll
  for (int c = 0; c < 64; ++c)
    v[c] = xa[((size_t)(b*64 + c)*128 + h)*128 + w];
  float gx = -1.f + 2.f*(float)w/127.f;
  float gy = -1.f + 2.f*(float)h/127.f;
  float o2[10];
  #pragma unroll
  for (int j = 0; j < 10; ++j) o2[j] = fc2_b[j];
  for (int o = 0; o < 128; ++o) {
    float a = fc1_b[o];
    #pragma unroll
    for (int i = 0; i < 64; ++i) a += v[i]*fc1_w[i*128 + o];
    a += gx*fc1_w[64*128 + o] + gy*fc1_w[65*128 + o];
    float g = 0.5f*a*(1.0f + erff(a*0.70710678118654752f));
    #pragma unroll
    for (int j = 0; j < 10; ++j) o2[j] += g*fc2_w[o*10 + j];
  }
  float* dst = out + ((size_t)bid*128 + w)*10;
  #pragma unroll
  for (int k = 0; k < 5; ++k) dst[k] = o2[2*k];
  #pragma unroll
  for (int k = 0; k < 5; ++k) {
    float sv = o2[2*k+1];
    float sp = fmaxf(sv, 0.f) + log1pf(expf(-fabsf(sv)));
    dst[5 + k] = sp + 1e-4f;
  }
}

extern "C" void kernel_launch(void* const* d_in, const int* in_sizes, int n_in,
                              void* d_out, int out_size, void* d_ws, size_t ws_size,
                              hipStream_t stream) {
  const float* frames = (const float*)d_in[0];
  const float* times  = (const float*)d_in[1];
  const float* lift_w = (const float*)d_in[2];
  const float* lift_b = (const float*)d_in[3];
  const float* spec_w = (const float*)d_in[4];
  const float* skip_w = (const float*)d_in[5];
  const float* skip_b = (const float*)d_in[6];
  const float* agg_w  = (const float*)d_in[7];
  const float* agg_b  = (const float*)d_in[8];
  const float* fc1_w  = (const float*)d_in[9];
  const float* fc1_b  = (const float*)d_in[10];
  const float* fc2_w  = (const float*)d_in[11];
  const float* fc2_b  = (const float*)d_in[12];
  float* out = (float*)d_out;
  char* ws = (char*)d_ws;

  // workspace layout (bytes)
  size_t off = 0;
  float*  x   = (float*)(ws + off);  off += (size_t)8*64*10*128*128*4;      // 335,544,320
  float2* xw  = (float2*)(ws + off); off += (size_t)8*64*10*128*8*8;        // 41,943,040
  float2* xh  = (float2*)(ws + off); off += (size_t)8*64*10*16*8*8;         // 5,242,880
  float2* xf  = (float2*)(ws + off); off += (size_t)8*1024*64*8;            // 4,194,304
  float2* yf  = (float2*)(ws + off); off += (size_t)8*1024*64*8;            // 4,194,304
  float*  xa  = (float*)(ws + off);  off += (size_t)8*64*128*128*4;         // 33,554,432
  float*  sw_t= (float*)(ws + off);  off += (size_t)4*64*64*4;              // 65,536
  float*  aw_t= (float*)(ws + off);  off += (size_t)640*64*4;               // 163,840
  float2* zt = xh;   // reuse
  float2* zh = xw;   // reuse

  k_prep<<<160, 256, 0, stream>>>(skip_w, agg_w, sw_t, aw_t);
  k_lift<<<10240, 128, 0, stream>>>(frames, times, lift_w, lift_b, x);

  for (int l = 0; l < 4; ++l) {
    k_fwdW<<<2560, 256, 0, stream>>>(x, xw);
    k_fwdH<<<5120, 128, 0, stream>>>(xw, xh);
    k_fwdT<<<2048, 256, 0, stream>>>(xh, xf);
    k_mix<<<128, 256, 0, stream>>>(xf, spec_w + (size_t)l*4*64*64*256*2, yf);
    k_invT<<<2560, 256, 0, stream>>>(yf, zt);
    k_invH<<<5120, 256, 0, stream>>>(zt, zh);
    k_invW_skip<<<10240, 128, 0, stream>>>(zh, sw_t + (size_t)l*4096, skip_b + l*64, x);
  }
  k_agg<<<1024, 128, 0, stream>>>(x, aw_t, agg_b, xa);
  k_head<<<1024, 128, 0, stream>>>(xa, fc1_w, fc1_b, fc2_w, fc2_b, out);
}

// Round 2
// 3347.568 us; speedup vs baseline: 1.1352x; 1.1352x over previous
//
#include <hip/hip_runtime.h>
#include <math.h>

// FNO3d forward. B=8,T=10,H=128,W=128, C=64, NL=4, modes: kt 8, kh 16, kw 8.
// All fp32. Partial DFTs instead of full FFTs.

#define NB 8
#define NT 10
#define NH 128
#define NW 128
#define NC 64
#define TWO_PI 6.2831853071795864769f
#define ORTHO_SC 2.4705294220065465e-3f  // 1/sqrt(10*128*128)

// ---------------- lift ----------------
__global__ __launch_bounds__(128) void k_lift(const float* __restrict__ frames,
                                              const float* __restrict__ times,
                                              const float* __restrict__ lift_w,
                                              const float* __restrict__ lift_b,
                                              float* __restrict__ x) {
  int row = blockIdx.x;           // b*T*H + t*H + h
  int h = row & 127;
  int bt = row >> 7;
  int t = bt % NT, b = bt / NT;
  int w = threadIdx.x;
  float f = frames[((size_t)(b*NT + t)*NH + h)*NW + w];
  float tv = times[b*NT + t];
  #pragma unroll 4
  for (int c = 0; c < NC; ++c) {
    float val = f*lift_w[2*c] + tv*lift_w[2*c+1] + lift_b[c];
    x[(((size_t)(b*NC + c)*NT + t)*NH + h)*NW + w] = val;
  }
}

// ---------------- prep: transpose skip_w and agg_w ----------------
__global__ __launch_bounds__(256) void k_prep(const float* __restrict__ skip_w,
                                              const float* __restrict__ agg_w,
                                              float* __restrict__ sw_t,   // [4][64 i][64 o]
                                              float* __restrict__ aw_t) { // [640 k][64 o]
  int tid = blockIdx.x*256 + threadIdx.x;
  if (tid < 4*64*64) {
    int l = tid >> 12, r = tid & 4095, o = r >> 6, i = r & 63;
    sw_t[((size_t)l*64 + i)*64 + o] = skip_w[tid];
  }
  if (tid < 64*640) {
    int o = tid / 640, k = tid % 640;
    aw_t[(size_t)k*64 + o] = agg_w[tid];
  }
}

// ---------------- prep: transpose one layer's spec_w ----------------
// in (float2 view): [q][ci][co][m 256]  ->  out wT: [q][m 256][ci][co]
__global__ __launch_bounds__(256) void k_prep_w(const float* __restrict__ spec_w_l,
                                                float2* __restrict__ wT) {
  __shared__ float2 tile[64][65];
  int blk = blockIdx.x;          // q*256 + ci*4 + mc
  int mc = blk & 3, ci = (blk >> 2) & 63, q = blk >> 8;
  const float2* in = (const float2*)spec_w_l + (((size_t)q*64 + ci)*64)*256 + mc*64;
  for (int i = threadIdx.x; i < 4096; i += 256) {
    int co = i >> 6, mm = i & 63;
    tile[co][mm] = in[(size_t)co*256 + mm];
  }
  __syncthreads();
  float2* out = wT + ((size_t)q*256 + mc*64)*4096 + (size_t)ci*64;
  for (int i = threadIdx.x; i < 4096; i += 256) {
    int mm = i >> 6, co = i & 63;
    out[(size_t)mm*4096 + co] = tile[co][mm];
  }
}

// ---------------- forward W-stage: x(.,128w) -> 8 complex modes ----------------
__global__ __launch_bounds__(256) void k_fwdW(const float* __restrict__ x,
                                              float2* __restrict__ xw) {
  size_t row = (size_t)blockIdx.x*256 + threadIdx.x;
  const float* src = x + row*128;
  float ar[8], ai[8];
  #pragma unroll
  for (int k = 0; k < 8; ++k) { ar[k] = 0.f; ai[k] = 0.f; }
  const float cb = 0.9987954562051724f;     // cos(2pi/128)
  const float sbn = -0.04906767432741801f;  // -sin(2pi/128)
  float pr = 1.f, pi = 0.f;  // e^{-2pi i w/128}
  for (int w4 = 0; w4 < 32; ++w4) {
    float4 xv = ((const float4*)src)[w4];
    auto body = [&](float xu) {
      ar[0] += xu;
      float qr = pr, qi = pi;
      #pragma unroll
      for (int k = 1; k < 8; ++k) {
        ar[k] += xu*qr; ai[k] += xu*qi;
        float nr = qr*pr - qi*pi; qi = qr*pi + qi*pr; qr = nr;
      }
      float npr = pr*cb - pi*sbn; pi = pr*sbn + pi*cb; pr = npr;
    };
    body(xv.x); body(xv.y); body(xv.z); body(xv.w);
  }
  float4* dst = (float4*)(xw + row*8);
  #pragma unroll
  for (int q = 0; q < 4; ++q)
    dst[q] = make_float4(ar[2*q], ai[2*q], ar[2*q+1], ai[2*q+1]);
}

// ---------------- forward H-stage: 128h -> 16 modes ----------------
__global__ __launch_bounds__(128) void k_fwdH(const float2* __restrict__ xw,
                                              float2* __restrict__ xh) {
  __shared__ float2 tile[1024];  // [h][kw]
  int bct = blockIdx.x;
  const float2* src = xw + (size_t)bct*1024;
  for (int i = threadIdx.x; i < 1024; i += 128) tile[i] = src[i];
  __syncthreads();
  int j = threadIdx.x;
  int khi = j >> 3, kwi = j & 7;
  int kh = (khi < 8) ? khi : (112 + khi);   // 8..15 -> 120..127
  float th = -TWO_PI * (float)kh / 128.0f;
  float c, s; sincosf(th, &s, &c);
  float tr = 1.f, ti = 0.f, accr = 0.f, acci = 0.f;
  for (int h = 0; h < 128; ++h) {
    float2 v = tile[h*8 + kwi];
    accr += v.x*tr - v.y*ti;
    acci += v.x*ti + v.y*tr;
    float nr = tr*c - ti*s; ti = tr*s + ti*c; tr = nr;
  }
  xh[(size_t)bct*128 + j] = make_float2(accr, acci);
}

// ---------------- forward T-stage: 10t -> 8 modes (scaled) ----------------
__global__ __launch_bounds__(256) void k_fwdT(const float2* __restrict__ xh,
                                              float2* __restrict__ xf) {
  int o = blockIdx.x*256 + threadIdx.x;
  int kmode = o & 127;
  int kti = (o >> 7) & 7;
  int c = (o >> 10) & 63;
  int b = o >> 16;
  int kt = (kti < 4) ? kti : (kti + 2);
  const float2* src = xh + (size_t)(b*64 + c)*1280 + kmode;
  float th = -TWO_PI * (float)kt / 10.0f;
  float cc, ss; sincosf(th, &ss, &cc);
  float tr = 1.f, ti = 0.f, accr = 0.f, acci = 0.f;
  #pragma unroll
  for (int t = 0; t < 10; ++t) {
    float2 v = src[t*128];
    accr += v.x*tr - v.y*ti;
    acci += v.x*ti + v.y*tr;
    float nr = tr*cc - ti*ss; ti = tr*ss + ti*cc; tr = nr;
  }
  // layout xf[b][m][ci], m = kti*128 + kmode
  xf[((size_t)b*1024 + kti*128 + kmode)*64 + c] = make_float2(accr*ORTHO_SC, acci*ORTHO_SC);
}

// ---------------- channel mix in mode space (transposed weights) ----------------
// block per 4 modes; 256 threads = 64 co x 4 mi
__global__ __launch_bounds__(256) void k_mix(const float2* __restrict__ xf,
                                             const float2* __restrict__ wTl, // [q][m][ci][co]
                                             float2* __restrict__ yf) {
  __shared__ float2 xfs[8][4][64];   // [b][mi][ci]
  int m0 = blockIdx.x * 4;
  for (int i = threadIdx.x; i < 2048; i += 256) {
    int bb = i >> 8, mi = (i >> 6) & 3, ci = i & 63;
    xfs[bb][mi][ci] = xf[((size_t)bb*1024 + m0 + mi)*64 + ci];
  }
  __syncthreads();
  int co = threadIdx.x & 63, mi = threadIdx.x >> 6;
  int m = m0 + mi;
  int kti = m >> 7, khi = (m >> 3) & 15, kwi = m & 7;
  int q = ((kti >= 4) ? 2 : 0) + ((khi >= 8) ? 1 : 0);
  int modeidx = ((kti & 3)*8 + (khi & 7))*8 + kwi;
  const float2* wp = wTl + ((size_t)q*256 + modeidx)*4096 + co;
  float accr[8], acci[8];
  #pragma unroll
  for (int bb = 0; bb < 8; ++bb) { accr[bb] = 0.f; acci[bb] = 0.f; }
  for (int ci = 0; ci < 64; ++ci) {
    float2 wv = wp[(size_t)ci*64];
    #pragma unroll
    for (int bb = 0; bb < 8; ++bb) {
      float2 xv = xfs[bb][mi][ci];
      accr[bb] += xv.x*wv.x - xv.y*wv.y;
      acci[bb] += xv.x*wv.y + xv.y*wv.x;
    }
  }
  #pragma unroll
  for (int bb = 0; bb < 8; ++bb)
    yf[((size_t)bb*64 + co)*1024 + m] = make_float2(accr[bb], acci[bb]);
}

// ---------------- inverse T-stage (scaled) ----------------
__global__ __launch_bounds__(256) void k_invT(const float2* __restrict__ yf,
                                              float2* __restrict__ zt) {
  int o = blockIdx.x*256 + threadIdx.x;
  int kmode = o & 127;
  int t = (o >> 7) % 10;
  int bc = o / 1280;
  const float2* src = yf + (size_t)bc*1024 + kmode;
  float th = TWO_PI * (float)t / 10.0f;
  float cc, ss; sincosf(th, &ss, &cc);
  float tr = 1.f, ti = 0.f, accr = 0.f, acci = 0.f;
  #pragma unroll
  for (int k = 0; k < 10; ++k) {
    if (k < 4 || k >= 6) {
      int kti = (k < 4) ? k : (k - 2);
      float2 v = src[kti*128];
      accr += v.x*tr - v.y*ti;
      acci += v.x*ti + v.y*tr;
    }
    float nr = tr*cc - ti*ss; ti = tr*ss + ti*cc; tr = nr;
  }
  zt[o] = make_float2(accr*ORTHO_SC, acci*ORTHO_SC);
}

// ---------------- inverse H-stage ----------------
__global__ __launch_bounds__(256) void k_invH(const float2* __restrict__ zt,
                                              float2* __restrict__ zh) {
  __shared__ float2 zs[128];  // [khi][kwi]
  int bct = blockIdx.x;
  int t = bct % 10;
  int c = (bct / 10) & 63;
  int b = bct / 640;
  if (threadIdx.x < 128) zs[threadIdx.x] = zt[(size_t)bct*128 + threadIdx.x];
  __syncthreads();
  int h = threadIdx.x & 127;
  int half = threadIdx.x >> 7;
  float th = TWO_PI * (float)h / 128.0f;
  float cc, ss; sincosf(th, &ss, &cc);
  float pwr[9], pwi[9];
  pwr[0] = 1.f; pwi[0] = 0.f;
  #pragma unroll
  for (int k = 1; k < 9; ++k) {
    pwr[k] = pwr[k-1]*cc - pwi[k-1]*ss;
    pwi[k] = pwr[k-1]*ss + pwi[k-1]*cc;
  }
  float ar[4] = {0,0,0,0}, ai[4] = {0,0,0,0};
  #pragma unroll
  for (int khi = 0; khi < 16; ++khi) {
    float tr = (khi < 8) ? pwr[khi] : pwr[16-khi];
    float ti = (khi < 8) ? pwi[khi] : -pwi[16-khi];
    #pragma unroll
    for (int kk = 0; kk < 4; ++kk) {
      float2 v = zs[khi*8 + half*4 + kk];
      ar[kk] += v.x*tr - v.y*ti;
      ai[kk] += v.x*ti + v.y*tr;
    }
  }
  float2* dst = zh + ((((size_t)(b*10 + t)*128 + h)*64 + c)*8 + half*4);
  #pragma unroll
  for (int kk = 0; kk < 4; ++kk) dst[kk] = make_float2(ar[kk], ai[kk]);
}

// ---------------- inverse W + skip + bias + GELU (in-place on x) ----------------
// block per (b,t,h); 256 threads; tile 4co x 8w per thread; swizzled xs
__global__ __launch_bounds__(256) void k_invW_skip(const float2* __restrict__ zh,
                                                   const float* __restrict__ sw,   // [ci][co]
                                                   const float* __restrict__ skb,
                                                   float* __restrict__ x) {
  __shared__ float xs[64][128];
  __shared__ float2 zsh[64][9];
  int bid = blockIdx.x;
  int h = bid & 127;
  int bt = bid >> 7;
  int t = bt % 10, b = bt / 10;
  int tid = threadIdx.x;
  for (int i = tid; i < 2048; i += 256) {
    int ci = i >> 5, c = i & 31;
    const float* rowp = x + (((size_t)(b*64 + ci)*10 + t)*16384) + (size_t)h*128;
    float4 v = ((const float4*)rowp)[c];
    ((float4*)&xs[ci][0])[c ^ ((c >> 3) & 1)] = v;
  }
  {
    const float2* zsrc = zh + (size_t)bid*512;
    for (int i = tid; i < 512; i += 256)
      zsh[i >> 3][i & 7] = zsrc[i];
  }
  __syncthreads();

  int wq = tid & 15, cg = tid >> 4;   // cg 0..15
  int w0 = wq*8, co0 = cg*4;
  int c0 = (2*wq) ^ (((2*wq) >> 3) & 1);
  int c1 = (2*wq+1) ^ (((2*wq+1) >> 3) & 1);

  float acc[4][8];
  #pragma unroll
  for (int j = 0; j < 4; ++j)
    #pragma unroll
    for (int u = 0; u < 8; ++u) acc[j][u] = 0.f;

  // Phase B: skip matmul (weights from global, L1-resident)
  for (int ci = 0; ci < 64; ++ci) {
    float4 xv0 = ((const float4*)&xs[ci][0])[c0];
    float4 xv1 = ((const float4*)&xs[ci][0])[c1];
    float4 wv = *(const float4*)&sw[ci*64 + co0];
    float xv[8] = {xv0.x,xv0.y,xv0.z,xv0.w, xv1.x,xv1.y,xv1.z,xv1.w};
    float wvv[4] = {wv.x,wv.y,wv.z,wv.w};
    #pragma unroll
    for (int j = 0; j < 4; ++j)
      #pragma unroll
      for (int u = 0; u < 8; ++u)
        acc[j][u] += wvv[j]*xv[u];
  }

  // Phase A: inverse rfft over w from 8 modes (recurrence twiddles)
  const float CS = 0.99879545620517239271f;  // cos(2pi/128)
  const float SN = 0.04906767432741801425f;  // sin(2pi/128)
  float bc, bs;
  sincosf(TWO_PI * (float)w0 / 128.0f, &bs, &bc);
  #pragma unroll
  for (int j = 0; j < 4; ++j) {
    float zr[8], zi[8];
    #pragma unroll
    for (int k = 0; k < 8; ++k) { float2 v = zsh[co0+j][k]; zr[k] = v.x; zi[k] = v.y; }
    float tr = bc, ti = bs;   // e^{+i 2pi (w0+u)/128}, u=0
    #pragma unroll
    for (int u = 0; u < 8; ++u) {
      float s = zr[0];
      float pr = tr, pi2 = ti;
      #pragma unroll
      for (int k = 1; k < 8; ++k) {
        s += 2.f*(zr[k]*pr - zi[k]*pi2);
        float nr = pr*tr - pi2*ti; pi2 = pr*ti + pi2*tr; pr = nr;
      }
      acc[j][u] += s;
      float nr2 = tr*CS - ti*SN; ti = tr*SN + ti*CS; tr = nr2;
    }
  }

  // Phase C: bias + GELU(exact) + store in place
  #pragma unroll
  for (int j = 0; j < 4; ++j) {
    float bias = skb[co0 + j];
    float res[8];
    #pragma unroll
    for (int u = 0; u < 8; ++u) {
      float val = acc[j][u] + bias;
      res[u] = 0.5f*val*(1.0f + erff(val*0.70710678118654752f));
    }
    float* dst = x + (((size_t)(b*64 + co0 + j)*10 + t)*16384) + (size_t)h*128 + w0;
    *(float4*)dst = make_float4(res[0], res[1], res[2], res[3]);
    *(float4*)(dst + 4) = make_float4(res[4], res[5], res[6], res[7]);
  }
}

// ---------------- aggregation over (ci,t): K=640 GEMM ----------------
// block per (b,h); 256 threads; tile 4co x 8w; swizzled xs
__global__ __launch_bounds__(256) void k_agg(const float* __restrict__ x,
                                             const float* __restrict__ aw_t,  // [k][o]
                                             const float* __restrict__ agg_b,
                                             float* __restrict__ xa) {
  __shared__ float xs[64][128];
  __shared__ float ws[64][64];
  int bid = blockIdx.x;
  int h = bid & 127;
  int b = bid >> 7;
  int tid = threadIdx.x;
  int wq = tid & 15, cg = tid >> 4;
  int w0 = wq*8, co0 = cg*4;
  int c0 = (2*wq) ^ (((2*wq) >> 3) & 1);
  int c1 = (2*wq+1) ^ (((2*wq+1) >> 3) & 1);
  float acc[4][8];
  #pragma unroll
  for (int j = 0; j < 4; ++j)
    #pragma unroll
    for (int u = 0; u < 8; ++u) acc[j][u] = 0.f;
  for (int chunk = 0; chunk < 10; ++chunk) {
    __syncthreads();
    for (int i = tid; i < 2048; i += 256) {
      int j = i >> 5, c = i & 31;
      int k = chunk*64 + j;
      int ci = k / 10, t = k % 10;
      const float* rowp = x + (((size_t)(b*64 + ci)*10 + t)*16384) + (size_t)h*128;
      ((float4*)&xs[j][0])[c ^ ((c >> 3) & 1)] = ((const float4*)rowp)[c];
    }
    for (int i = tid; i < 1024; i += 256)
      ((float4*)ws)[i] = ((const float4*)(aw_t + (size_t)chunk*4096))[i];
    __syncthreads();
    #pragma unroll 4
    for (int j = 0; j < 64; ++j) {
      float4 xv0 = ((const float4*)&xs[j][0])[c0];
      float4 xv1 = ((const float4*)&xs[j][0])[c1];
      float4 wv = *(const float4*)&ws[j][co0];
      float xv[8] = {xv0.x,xv0.y,xv0.z,xv0.w, xv1.x,xv1.y,xv1.z,xv1.w};
      float wvv[4] = {wv.x,wv.y,wv.z,wv.w};
      #pragma unroll
      for (int jj = 0; jj < 4; ++jj)
        #pragma unroll
        for (int u = 0; u < 8; ++u)
          acc[jj][u] += wvv[jj]*xv[u];
    }
  }
  #pragma unroll
  for (int j = 0; j < 4; ++j) {
    float bias = agg_b[co0 + j];
    float* dst = xa + ((size_t)(b*64 + co0 + j)*128 + h)*128 + w0;
    *(float4*)dst = make_float4(acc[j][0]+bias, acc[j][1]+bias, acc[j][2]+bias, acc[j][3]+bias);
    *(float4*)(dst+4) = make_float4(acc[j][4]+bias, acc[j][5]+bias, acc[j][6]+bias, acc[j][7]+bias);
  }
}

// ---------------- MLP head ----------------
__global__ __launch_bounds__(128) void k_head(const float* __restrict__ xa,
                                              const float* __restrict__ fc1_w,
                                              const float* __restrict__ fc1_b,
                                              const float* __restrict__ fc2_w,
                                              const float* __restrict__ fc2_b,
                                              float* __restrict__ out) {
  int bid = blockIdx.x;
  int h = bid & 127, b = bid >> 7;
  int w = threadIdx.x;
  float v[64];
  #pragma unroll
  for (int c = 0; c < 64; ++c)
    v[c] = xa[((size_t)(b*64 + c)*128 + h)*128 + w];
  float gx = -1.f + 2.f*(float)w/127.f;
  float gy = -1.f + 2.f*(float)h/127.f;
  float o2[10];
  #pragma unroll
  for (int j = 0; j < 10; ++j) o2[j] = fc2_b[j];
  for (int o = 0; o < 128; ++o) {
    float a = fc1_b[o];
    #pragma unroll
    for (int i = 0; i < 64; ++i) a += v[i]*fc1_w[i*128 + o];
    a += gx*fc1_w[64*128 + o] + gy*fc1_w[65*128 + o];
    float g = 0.5f*a*(1.0f + erff(a*0.70710678118654752f));
    #pragma unroll
    for (int j = 0; j < 10; ++j) o2[j] += g*fc2_w[o*10 + j];
  }
  float* dst = out + ((size_t)bid*128 + w)*10;
  #pragma unroll
  for (int k = 0; k < 5; ++k) dst[k] = o2[2*k];
  #pragma unroll
  for (int k = 0; k < 5; ++k) {
    float sv = o2[2*k+1];
    float sp = fmaxf(sv, 0.f) + log1pf(expf(-fabsf(sv)));
    dst[5 + k] = sp + 1e-4f;
  }
}

extern "C" void kernel_launch(void* const* d_in, const int* in_sizes, int n_in,
                              void* d_out, int out_size, void* d_ws, size_t ws_size,
                              hipStream_t stream) {
  const float* frames = (const float*)d_in[0];
  const float* times  = (const float*)d_in[1];
  const float* lift_w = (const float*)d_in[2];
  const float* lift_b = (const float*)d_in[3];
  const float* spec_w = (const float*)d_in[4];
  const float* skip_w = (const float*)d_in[5];
  const float* skip_b = (const float*)d_in[6];
  const float* agg_w  = (const float*)d_in[7];
  const float* agg_b  = (const float*)d_in[8];
  const float* fc1_w  = (const float*)d_in[9];
  const float* fc1_b  = (const float*)d_in[10];
  const float* fc2_w  = (const float*)d_in[11];
  const float* fc2_b  = (const float*)d_in[12];
  float* out = (float*)d_out;
  char* ws = (char*)d_ws;

  // workspace layout (bytes)
  size_t off = 0;
  float*  x   = (float*)(ws + off);  off += (size_t)8*64*10*128*128*4;      // 335,544,320
  float2* xw  = (float2*)(ws + off); off += (size_t)8*64*10*128*8*8;        // 41,943,040
  float2* xh  = (float2*)(ws + off); off += (size_t)8*64*10*16*8*8;         // 5,242,880
  float2* xf  = (float2*)(ws + off); off += (size_t)8*1024*64*8;            // 4,194,304
  float2* yf  = (float2*)(ws + off); off += (size_t)8*1024*64*8;            // 4,194,304
  float*  xa  = (float*)(ws + off);  off += (size_t)8*64*128*128*4;         // 33,554,432
  float*  sw_t= (float*)(ws + off);  off += (size_t)4*64*64*4;              // 65,536
  float*  aw_t= (float*)(ws + off);  off += (size_t)640*64*4;               // 163,840
  float2* wT  = (float2*)(ws + off); off += (size_t)4*256*64*64*8;          // 33,554,432
  float2* zt = xh;   // reuse
  float2* zh = xw;   // reuse

  k_prep<<<160, 256, 0, stream>>>(skip_w, agg_w, sw_t, aw_t);
  k_lift<<<10240, 128, 0, stream>>>(frames, times, lift_w, lift_b, x);

  for (int l = 0; l < 4; ++l) {
    k_fwdW<<<2560, 256, 0, stream>>>(x, xw);
    k_fwdH<<<5120, 128, 0, stream>>>(xw, xh);
    k_fwdT<<<2048, 256, 0, stream>>>(xh, xf);
    k_prep_w<<<1024, 256, 0, stream>>>(spec_w + (size_t)l*4*64*64*256*2, wT);
    k_mix<<<256, 256, 0, stream>>>(xf, wT, yf);
    k_invT<<<2560, 256, 0, stream>>>(yf, zt);
    k_invH<<<5120, 256, 0, stream>>>(zt, zh);
    k_invW_skip<<<10240, 256, 0, stream>>>(zh, sw_t + (size_t)l*4096, skip_b + l*64, x);
  }
  k_agg<<<1024, 256, 0, stream>>>(x, aw_t, agg_b, xa);
  k_head<<<1024, 128, 0, stream>>>(xa, fc1_w, fc1_b, fc2_w, fc2_b, out);
}

// Round 3
// 1968.164 us; speedup vs baseline: 1.9308x; 1.7009x over previous
//
#include <hip/hip_runtime.h>
#include <math.h>

// FNO3d forward. B=8,T=10,H=128,W=128, C=64, NL=4, modes kt8 kh16 kw8.
// x kept TRANSPOSED: xT[(b*10+t)*128+h][w][ci]  (ci innermost)
// Skip+spectral-inverse-W fused as split-bf16 MFMA GEMM, K = 64(ci)+16(z)+16(pad).

#define TWO_PI 6.2831853071795864769f
#define ORTHO_SC 2.4705294220065465e-3f  // 1/sqrt(10*128*128)

typedef unsigned short u16;
typedef __attribute__((ext_vector_type(8))) short bf16x8;
typedef __attribute__((ext_vector_type(4))) float f32x4;

__device__ __forceinline__ u16 bf16rn(float v) {
  unsigned u = __float_as_uint(v);
  return (u16)((u + 0x7FFFu + ((u >> 16) & 1u)) >> 16);
}

#define MFMA16(acc, a, b) acc = __builtin_amdgcn_mfma_f32_16x16x32_bf16(a, b, acc, 0, 0, 0)

// ---------------- prep: weight fragments + twiddle tables ----------------
// swf: [layer4][strip4][ks2][half2][lane64][8]  (A-frags of skip_w, bf16 hi/lo)
// awf: [strip4][t10][ks2][half2][lane64][8]     (A-frags of agg_w)
// Tt : [half2][w128][kk32]                       (B twiddle rows for spectral K-ext)
// twf: [w128][k8] float2 = (cos(2pi kw/128), -sin(2pi kw/128))
__global__ __launch_bounds__(256) void k_prep2(const float* __restrict__ skip_w,
                                               const float* __restrict__ agg_w,
                                               u16* __restrict__ swf,
                                               u16* __restrict__ awf,
                                               u16* __restrict__ Tt,
                                               float2* __restrict__ twf) {
  int e = blockIdx.x*256 + threadIdx.x;
  if (e < 32768) {
    int j = e & 7, lane = (e >> 3) & 63, half = (e >> 9) & 1, ks = (e >> 10) & 1;
    int strip = (e >> 11) & 3, layer = e >> 13;
    int co = strip*16 + (lane & 15);
    int ci = ks*32 + (lane >> 4)*8 + j;
    float v = skip_w[((size_t)(layer*64) + co)*64 + ci];
    u16 hi = bf16rn(v);
    float r = v - __uint_as_float((unsigned)hi << 16);
    swf[e] = half ? bf16rn(r) : hi;
  } else if (e < 32768 + 81920) {
    int ee = e - 32768;
    int j = ee & 7, lane = (ee >> 3) & 63;
    int v9 = ee >> 9;
    int half = v9 & 1; v9 >>= 1;
    int ks = v9 & 1; v9 >>= 1;
    int t = v9 % 10, strip = v9 / 10;
    int co = strip*16 + (lane & 15);
    int ci = ks*32 + (lane >> 4)*8 + j;
    float v = agg_w[((size_t)co*64 + ci)*10 + t];
    u16 hi = bf16rn(v);
    float r = v - __uint_as_float((unsigned)hi << 16);
    awf[ee] = half ? bf16rn(r) : hi;
  } else if (e < 32768 + 81920 + 8192) {
    int ee = e - (32768 + 81920);
    int half = ee >> 12, r = ee & 4095, w = r >> 5, kk = r & 31;
    int m = kk >> 1;
    float val;
    if (kk >= 16) val = 0.f;
    else if (kk == 0) val = 1.f;
    else if (kk == 1) val = 0.f;
    else {
      float th = TWO_PI * (float)m * (float)w / 128.0f;
      val = (kk & 1) ? (-2.f*sinf(th)) : (2.f*cosf(th));
    }
    u16 hi = bf16rn(val);
    float rr = val - __uint_as_float((unsigned)hi << 16);
    Tt[ee] = half ? bf16rn(rr) : hi;
  } else if (e < 32768 + 81920 + 8192 + 1024) {
    int ee = e - (32768 + 81920 + 8192);
    int w = ee >> 3, k = ee & 7;
    float th = TWO_PI * (float)k * (float)w / 128.0f;
    twf[ee] = make_float2(cosf(th), -sinf(th));
  }
}

// ---------------- lift (writes xT) ----------------
__global__ __launch_bounds__(128) void k_liftT(const float* __restrict__ frames,
                                               const float* __restrict__ times,
                                               const float* __restrict__ lift_w,
                                               const float* __restrict__ lift_b,
                                               float* __restrict__ xT) {
  __shared__ float fr[128];
  __shared__ float lw0[64], lw1[64], lb[64];
  int bth = blockIdx.x;
  int h = bth & 127; int bt = bth >> 7; int t = bt % 10, b = bt / 10;
  int tid = threadIdx.x;
  fr[tid] = frames[((size_t)(b*10 + t)*128 + h)*128 + tid];
  if (tid < 64) { lw0[tid] = lift_w[2*tid]; lw1[tid] = lift_w[2*tid+1]; lb[tid] = lift_b[tid]; }
  __syncthreads();
  float tv = times[b*10 + t];
  int ci = tid & 63;
  float a0 = lw0[ci];
  float a1 = lw1[ci]*tv + lb[ci];
  float* dst = xT + (size_t)bth*8192;
  for (int u = tid; u < 8192; u += 128) {
    int w = u >> 6;
    dst[u] = fr[w]*a0 + a1;
  }
}

// ---------------- forward W-stage from xT ----------------
// wave per (b,t,h); lane = ci; table twiddles
__global__ __launch_bounds__(256) void k_fwdWT(const float* __restrict__ xT,
                                               const float2* __restrict__ twf,
                                               float2* __restrict__ xw) {
  __shared__ float2 tw[128][8];
  int tid = threadIdx.x;
  for (int i = tid; i < 1024; i += 256) tw[i >> 3][i & 7] = twf[i];
  __syncthreads();
  int bth = blockIdx.x*4 + (tid >> 6);
  int lane = tid & 63;
  int h = bth & 127; int bt = bth >> 7; int t = bt % 10, b = bt / 10;
  const float* src = xT + (size_t)bth*8192 + lane;
  float ar[8], ai[8];
  #pragma unroll
  for (int k = 0; k < 8; ++k) { ar[k] = 0.f; ai[k] = 0.f; }
  for (int w = 0; w < 128; ++w) {
    float xu = src[w*64];
    ar[0] += xu;
    #pragma unroll
    for (int k = 1; k < 8; ++k) {
      float2 ew = tw[w][k];
      ar[k] += xu*ew.x; ai[k] += xu*ew.y;
    }
  }
  size_t row = ((size_t)(b*64 + lane)*10 + t)*128 + h;
  float4* dst = (float4*)(xw + row*8);
  #pragma unroll
  for (int q = 0; q < 4; ++q)
    dst[q] = make_float4(ar[2*q], ai[2*q], ar[2*q+1], ai[2*q+1]);
}

// ---------------- forward H-stage: 128h -> 16 modes ----------------
__global__ __launch_bounds__(128) void k_fwdH(const float2* __restrict__ xw,
                                              float2* __restrict__ xh) {
  __shared__ float2 tile[1024];  // [h][kw]
  int bct = blockIdx.x;
  const float2* src = xw + (size_t)bct*1024;
  for (int i = threadIdx.x; i < 1024; i += 128) tile[i] = src[i];
  __syncthreads();
  int j = threadIdx.x;
  int khi = j >> 3, kwi = j & 7;
  int kh = (khi < 8) ? khi : (112 + khi);
  float th = -TWO_PI * (float)kh / 128.0f;
  float c, s; sincosf(th, &s, &c);
  float tr = 1.f, ti = 0.f, accr = 0.f, acci = 0.f;
  for (int h = 0; h < 128; ++h) {
    float2 v = tile[h*8 + kwi];
    accr += v.x*tr - v.y*ti;
    acci += v.x*ti + v.y*tr;
    float nr = tr*c - ti*s; ti = tr*s + ti*c; tr = nr;
  }
  xh[(size_t)bct*128 + j] = make_float2(accr, acci);
}

// ---------------- forward T-stage: 10t -> 8 modes (scaled) ----------------
__global__ __launch_bounds__(256) void k_fwdT(const float2* __restrict__ xh,
                                              float2* __restrict__ xf) {
  int o = blockIdx.x*256 + threadIdx.x;
  int kmode = o & 127;
  int kti = (o >> 7) & 7;
  int c = (o >> 10) & 63;
  int b = o >> 16;
  int kt = (kti < 4) ? kti : (kti + 2);
  const float2* src = xh + (size_t)(b*64 + c)*1280 + kmode;
  float th = -TWO_PI * (float)kt / 10.0f;
  float cc, ss; sincosf(th, &ss, &cc);
  float tr = 1.f, ti = 0.f, accr = 0.f, acci = 0.f;
  #pragma unroll
  for (int t = 0; t < 10; ++t) {
    float2 v = src[t*128];
    accr += v.x*tr - v.y*ti;
    acci += v.x*ti + v.y*tr;
    float nr = tr*cc - ti*ss; ti = tr*ss + ti*cc; tr = nr;
  }
  xf[((size_t)b*1024 + kti*128 + kmode)*64 + c] = make_float2(accr*ORTHO_SC, acci*ORTHO_SC);
}

// ---------------- prep: transpose one layer's spec_w ----------------
__global__ __launch_bounds__(256) void k_prep_w(const float* __restrict__ spec_w_l,
                                                float2* __restrict__ wT) {
  __shared__ float2 tile[64][65];
  int blk = blockIdx.x;
  int mc = blk & 3, ci = (blk >> 2) & 63, q = blk >> 8;
  const float2* in = (const float2*)spec_w_l + (((size_t)q*64 + ci)*64)*256 + mc*64;
  for (int i = threadIdx.x; i < 4096; i += 256) {
    int co = i >> 6, mm = i & 63;
    tile[co][mm] = in[(size_t)co*256 + mm];
  }
  __syncthreads();
  float2* out = wT + ((size_t)q*256 + mc*64)*4096 + (size_t)ci*64;
  for (int i = threadIdx.x; i < 4096; i += 256) {
    int mm = i >> 6, co = i & 63;
    out[(size_t)mm*4096 + co] = tile[co][mm];
  }
}

// ---------------- channel mix ----------------
__global__ __launch_bounds__(256) void k_mix(const float2* __restrict__ xf,
                                             const float2* __restrict__ wTl,
                                             float2* __restrict__ yf) {
  __shared__ float2 xfs[8][4][64];
  int m0 = blockIdx.x * 4;
  for (int i = threadIdx.x; i < 2048; i += 256) {
    int bb = i >> 8, mi = (i >> 6) & 3, ci = i & 63;
    xfs[bb][mi][ci] = xf[((size_t)bb*1024 + m0 + mi)*64 + ci];
  }
  __syncthreads();
  int co = threadIdx.x & 63, mi = threadIdx.x >> 6;
  int m = m0 + mi;
  int kti = m >> 7, khi = (m >> 3) & 15, kwi = m & 7;
  int q = ((kti >= 4) ? 2 : 0) + ((khi >= 8) ? 1 : 0);
  int modeidx = ((kti & 3)*8 + (khi & 7))*8 + kwi;
  const float2* wp = wTl + ((size_t)q*256 + modeidx)*4096 + co;
  float accr[8], acci[8];
  #pragma unroll
  for (int bb = 0; bb < 8; ++bb) { accr[bb] = 0.f; acci[bb] = 0.f; }
  for (int ci = 0; ci < 64; ++ci) {
    float2 wv = wp[(size_t)ci*64];
    #pragma unroll
    for (int bb = 0; bb < 8; ++bb) {
      float2 xv = xfs[bb][mi][ci];
      accr[bb] += xv.x*wv.x - xv.y*wv.y;
      acci[bb] += xv.x*wv.y + xv.y*wv.x;
    }
  }
  #pragma unroll
  for (int bb = 0; bb < 8; ++bb)
    yf[((size_t)bb*64 + co)*1024 + m] = make_float2(accr[bb], acci[bb]);
}

// ---------------- inverse T-stage ----------------
__global__ __launch_bounds__(256) void k_invT(const float2* __restrict__ yf,
                                              float2* __restrict__ zt) {
  int o = blockIdx.x*256 + threadIdx.x;
  int kmode = o & 127;
  int t = (o >> 7) % 10;
  int bc = o / 1280;
  const float2* src = yf + (size_t)bc*1024 + kmode;
  float th = TWO_PI * (float)t / 10.0f;
  float cc, ss; sincosf(th, &ss, &cc);
  float tr = 1.f, ti = 0.f, accr = 0.f, acci = 0.f;
  #pragma unroll
  for (int k = 0; k < 10; ++k) {
    if (k < 4 || k >= 6) {
      int kti = (k < 4) ? k : (k - 2);
      float2 v = src[kti*128];
      accr += v.x*tr - v.y*ti;
      acci += v.x*ti + v.y*tr;
    }
    float nr = tr*cc - ti*ss; ti = tr*ss + ti*cc; tr = nr;
  }
  zt[o] = make_float2(accr*ORTHO_SC, acci*ORTHO_SC);
}

// ---------------- inverse H-stage ----------------
__global__ __launch_bounds__(256) void k_invH(const float2* __restrict__ zt,
                                              float2* __restrict__ zh) {
  __shared__ float2 zs[128];
  int bct = blockIdx.x;
  int t = bct % 10;
  int c = (bct / 10) & 63;
  int b = bct / 640;
  if (threadIdx.x < 128) zs[threadIdx.x] = zt[(size_t)bct*128 + threadIdx.x];
  __syncthreads();
  int h = threadIdx.x & 127;
  int half = threadIdx.x >> 7;
  float th = TWO_PI * (float)h / 128.0f;
  float cc, ss; sincosf(th, &ss, &cc);
  float pwr[9], pwi[9];
  pwr[0] = 1.f; pwi[0] = 0.f;
  #pragma unroll
  for (int k = 1; k < 9; ++k) {
    pwr[k] = pwr[k-1]*cc - pwi[k-1]*ss;
    pwi[k] = pwr[k-1]*ss + pwi[k-1]*cc;
  }
  float ar[4] = {0,0,0,0}, ai[4] = {0,0,0,0};
  #pragma unroll
  for (int khi = 0; khi < 16; ++khi) {
    float tr = (khi < 8) ? pwr[khi] : pwr[16-khi];
    float ti = (khi < 8) ? pwi[khi] : -pwi[16-khi];
    #pragma unroll
    for (int kk = 0; kk < 4; ++kk) {
      float2 v = zs[khi*8 + half*4 + kk];
      ar[kk] += v.x*tr - v.y*ti;
      ai[kk] += v.x*ti + v.y*tr;
    }
  }
  float2* dst = zh + ((((size_t)(b*10 + t)*128 + h)*64 + c)*8 + half*4);
  #pragma unroll
  for (int kk = 0; kk < 4; ++kk) dst[kk] = make_float2(ar[kk], ai[kk]);
}

// ---------------- fused inverse-W + skip as split-bf16 MFMA ----------------
// block per (b,t,h); 256 thr = 4 waves; C[64co][128w]; K=96 (64 ci + 16 z + pad)
// LDS rows: BH/BL [128 w][104 u16] (k 0..63 = x, 64..95 = T, 96..103 = zA pads)
__global__ __launch_bounds__(256) void k_invW_mfma(const float* __restrict__ xT,
                                                   const float2* __restrict__ zh,
                                                   const u16* __restrict__ swf_l,
                                                   const u16* __restrict__ Tt,
                                                   const float* __restrict__ skb,
                                                   float* __restrict__ xTo) {
  __shared__ __align__(16) char smem[53248];
  u16* BH = (u16*)smem;             // [128][104]
  u16* BL = (u16*)(smem + 26624);   // [128][104]
  int tid = threadIdx.x;
  int bth = blockIdx.x;
  const float* xsrc = xT + (size_t)bth*8192;

  // stage x (k=0..63), split hi/lo
  for (int u = tid; u < 512; u += 256) {
    int w = u >> 2, c = u & 3;
    const float4* p = (const float4*)(xsrc + w*64 + c*16);
    float4 v0 = p[0], v1 = p[1], v2 = p[2], v3 = p[3];
    float vals[16] = {v0.x,v0.y,v0.z,v0.w, v1.x,v1.y,v1.z,v1.w,
                      v2.x,v2.y,v2.z,v2.w, v3.x,v3.y,v3.z,v3.w};
    unsigned hp[8], lp[8];
    #pragma unroll
    for (int q = 0; q < 8; ++q) {
      float a = vals[2*q], bv = vals[2*q+1];
      u16 ha = bf16rn(a), hb = bf16rn(bv);
      float ra = a - __uint_as_float((unsigned)ha << 16);
      float rb = bv - __uint_as_float((unsigned)hb << 16);
      hp[q] = (unsigned)ha | ((unsigned)hb << 16);
      lp[q] = (unsigned)bf16rn(ra) | ((unsigned)bf16rn(rb) << 16);
    }
    uint4* dh = (uint4*)(BH + w*104 + c*16);
    dh[0] = make_uint4(hp[0],hp[1],hp[2],hp[3]);
    dh[1] = make_uint4(hp[4],hp[5],hp[6],hp[7]);
    uint4* dl = (uint4*)(BL + w*104 + c*16);
    dl[0] = make_uint4(lp[0],lp[1],lp[2],lp[3]);
    dl[1] = make_uint4(lp[4],lp[5],lp[6],lp[7]);
  }
  // stage T rows (k=64..95) from prepped global
  {
    int u = tid;
    if (u < 256) {
      int w = u >> 1, c = u & 1;
      const uint4* sh = (const uint4*)(Tt + w*32 + c*16);
      const uint4* sl = (const uint4*)(Tt + 4096 + w*32 + c*16);
      uint4* dh = (uint4*)(BH + w*104 + 64 + c*16);
      uint4* dl = (uint4*)(BL + w*104 + 64 + c*16);
      dh[0] = sh[0]; dh[1] = sh[1];
      dl[0] = sl[0]; dl[1] = sl[1];
    }
  }
  // stage zA into row pads: zA(co, g) at (2co+g)*104 + 96
  {
    const float2* zsrc = zh + (size_t)bth*512;
    for (int u = tid; u < 512; u += 256) {
      int co = u >> 3, m = u & 7;
      float2 v = zsrc[u];
      u16 hr = bf16rn(v.x);
      float rr = v.x - __uint_as_float((unsigned)hr << 16);
      u16 lr = bf16rn(rr);
      u16 hi_ = bf16rn(v.y);
      float ri = v.y - __uint_as_float((unsigned)hi_ << 16);
      u16 li_ = bf16rn(ri);
      int g = m >> 2;
      int off = (2*co + g)*104 + 96 + ((2*m) & 7);
      *(unsigned*)(BH + off) = (unsigned)hr | ((unsigned)hi_ << 16);
      *(unsigned*)(BL + off) = (unsigned)lr | ((unsigned)li_ << 16);
    }
  }
  __syncthreads();

  int lane = tid & 63;
  int wv = tid >> 6;
  int cL = lane & 15;
  int g = lane >> 4;

  // A-fragments (global, L2-hot): skip weights hi/lo for both K-steps
  bf16x8 A0h = *(const bf16x8*)(swf_l + (((wv*2+0)*2+0)*64 + lane)*8);
  bf16x8 A0l = *(const bf16x8*)(swf_l + (((wv*2+0)*2+1)*64 + lane)*8);
  bf16x8 A1h = *(const bf16x8*)(swf_l + (((wv*2+1)*2+0)*64 + lane)*8);
  bf16x8 A1l = *(const bf16x8*)(swf_l + (((wv*2+1)*2+1)*64 + lane)*8);
  // spectral A-fragment (rows = co, k = 16 z values then zeros)
  int coA = wv*16 + cL;
  bf16x8 Azh, Azl;
  {
    int zoff = (2*coA + (g & 1))*104 + 96;
    bf16x8 th_ = *(const bf16x8*)(BH + zoff);
    bf16x8 tl_ = *(const bf16x8*)(BL + zoff);
    bf16x8 zero8 = {0,0,0,0,0,0,0,0};
    Azh = (g < 2) ? th_ : zero8;
    Azl = (g < 2) ? tl_ : zero8;
  }

  f32x4 acc[8];
  #pragma unroll
  for (int t = 0; t < 8; ++t) acc[t] = (f32x4){0.f,0.f,0.f,0.f};

  #pragma unroll
  for (int t = 0; t < 8; ++t) {
    const u16* rowH = BH + (16*t + cL)*104;
    const u16* rowL = BL + (16*t + cL)*104;
    bf16x8 bh, bl;
    bh = *(const bf16x8*)(rowH + g*8);
    bl = *(const bf16x8*)(rowL + g*8);
    MFMA16(acc[t], A0h, bh); MFMA16(acc[t], A0l, bh); MFMA16(acc[t], A0h, bl);
    bh = *(const bf16x8*)(rowH + 32 + g*8);
    bl = *(const bf16x8*)(rowL + 32 + g*8);
    MFMA16(acc[t], A1h, bh); MFMA16(acc[t], A1l, bh); MFMA16(acc[t], A1h, bl);
    bh = *(const bf16x8*)(rowH + 64 + g*8);
    bl = *(const bf16x8*)(rowL + 64 + g*8);
    MFMA16(acc[t], Azh, bh); MFMA16(acc[t], Azl, bh); MFMA16(acc[t], Azh, bl);
  }

  __syncthreads();
  float* outT = (float*)smem;  // [64][132]
  float4 bias4 = *(const float4*)(skb + wv*16 + g*4);
  float bb[4] = {bias4.x, bias4.y, bias4.z, bias4.w};
  #pragma unroll
  for (int t = 0; t < 8; ++t) {
    #pragma unroll
    for (int r = 0; r < 4; ++r) {
      int co = wv*16 + g*4 + r;
      float val = acc[t][r] + bb[r];
      float ge = 0.5f*val*(1.0f + erff(val*0.70710678118654752f));
      outT[co*132 + t*16 + cL] = ge;
    }
  }
  __syncthreads();
  float* xdst = xTo + (size_t)bth*8192;
  for (int u = tid; u < 512; u += 256) {
    int w = u >> 2, c = u & 3;
    float o[16];
    #pragma unroll
    for (int j = 0; j < 16; ++j) o[j] = outT[(c*16 + j)*132 + w];
    float4* dst = (float4*)(xdst + w*64 + c*16);
    dst[0] = make_float4(o[0],o[1],o[2],o[3]);
    dst[1] = make_float4(o[4],o[5],o[6],o[7]);
    dst[2] = make_float4(o[8],o[9],o[10],o[11]);
    dst[3] = make_float4(o[12],o[13],o[14],o[15]);
  }
}

// ---------------- aggregation as split-bf16 MFMA (K = 640) ----------------
__global__ __launch_bounds__(256) void k_agg_mfma(const float* __restrict__ xT,
                                                  const u16* __restrict__ awf,
                                                  const float* __restrict__ agg_b,
                                                  float* __restrict__ xa) {
  __shared__ __align__(16) char smem[36864];
  u16* BH = (u16*)smem;             // [128][72]
  u16* BL = (u16*)(smem + 18432);
  int tid = threadIdx.x;
  int bid = blockIdx.x;
  int h = bid & 127, b = bid >> 7;
  int lane = tid & 63;
  int wv = tid >> 6;
  int cL = lane & 15;
  int g = lane >> 4;

  f32x4 acc[8];
  #pragma unroll
  for (int t = 0; t < 8; ++t) acc[t] = (f32x4){0.f,0.f,0.f,0.f};

  for (int t = 0; t < 10; ++t) {
    __syncthreads();
    const float* xsrc = xT + ((size_t)(b*10 + t)*128 + h)*8192;
    for (int u = tid; u < 512; u += 256) {
      int w = u >> 2, c = u & 3;
      const float4* p = (const float4*)(xsrc + w*64 + c*16);
      float4 v0 = p[0], v1 = p[1], v2 = p[2], v3 = p[3];
      float vals[16] = {v0.x,v0.y,v0.z,v0.w, v1.x,v1.y,v1.z,v1.w,
                        v2.x,v2.y,v2.z,v2.w, v3.x,v3.y,v3.z,v3.w};
      unsigned hp[8], lp[8];
      #pragma unroll
      for (int q = 0; q < 8; ++q) {
        float a = vals[2*q], bv = vals[2*q+1];
        u16 ha = bf16rn(a), hb = bf16rn(bv);
        float ra = a - __uint_as_float((unsigned)ha << 16);
        float rb = bv - __uint_as_float((unsigned)hb << 16);
        hp[q] = (unsigned)ha | ((unsigned)hb << 16);
        lp[q] = (unsigned)bf16rn(ra) | ((unsigned)bf16rn(rb) << 16);
      }
      uint4* dh = (uint4*)(BH + w*72 + c*16);
      dh[0] = make_uint4(hp[0],hp[1],hp[2],hp[3]);
      dh[1] = make_uint4(hp[4],hp[5],hp[6],hp[7]);
      uint4* dl = (uint4*)(BL + w*72 + c*16);
      dl[0] = make_uint4(lp[0],lp[1],lp[2],lp[3]);
      dl[1] = make_uint4(lp[4],lp[5],lp[6],lp[7]);
    }
    __syncthreads();
    const u16* af = awf + ((size_t)(wv*10 + t)*4)*512;
    #pragma unroll
    for (int ks = 0; ks < 2; ++ks) {
      bf16x8 Ah = *(const bf16x8*)(af + (ks*2+0)*512 + lane*8);
      bf16x8 Al = *(const bf16x8*)(af + (ks*2+1)*512 + lane*8);
      #pragma unroll
      for (int t8 = 0; t8 < 8; ++t8) {
        const u16* rowH = BH + (16*t8 + cL)*72 + ks*32 + g*8;
        const u16* rowL = BL + (16*t8 + cL)*72 + ks*32 + g*8;
        bf16x8 bh = *(const bf16x8*)rowH;
        bf16x8 bl = *(const bf16x8*)rowL;
        MFMA16(acc[t8], Ah, bh); MFMA16(acc[t8], Al, bh); MFMA16(acc[t8], Ah, bl);
      }
    }
  }

  __syncthreads();
  float* outT = (float*)smem;  // [64][132]
  float4 bias4 = *(const float4*)(agg_b + wv*16 + g*4);
  float bb[4] = {bias4.x, bias4.y, bias4.z, bias4.w};
  #pragma unroll
  for (int t = 0; t < 8; ++t) {
    #pragma unroll
    for (int r = 0; r < 4; ++r) {
      int co = wv*16 + g*4 + r;
      outT[co*132 + t*16 + cL] = acc[t][r] + bb[r];
    }
  }
  __syncthreads();
  for (int u = tid; u < 256; u += 256) {
    int co = u >> 2, c32 = u & 3;
    float* dst = xa + ((size_t)(b*64 + co)*128 + h)*128 + c32*32;
    #pragma unroll
    for (int q = 0; q < 8; ++q) {
      float4 vv = make_float4(outT[co*132 + c32*32 + 4*q],
                              outT[co*132 + c32*32 + 4*q + 1],
                              outT[co*132 + c32*32 + 4*q + 2],
                              outT[co*132 + c32*32 + 4*q + 3]);
      ((float4*)dst)[q] = vv;
    }
  }
}

// ---------------- MLP head ----------------
__global__ __launch_bounds__(128) void k_head(const float* __restrict__ xa,
                                              const float* __restrict__ fc1_w,
                                              const float* __restrict__ fc1_b,
                                              const float* __restrict__ fc2_w,
                                              const float* __restrict__ fc2_b,
                                              float* __restrict__ out) {
  int bid = blockIdx.x;
  int h = bid & 127, b = bid >> 7;
  int w = threadIdx.x;
  float v[64];
  #pragma unroll
  for (int c = 0; c < 64; ++c)
    v[c] = xa[((size_t)(b*64 + c)*128 + h)*128 + w];
  float gx = -1.f + 2.f*(float)w/127.f;
  float gy = -1.f + 2.f*(float)h/127.f;
  float o2[10];
  #pragma unroll
  for (int j = 0; j < 10; ++j) o2[j] = fc2_b[j];
  for (int o = 0; o < 128; ++o) {
    float a = fc1_b[o];
    #pragma unroll
    for (int i = 0; i < 64; ++i) a += v[i]*fc1_w[i*128 + o];
    a += gx*fc1_w[64*128 + o] + gy*fc1_w[65*128 + o];
    float g = 0.5f*a*(1.0f + erff(a*0.70710678118654752f));
    #pragma unroll
    for (int j = 0; j < 10; ++j) o2[j] += g*fc2_w[o*10 + j];
  }
  float* dst = out + ((size_t)bid*128 + w)*10;
  #pragma unroll
  for (int k = 0; k < 5; ++k) dst[k] = o2[2*k];
  #pragma unroll
  for (int k = 0; k < 5; ++k) {
    float sv = o2[2*k+1];
    float sp = fmaxf(sv, 0.f) + log1pf(expf(-fabsf(sv)));
    dst[5 + k] = sp + 1e-4f;
  }
}

extern "C" void kernel_launch(void* const* d_in, const int* in_sizes, int n_in,
                              void* d_out, int out_size, void* d_ws, size_t ws_size,
                              hipStream_t stream) {
  const float* frames = (const float*)d_in[0];
  const float* times  = (const float*)d_in[1];
  const float* lift_w = (const float*)d_in[2];
  const float* lift_b = (const float*)d_in[3];
  const float* spec_w = (const float*)d_in[4];
  const float* skip_w = (const float*)d_in[5];
  const float* skip_b = (const float*)d_in[6];
  const float* agg_w  = (const float*)d_in[7];
  const float* agg_b  = (const float*)d_in[8];
  const float* fc1_w  = (const float*)d_in[9];
  const float* fc1_b  = (const float*)d_in[10];
  const float* fc2_w  = (const float*)d_in[11];
  const float* fc2_b  = (const float*)d_in[12];
  float* out = (float*)d_out;
  char* ws = (char*)d_ws;

  size_t off = 0;
  float*  xT  = (float*)(ws + off);  off += (size_t)8*10*128*128*64*4;      // 335,544,320
  float2* xw  = (float2*)(ws + off); off += (size_t)8*64*10*128*8*8;        // 41,943,040
  float2* xh  = (float2*)(ws + off); off += (size_t)8*64*10*16*8*8;         // 5,242,880
  float2* xf  = (float2*)(ws + off); off += (size_t)8*1024*64*8;            // 4,194,304
  float2* yf  = (float2*)(ws + off); off += (size_t)8*1024*64*8;            // 4,194,304
  float*  xa  = (float*)(ws + off);  off += (size_t)8*64*128*128*4;         // 33,554,432
  float2* wT  = (float2*)(ws + off); off += (size_t)4*256*64*64*8;          // 33,554,432
  u16*    swf = (u16*)(ws + off);    off += (size_t)32768*2;                // 65,536
  u16*    awf = (u16*)(ws + off);    off += (size_t)81920*2;                // 163,840
  u16*    Tt  = (u16*)(ws + off);    off += (size_t)8192*2;                 // 16,384
  float2* twf = (float2*)(ws + off); off += (size_t)1024*8;                 // 8,192
  float2* zt = xh;
  float2* zh = xw;

  k_prep2<<<484, 256, 0, stream>>>(skip_w, agg_w, swf, awf, Tt, twf);
  k_liftT<<<10240, 128, 0, stream>>>(frames, times, lift_w, lift_b, xT);

  for (int l = 0; l < 4; ++l) {
    k_fwdWT<<<2560, 256, 0, stream>>>(xT, twf, xw);
    k_fwdH<<<5120, 128, 0, stream>>>(xw, xh);
    k_fwdT<<<2048, 256, 0, stream>>>(xh, xf);
    k_prep_w<<<1024, 256, 0, stream>>>(spec_w + (size_t)l*4*64*64*256*2, wT);
    k_mix<<<256, 256, 0, stream>>>(xf, wT, yf);
    k_invT<<<2560, 256, 0, stream>>>(yf, zt);
    k_invH<<<5120, 256, 0, stream>>>(zt, zh);
    k_invW_mfma<<<10240, 256, 0, stream>>>(xT, zh, swf + (size_t)l*8192, Tt,
                                           skip_b + l*64, xT);
  }
  k_agg_mfma<<<1024, 256, 0, stream>>>(xT, awf, agg_b, xa);
  k_head<<<1024, 128, 0, stream>>>(xa, fc1_w, fc1_b, fc2_w, fc2_b, out);
}

// Round 5
// 1819.759 us; speedup vs baseline: 2.0882x; 1.0816x over previous
//
#include <hip/hip_runtime.h>
#include <math.h>

// FNO3d forward. B=8,T=10,H=128,W=128, C=64, NL=4, modes kt8 kh16 kw8.
// x kept TRANSPOSED: xT[(b*10+t)*128+h][w][ci]  (ci innermost)
// Skip+spectral-inverse-W fused as split-bf16 MFMA GEMM, K = 64(ci)+32(T)+pad.
// Round 5: wave tiling = 64co x 32w (4 A-strips per wave) -> 4x fewer LDS B-reads.

#define TWO_PI 6.2831853071795864769f
#define ORTHO_SC 2.4705294220065465e-3f  // 1/sqrt(10*128*128)

typedef unsigned short u16;
typedef __attribute__((ext_vector_type(8))) short bf16x8;
typedef __attribute__((ext_vector_type(4))) float f32x4;

__device__ __forceinline__ u16 bf16rn(float v) {
  unsigned u = __float_as_uint(v);
  return (u16)((u + 0x7FFFu + ((u >> 16) & 1u)) >> 16);
}

#define MFMA16(acc, a, b) acc = __builtin_amdgcn_mfma_f32_16x16x32_bf16(a, b, acc, 0, 0, 0)

// ---------------- prep: weight fragments + twiddle tables ----------------
__global__ __launch_bounds__(256) void k_prep2(const float* __restrict__ skip_w,
                                               const float* __restrict__ agg_w,
                                               u16* __restrict__ swf,
                                               u16* __restrict__ awf,
                                               u16* __restrict__ Tt,
                                               float2* __restrict__ twf) {
  int e = blockIdx.x*256 + threadIdx.x;
  if (e < 32768) {
    int j = e & 7, lane = (e >> 3) & 63, half = (e >> 9) & 1, ks = (e >> 10) & 1;
    int strip = (e >> 11) & 3, layer = e >> 13;
    int co = strip*16 + (lane & 15);
    int ci = ks*32 + (lane >> 4)*8 + j;
    float v = skip_w[((size_t)(layer*64) + co)*64 + ci];
    u16 hi = bf16rn(v);
    float r = v - __uint_as_float((unsigned)hi << 16);
    swf[e] = half ? bf16rn(r) : hi;
  } else if (e < 32768 + 81920) {
    int ee = e - 32768;
    int j = ee & 7, lane = (ee >> 3) & 63;
    int v9 = ee >> 9;
    int half = v9 & 1; v9 >>= 1;
    int ks = v9 & 1; v9 >>= 1;
    int t = v9 % 10, strip = v9 / 10;
    int co = strip*16 + (lane & 15);
    int ci = ks*32 + (lane >> 4)*8 + j;
    float v = agg_w[((size_t)co*64 + ci)*10 + t];
    u16 hi = bf16rn(v);
    float r = v - __uint_as_float((unsigned)hi << 16);
    awf[ee] = half ? bf16rn(r) : hi;
  } else if (e < 32768 + 81920 + 8192) {
    int ee = e - (32768 + 81920);
    int half = ee >> 12, r = ee & 4095, w = r >> 5, kk = r & 31;
    int m = kk >> 1;
    float val;
    if (kk >= 16) val = 0.f;
    else if (kk == 0) val = 1.f;
    else if (kk == 1) val = 0.f;
    else {
      float th = TWO_PI * (float)m * (float)w / 128.0f;
      val = (kk & 1) ? (-2.f*sinf(th)) : (2.f*cosf(th));
    }
    u16 hi = bf16rn(val);
    float rr = val - __uint_as_float((unsigned)hi << 16);
    Tt[ee] = half ? bf16rn(rr) : hi;
  } else if (e < 32768 + 81920 + 8192 + 1024) {
    int ee = e - (32768 + 81920 + 8192);
    int w = ee >> 3, k = ee & 7;
    float th = TWO_PI * (float)k * (float)w / 128.0f;
    twf[ee] = make_float2(cosf(th), -sinf(th));
  }
}

// ---------------- lift (writes xT) ----------------
__global__ __launch_bounds__(128) void k_liftT(const float* __restrict__ frames,
                                               const float* __restrict__ times,
                                               const float* __restrict__ lift_w,
                                               const float* __restrict__ lift_b,
                                               float* __restrict__ xT) {
  __shared__ float fr[128];
  __shared__ float lw0[64], lw1[64], lb[64];
  int bth = blockIdx.x;
  int h = bth & 127; int bt = bth >> 7; int t = bt % 10, b = bt / 10;
  int tid = threadIdx.x;
  fr[tid] = frames[((size_t)(b*10 + t)*128 + h)*128 + tid];
  if (tid < 64) { lw0[tid] = lift_w[2*tid]; lw1[tid] = lift_w[2*tid+1]; lb[tid] = lift_b[tid]; }
  __syncthreads();
  float tv = times[b*10 + t];
  int ci = tid & 63;
  float a0 = lw0[ci];
  float a1 = lw1[ci]*tv + lb[ci];
  float* dst = xT + (size_t)bth*8192;
  for (int u = tid; u < 8192; u += 128) {
    int w = u >> 6;
    dst[u] = fr[w]*a0 + a1;
  }
}

// ---------------- forward W-stage from xT ----------------
__global__ __launch_bounds__(256) void k_fwdWT(const float* __restrict__ xT,
                                               const float2* __restrict__ twf,
                                               float2* __restrict__ xw) {
  __shared__ float2 tw[128][8];
  int tid = threadIdx.x;
  for (int i = tid; i < 1024; i += 256) tw[i >> 3][i & 7] = twf[i];
  __syncthreads();
  int bth = blockIdx.x*4 + (tid >> 6);
  int lane = tid & 63;
  int h = bth & 127; int bt = bth >> 7; int t = bt % 10, b = bt / 10;
  const float* src = xT + (size_t)bth*8192 + lane;
  float ar[8], ai[8];
  #pragma unroll
  for (int k = 0; k < 8; ++k) { ar[k] = 0.f; ai[k] = 0.f; }
  for (int w = 0; w < 128; ++w) {
    float xu = src[w*64];
    ar[0] += xu;
    #pragma unroll
    for (int k = 1; k < 8; ++k) {
      float2 ew = tw[w][k];
      ar[k] += xu*ew.x; ai[k] += xu*ew.y;
    }
  }
  size_t row = ((size_t)(b*64 + lane)*10 + t)*128 + h;
  float4* dst = (float4*)(xw + row*8);
  #pragma unroll
  for (int q = 0; q < 4; ++q)
    dst[q] = make_float4(ar[2*q], ai[2*q], ar[2*q+1], ai[2*q+1]);
}

// ---------------- forward H-stage: 128h -> 16 modes ----------------
__global__ __launch_bounds__(128) void k_fwdH(const float2* __restrict__ xw,
                                              float2* __restrict__ xh) {
  __shared__ float2 tile[1024];
  int bct = blockIdx.x;
  const float2* src = xw + (size_t)bct*1024;
  for (int i = threadIdx.x; i < 1024; i += 128) tile[i] = src[i];
  __syncthreads();
  int j = threadIdx.x;
  int khi = j >> 3, kwi = j & 7;
  int kh = (khi < 8) ? khi : (112 + khi);
  float th = -TWO_PI * (float)kh / 128.0f;
  float c, s; sincosf(th, &s, &c);
  float tr = 1.f, ti = 0.f, accr = 0.f, acci = 0.f;
  for (int h = 0; h < 128; ++h) {
    float2 v = tile[h*8 + kwi];
    accr += v.x*tr - v.y*ti;
    acci += v.x*ti + v.y*tr;
    float nr = tr*c - ti*s; ti = tr*s + ti*c; tr = nr;
  }
  xh[(size_t)bct*128 + j] = make_float2(accr, acci);
}

// ---------------- forward T-stage: 10t -> 8 modes (scaled) ----------------
__global__ __launch_bounds__(256) void k_fwdT(const float2* __restrict__ xh,
                                              float2* __restrict__ xf) {
  int o = blockIdx.x*256 + threadIdx.x;
  int kmode = o & 127;
  int kti = (o >> 7) & 7;
  int c = (o >> 10) & 63;
  int b = o >> 16;
  int kt = (kti < 4) ? kti : (kti + 2);
  const float2* src = xh + (size_t)(b*64 + c)*1280 + kmode;
  float th = -TWO_PI * (float)kt / 10.0f;
  float cc, ss; sincosf(th, &ss, &cc);
  float tr = 1.f, ti = 0.f, accr = 0.f, acci = 0.f;
  #pragma unroll
  for (int t = 0; t < 10; ++t) {
    float2 v = src[t*128];
    accr += v.x*tr - v.y*ti;
    acci += v.x*ti + v.y*tr;
    float nr = tr*cc - ti*ss; ti = tr*ss + ti*cc; tr = nr;
  }
  xf[((size_t)b*1024 + kti*128 + kmode)*64 + c] = make_float2(accr*ORTHO_SC, acci*ORTHO_SC);
}

// ---------------- prep: transpose one layer's spec_w ----------------
__global__ __launch_bounds__(256) void k_prep_w(const float* __restrict__ spec_w_l,
                                                float2* __restrict__ wT) {
  __shared__ float2 tile[64][65];
  int blk = blockIdx.x;
  int mc = blk & 3, ci = (blk >> 2) & 63, q = blk >> 8;
  const float2* in = (const float2*)spec_w_l + (((size_t)q*64 + ci)*64)*256 + mc*64;
  for (int i = threadIdx.x; i < 4096; i += 256) {
    int co = i >> 6, mm = i & 63;
    tile[co][mm] = in[(size_t)co*256 + mm];
  }
  __syncthreads();
  float2* out = wT + ((size_t)q*256 + mc*64)*4096 + (size_t)ci*64;
  for (int i = threadIdx.x; i < 4096; i += 256) {
    int mm = i >> 6, co = i & 63;
    out[(size_t)mm*4096 + co] = tile[co][mm];
  }
}

// ---------------- channel mix ----------------
__global__ __launch_bounds__(256) void k_mix(const float2* __restrict__ xf,
                                             const float2* __restrict__ wTl,
                                             float2* __restrict__ yf) {
  __shared__ float2 xfs[8][4][64];
  int m0 = blockIdx.x * 4;
  for (int i = threadIdx.x; i < 2048; i += 256) {
    int bb = i >> 8, mi = (i >> 6) & 3, ci = i & 63;
    xfs[bb][mi][ci] = xf[((size_t)bb*1024 + m0 + mi)*64 + ci];
  }
  __syncthreads();
  int co = threadIdx.x & 63, mi = threadIdx.x >> 6;
  int m = m0 + mi;
  int kti = m >> 7, khi = (m >> 3) & 15, kwi = m & 7;
  int q = ((kti >= 4) ? 2 : 0) + ((khi >= 8) ? 1 : 0);
  int modeidx = ((kti & 3)*8 + (khi & 7))*8 + kwi;
  const float2* wp = wTl + ((size_t)q*256 + modeidx)*4096 + co;
  float accr[8], acci[8];
  #pragma unroll
  for (int bb = 0; bb < 8; ++bb) { accr[bb] = 0.f; acci[bb] = 0.f; }
  for (int ci = 0; ci < 64; ++ci) {
    float2 wv = wp[(size_t)ci*64];
    #pragma unroll
    for (int bb = 0; bb < 8; ++bb) {
      float2 xv = xfs[bb][mi][ci];
      accr[bb] += xv.x*wv.x - xv.y*wv.y;
      acci[bb] += xv.x*wv.y + xv.y*wv.x;
    }
  }
  #pragma unroll
  for (int bb = 0; bb < 8; ++bb)
    yf[((size_t)bb*64 + co)*1024 + m] = make_float2(accr[bb], acci[bb]);
}

// ---------------- inverse T-stage ----------------
__global__ __launch_bounds__(256) void k_invT(const float2* __restrict__ yf,
                                              float2* __restrict__ zt) {
  int o = blockIdx.x*256 + threadIdx.x;
  int kmode = o & 127;
  int t = (o >> 7) % 10;
  int bc = o / 1280;
  const float2* src = yf + (size_t)bc*1024 + kmode;
  float th = TWO_PI * (float)t / 10.0f;
  float cc, ss; sincosf(th, &ss, &cc);
  float tr = 1.f, ti = 0.f, accr = 0.f, acci = 0.f;
  #pragma unroll
  for (int k = 0; k < 10; ++k) {
    if (k < 4 || k >= 6) {
      int kti = (k < 4) ? k : (k - 2);
      float2 v = src[kti*128];
      accr += v.x*tr - v.y*ti;
      acci += v.x*ti + v.y*tr;
    }
    float nr = tr*cc - ti*ss; ti = tr*ss + ti*cc; tr = nr;
  }
  zt[o] = make_float2(accr*ORTHO_SC, acci*ORTHO_SC);
}

// ---------------- inverse H-stage ----------------
__global__ __launch_bounds__(256) void k_invH(const float2* __restrict__ zt,
                                              float2* __restrict__ zh) {
  __shared__ float2 zs[128];
  int bct = blockIdx.x;
  int t = bct % 10;
  int c = (bct / 10) & 63;
  int b = bct / 640;
  if (threadIdx.x < 128) zs[threadIdx.x] = zt[(size_t)bct*128 + threadIdx.x];
  __syncthreads();
  int h = threadIdx.x & 127;
  int half = threadIdx.x >> 7;
  float th = TWO_PI * (float)h / 128.0f;
  float cc, ss; sincosf(th, &ss, &cc);
  float pwr[9], pwi[9];
  pwr[0] = 1.f; pwi[0] = 0.f;
  #pragma unroll
  for (int k = 1; k < 9; ++k) {
    pwr[k] = pwr[k-1]*cc - pwi[k-1]*ss;
    pwi[k] = pwr[k-1]*ss + pwi[k-1]*cc;
  }
  float ar[4] = {0,0,0,0}, ai[4] = {0,0,0,0};
  #pragma unroll
  for (int khi = 0; khi < 16; ++khi) {
    float tr = (khi < 8) ? pwr[khi] : pwr[16-khi];
    float ti = (khi < 8) ? pwi[khi] : -pwi[16-khi];
    #pragma unroll
    for (int kk = 0; kk < 4; ++kk) {
      float2 v = zs[khi*8 + half*4 + kk];
      ar[kk] += v.x*tr - v.y*ti;
      ai[kk] += v.x*ti + v.y*tr;
    }
  }
  float2* dst = zh + ((((size_t)(b*10 + t)*128 + h)*64 + c)*8 + half*4);
  #pragma unroll
  for (int kk = 0; kk < 4; ++kk) dst[kk] = make_float2(ar[kk], ai[kk]);
}

// ---------------- fused inverse-W + skip as split-bf16 MFMA ----------------
// block per (b,t,h); 256 thr = 4 waves; C[64co][128w].
// Round-5 tiling: wave wq owns w in [wq*32, wq*32+32), ALL 64 co (4 A-strips).
__global__ __launch_bounds__(256) void k_invW_mfma(const float* __restrict__ xT,
                                                   const float2* __restrict__ zh,
                                                   const u16* __restrict__ swf_l,
                                                   const u16* __restrict__ Tt,
                                                   const float* __restrict__ skb,
                                                   float* __restrict__ xTo) {
  __shared__ __align__(16) char smem[53248];
  u16* BH = (u16*)smem;             // [128][104]
  u16* BL = (u16*)(smem + 26624);   // [128][104]
  int tid = threadIdx.x;
  int bth = blockIdx.x;
  const float* xsrc = xT + (size_t)bth*8192;

  // stage x (k=0..63), split hi/lo  (verbatim round 3)
  for (int u = tid; u < 512; u += 256) {
    int w = u >> 2, c = u & 3;
    const float4* p = (const float4*)(xsrc + w*64 + c*16);
    float4 v0 = p[0], v1 = p[1], v2 = p[2], v3 = p[3];
    float vals[16] = {v0.x,v0.y,v0.z,v0.w, v1.x,v1.y,v1.z,v1.w,
                      v2.x,v2.y,v2.z,v2.w, v3.x,v3.y,v3.z,v3.w};
    unsigned hp[8], lp[8];
    #pragma unroll
    for (int q = 0; q < 8; ++q) {
      float a = vals[2*q], bv = vals[2*q+1];
      u16 ha = bf16rn(a), hb = bf16rn(bv);
      float ra = a - __uint_as_float((unsigned)ha << 16);
      float rb = bv - __uint_as_float((unsigned)hb << 16);
      hp[q] = (unsigned)ha | ((unsigned)hb << 16);
      lp[q] = (unsigned)bf16rn(ra) | ((unsigned)bf16rn(rb) << 16);
    }
    uint4* dh = (uint4*)(BH + w*104 + c*16);
    dh[0] = make_uint4(hp[0],hp[1],hp[2],hp[3]);
    dh[1] = make_uint4(hp[4],hp[5],hp[6],hp[7]);
    uint4* dl = (uint4*)(BL + w*104 + c*16);
    dl[0] = make_uint4(lp[0],lp[1],lp[2],lp[3]);
    dl[1] = make_uint4(lp[4],lp[5],lp[6],lp[7]);
  }
  // stage T rows (k=64..95)  (verbatim round 3)
  {
    int u = tid;
    if (u < 256) {
      int w = u >> 1, c = u & 1;
      const uint4* sh = (const uint4*)(Tt + w*32 + c*16);
      const uint4* sl = (const uint4*)(Tt + 4096 + w*32 + c*16);
      uint4* dh = (uint4*)(BH + w*104 + 64 + c*16);
      uint4* dl = (uint4*)(BL + w*104 + 64 + c*16);
      dh[0] = sh[0]; dh[1] = sh[1];
      dl[0] = sl[0]; dl[1] = sl[1];
    }
  }
  // stage zA into row pads  (verbatim round 3)
  {
    const float2* zsrc = zh + (size_t)bth*512;
    for (int u = tid; u < 512; u += 256) {
      int co = u >> 3, m = u & 7;
      float2 v = zsrc[u];
      u16 hr = bf16rn(v.x);
      float rr = v.x - __uint_as_float((unsigned)hr << 16);
      u16 lr = bf16rn(rr);
      u16 hi_ = bf16rn(v.y);
      float ri = v.y - __uint_as_float((unsigned)hi_ << 16);
      u16 li_ = bf16rn(ri);
      int g = m >> 2;
      int off = (2*co + g)*104 + 96 + ((2*m) & 7);
      *(unsigned*)(BH + off) = (unsigned)hr | ((unsigned)hi_ << 16);
      *(unsigned*)(BL + off) = (unsigned)lr | ((unsigned)li_ << 16);
    }
  }
  __syncthreads();

  int lane = tid & 63;
  int wq = tid >> 6;        // wave's w-quarter
  int cL = lane & 15;
  int g = lane >> 4;

  f32x4 acc[4][2];
  #pragma unroll
  for (int s = 0; s < 4; ++s)
    #pragma unroll
    for (int t2 = 0; t2 < 2; ++t2) acc[s][t2] = (f32x4){0.f,0.f,0.f,0.f};

  // x k-blocks (kb=0: ci 0..31, kb=1: ci 32..63)
  #pragma unroll
  for (int kb = 0; kb < 2; ++kb) {
    bf16x8 Ah[4], Al[4];
    #pragma unroll
    for (int s = 0; s < 4; ++s) {
      Ah[s] = *(const bf16x8*)(swf_l + (size_t)(((s*2+kb)*2+0)*64 + lane)*8);
      Al[s] = *(const bf16x8*)(swf_l + (size_t)(((s*2+kb)*2+1)*64 + lane)*8);
    }
    #pragma unroll
    for (int t2 = 0; t2 < 2; ++t2) {
      int wrow = wq*32 + t2*16 + cL;
      bf16x8 bh = *(const bf16x8*)(BH + wrow*104 + kb*32 + g*8);
      bf16x8 bl = *(const bf16x8*)(BL + wrow*104 + kb*32 + g*8);
      #pragma unroll
      for (int s = 0; s < 4; ++s) {
        MFMA16(acc[s][t2], Ah[s], bh);
        MFMA16(acc[s][t2], Al[s], bh);
        MFMA16(acc[s][t2], Ah[s], bl);
      }
    }
  }
  // T k-block (spectral z * twiddle rows)
  {
    bf16x8 Azh[4], Azl[4];
    bf16x8 zero8 = {0,0,0,0,0,0,0,0};
    #pragma unroll
    for (int s = 0; s < 4; ++s) {
      if (g < 2) {
        int zoff = (2*(s*16 + cL) + (g & 1))*104 + 96;
        Azh[s] = *(const bf16x8*)(BH + zoff);
        Azl[s] = *(const bf16x8*)(BL + zoff);
      } else { Azh[s] = zero8; Azl[s] = zero8; }
    }
    #pragma unroll
    for (int t2 = 0; t2 < 2; ++t2) {
      int wrow = wq*32 + t2*16 + cL;
      bf16x8 bh = *(const bf16x8*)(BH + wrow*104 + 64 + g*8);
      bf16x8 bl = *(const bf16x8*)(BL + wrow*104 + 64 + g*8);
      #pragma unroll
      for (int s = 0; s < 4; ++s) {
        MFMA16(acc[s][t2], Azh[s], bh);
        MFMA16(acc[s][t2], Azl[s], bh);
        MFMA16(acc[s][t2], Azh[s], bl);
      }
    }
  }

  __syncthreads();
  float* outT = (float*)smem;  // [64][132]
  #pragma unroll
  for (int s = 0; s < 4; ++s) {
    float4 b4 = *(const float4*)(skb + s*16 + g*4);
    float bb[4] = {b4.x, b4.y, b4.z, b4.w};
    #pragma unroll
    for (int t2 = 0; t2 < 2; ++t2) {
      int w = wq*32 + t2*16 + cL;
      #pragma unroll
      for (int r = 0; r < 4; ++r) {
        int co = s*16 + g*4 + r;
        float val = acc[s][t2][r] + bb[r];
        float ge = 0.5f*val*(1.0f + erff(val*0.70710678118654752f));
        outT[co*132 + w] = ge;
      }
    }
  }
  __syncthreads();
  float* xdst = xTo + (size_t)bth*8192;
  for (int u = tid; u < 512; u += 256) {
    int w = u >> 2, c = u & 3;
    float o[16];
    #pragma unroll
    for (int j = 0; j < 16; ++j) o[j] = outT[(c*16 + j)*132 + w];
    float4* dst = (float4*)(xdst + w*64 + c*16);
    dst[0] = make_float4(o[0],o[1],o[2],o[3]);
    dst[1] = make_float4(o[4],o[5],o[6],o[7]);
    dst[2] = make_float4(o[8],o[9],o[10],o[11]);
    dst[3] = make_float4(o[12],o[13],o[14],o[15]);
  }
}

// ---------------- aggregation as split-bf16 MFMA (K = 640) ----------------
__global__ __launch_bounds__(256) void k_agg_mfma(const float* __restrict__ xT,
                                                  const u16* __restrict__ awf,
                                                  const float* __restrict__ agg_b,
                                                  float* __restrict__ xa) {
  __shared__ __align__(16) char smem[36864];
  u16* BH = (u16*)smem;             // [128][72]
  u16* BL = (u16*)(smem + 18432);
  int tid = threadIdx.x;
  int bid = blockIdx.x;
  int h = bid & 127, b = bid >> 7;
  int lane = tid & 63;
  int wq = tid >> 6;
  int cL = lane & 15;
  int g = lane >> 4;

  f32x4 acc[4][2];
  #pragma unroll
  for (int s = 0; s < 4; ++s)
    #pragma unroll
    for (int t2 = 0; t2 < 2; ++t2) acc[s][t2] = (f32x4){0.f,0.f,0.f,0.f};

  for (int t = 0; t < 10; ++t) {
    __syncthreads();
    const float* xsrc = xT + ((size_t)(b*10 + t)*128 + h)*8192;
    for (int u = tid; u < 512; u += 256) {
      int w = u >> 2, c = u & 3;
      const float4* p = (const float4*)(xsrc + w*64 + c*16);
      float4 v0 = p[0], v1 = p[1], v2 = p[2], v3 = p[3];
      float vals[16] = {v0.x,v0.y,v0.z,v0.w, v1.x,v1.y,v1.z,v1.w,
                        v2.x,v2.y,v2.z,v2.w, v3.x,v3.y,v3.z,v3.w};
      unsigned hp[8], lp[8];
      #pragma unroll
      for (int q = 0; q < 8; ++q) {
        float a = vals[2*q], bv = vals[2*q+1];
        u16 ha = bf16rn(a), hb = bf16rn(bv);
        float ra = a - __uint_as_float((unsigned)ha << 16);
        float rb = bv - __uint_as_float((unsigned)hb << 16);
        hp[q] = (unsigned)ha | ((unsigned)hb << 16);
        lp[q] = (unsigned)bf16rn(ra) | ((unsigned)bf16rn(rb) << 16);
      }
      uint4* dh = (uint4*)(BH + w*72 + c*16);
      dh[0] = make_uint4(hp[0],hp[1],hp[2],hp[3]);
      dh[1] = make_uint4(hp[4],hp[5],hp[6],hp[7]);
      uint4* dl = (uint4*)(BL + w*72 + c*16);
      dl[0] = make_uint4(lp[0],lp[1],lp[2],lp[3]);
      dl[1] = make_uint4(lp[4],lp[5],lp[6],lp[7]);
    }
    __syncthreads();
    #pragma unroll
    for (int kc = 0; kc < 2; ++kc) {
      bf16x8 Ah[4], Al[4];
      #pragma unroll
      for (int s = 0; s < 4; ++s) {
        const u16* af = awf + (size_t)((s*10 + t)*4 + kc*2)*512;
        Ah[s] = *(const bf16x8*)(af + lane*8);
        Al[s] = *(const bf16x8*)(af + 512 + lane*8);
      }
      #pragma unroll
      for (int t2 = 0; t2 < 2; ++t2) {
        int wrow = wq*32 + t2*16 + cL;
        bf16x8 bh = *(const bf16x8*)(BH + wrow*72 + kc*32 + g*8);
        bf16x8 bl = *(const bf16x8*)(BL + wrow*72 + kc*32 + g*8);
        #pragma unroll
        for (int s = 0; s < 4; ++s) {
          MFMA16(acc[s][t2], Ah[s], bh);
          MFMA16(acc[s][t2], Al[s], bh);
          MFMA16(acc[s][t2], Ah[s], bl);
        }
      }
    }
  }

  __syncthreads();
  float* outT = (float*)smem;  // [64][132]
  #pragma unroll
  for (int s = 0; s < 4; ++s) {
    float4 b4 = *(const float4*)(agg_b + s*16 + g*4);
    float bb[4] = {b4.x, b4.y, b4.z, b4.w};
    #pragma unroll
    for (int t2 = 0; t2 < 2; ++t2) {
      int w = wq*32 + t2*16 + cL;
      #pragma unroll
      for (int r = 0; r < 4; ++r) {
        int co = s*16 + g*4 + r;
        outT[co*132 + w] = acc[s][t2][r] + bb[r];
      }
    }
  }
  __syncthreads();
  for (int u = tid; u < 256; u += 256) {
    int co = u >> 2, c32 = u & 3;
    float* dst = xa + ((size_t)(b*64 + co)*128 + h)*128 + c32*32;
    #pragma unroll
    for (int q = 0; q < 8; ++q) {
      float4 vv = make_float4(outT[co*132 + c32*32 + 4*q],
                              outT[co*132 + c32*32 + 4*q + 1],
                              outT[co*132 + c32*32 + 4*q + 2],
                              outT[co*132 + c32*32 + 4*q + 3]);
      ((float4*)dst)[q] = vv;
    }
  }
}

// ---------------- MLP head (weights staged in LDS) ----------------
__global__ __launch_bounds__(128) void k_head(const float* __restrict__ xa,
                                              const float* __restrict__ fc1_w,
                                              const float* __restrict__ fc1_b,
                                              const float* __restrict__ fc2_w,
                                              const float* __restrict__ fc2_b,
                                              float* __restrict__ out) {
  __shared__ float w1[66*128];
  __shared__ float w2[128*10];
  __shared__ float b1s[128];
  __shared__ float b2s[16];
  int bid = blockIdx.x;
  int h = bid & 127, b = bid >> 7;
  int tid = threadIdx.x;
  for (int i = tid; i < 66*128; i += 128) w1[i] = fc1_w[i];
  for (int i = tid; i < 1280; i += 128) w2[i] = fc2_w[i];
  b1s[tid] = fc1_b[tid];
  if (tid < 10) b2s[tid] = fc2_b[tid];
  float v[64];
  #pragma unroll
  for (int c = 0; c < 64; ++c)
    v[c] = xa[((size_t)(b*64 + c)*128 + h)*128 + tid];
  __syncthreads();
  float gx = -1.f + 2.f*(float)tid/127.f;
  float gy = -1.f + 2.f*(float)h/127.f;
  float o2[10];
  #pragma unroll
  for (int j = 0; j < 10; ++j) o2[j] = b2s[j];
  for (int o = 0; o < 128; ++o) {
    float a = b1s[o];
    #pragma unroll
    for (int i = 0; i < 64; ++i) a += v[i]*w1[i*128 + o];
    a += gx*w1[64*128 + o] + gy*w1[65*128 + o];
    float g = 0.5f*a*(1.0f + erff(a*0.70710678118654752f));
    #pragma unroll
    for (int j = 0; j < 10; ++j) o2[j] += g*w2[o*10 + j];
  }
  float* dst = out + ((size_t)bid*128 + tid)*10;
  #pragma unroll
  for (int k = 0; k < 5; ++k) dst[k] = o2[2*k];
  #pragma unroll
  for (int k = 0; k < 5; ++k) {
    float sv = o2[2*k+1];
    float sp = fmaxf(sv, 0.f) + log1pf(expf(-fabsf(sv)));
    dst[5 + k] = sp + 1e-4f;
  }
}

extern "C" void kernel_launch(void* const* d_in, const int* in_sizes, int n_in,
                              void* d_out, int out_size, void* d_ws, size_t ws_size,
                              hipStream_t stream) {
  const float* frames = (const float*)d_in[0];
  const float* times  = (const float*)d_in[1];
  const float* lift_w = (const float*)d_in[2];
  const float* lift_b = (const float*)d_in[3];
  const float* spec_w = (const float*)d_in[4];
  const float* skip_w = (const float*)d_in[5];
  const float* skip_b = (const float*)d_in[6];
  const float* agg_w  = (const float*)d_in[7];
  const float* agg_b  = (const float*)d_in[8];
  const float* fc1_w  = (const float*)d_in[9];
  const float* fc1_b  = (const float*)d_in[10];
  const float* fc2_w  = (const float*)d_in[11];
  const float* fc2_b  = (const float*)d_in[12];
  float* out = (float*)d_out;
  char* ws = (char*)d_ws;

  size_t off = 0;
  float*  xT  = (float*)(ws + off);  off += (size_t)8*10*128*128*64*4;      // 335,544,320
  float2* xw  = (float2*)(ws + off); off += (size_t)8*64*10*128*8*8;        // 41,943,040
  float2* xh  = (float2*)(ws + off); off += (size_t)8*64*10*16*8*8;         // 5,242,880
  float2* xf  = (float2*)(ws + off); off += (size_t)8*1024*64*8;            // 4,194,304
  float2* yf  = (float2*)(ws + off); off += (size_t)8*1024*64*8;            // 4,194,304
  float*  xa  = (float*)(ws + off);  off += (size_t)8*64*128*128*4;         // 33,554,432
  float2* wT  = (float2*)(ws + off); off += (size_t)4*256*64*64*8;          // 33,554,432
  u16*    swf = (u16*)(ws + off);    off += (size_t)32768*2;                // 65,536
  u16*    awf = (u16*)(ws + off);    off += (size_t)81920*2;                // 163,840
  u16*    Tt  = (u16*)(ws + off);    off += (size_t)8192*2;                 // 16,384
  float2* twf = (float2*)(ws + off); off += (size_t)1024*8;                 // 8,192
  float2* zt = xh;
  float2* zh = xw;

  k_prep2<<<484, 256, 0, stream>>>(skip_w, agg_w, swf, awf, Tt, twf);
  k_liftT<<<10240, 128, 0, stream>>>(frames, times, lift_w, lift_b, xT);

  for (int l = 0; l < 4; ++l) {
    k_fwdWT<<<2560, 256, 0, stream>>>(xT, twf, (float2*)xw);
    k_fwdH<<<5120, 128, 0, stream>>>((const float2*)xw, xh);
    k_fwdT<<<2048, 256, 0, stream>>>(xh, xf);
    k_prep_w<<<1024, 256, 0, stream>>>(spec_w + (size_t)l*4*64*64*256*2, wT);
    k_mix<<<256, 256, 0, stream>>>(xf, wT, yf);
    k_invT<<<2560, 256, 0, stream>>>(yf, zt);
    k_invH<<<5120, 256, 0, stream>>>(zt, zh);
    k_invW_mfma<<<10240, 256, 0, stream>>>(xT, zh, swf + (size_t)l*8192, Tt,
                                           skip_b + l*64, xT);
  }
  k_agg_mfma<<<1024, 256, 0, stream>>>(xT, awf, agg_b, xa);
  k_head<<<1024, 128, 0, stream>>>(xa, fc1_w, fc1_b, fc2_w, fc2_b, out);
}

// Round 6
// 1285.043 us; speedup vs baseline: 2.9571x; 1.4161x over previous
//
#include <hip/hip_runtime.h>
#include <math.h>

// FNO3d forward. B=8,T=10,H=128,W=128, C=64, NL=4, modes kt8 kh16 kw8.
// x stored FP16, layout xT[(b*10+t)*128+h][w][ci] (ci innermost).
// GEMMs: A = offline split-fp16 (hi+lo, 2^-22), B = x in fp16 (EXACT, since x
// is stored fp16). T-twiddle block: 3-product split (zh*Th + zl*Th + zh*Tl).
// Round 6 = round-5 structure + fp16 storage/MFMA only (one change).

#define TWO_PI 6.2831853071795864769f
#define ORTHO_SC 2.4705294220065465e-3f  // 1/sqrt(10*128*128)

typedef unsigned short u16;
typedef _Float16 f16;
typedef __attribute__((ext_vector_type(8))) _Float16 f16x8;
typedef __attribute__((ext_vector_type(4))) float f32x4;

#define MFMAH(acc, a, b) acc = __builtin_amdgcn_mfma_f32_16x16x32_f16(a, b, acc, 0, 0, 0)

__device__ __forceinline__ u16 f16b(float v) {
  f16 h = (f16)v;
  return __builtin_bit_cast(u16, h);
}
__device__ __forceinline__ float f16lo(float v) {  // v - fp16(v)
  f16 h = (f16)v;
  return v - (float)h;
}

// ---------------- prep: A-fragments (split fp16) + twiddle tables ----------------
// swf: [layer4][strip4][kb2][hl2][lane64][8]
// awf: [strip4][t10][kc2][hl2][lane64][8]
// Tt : [hl2][w128][kk32] (kk>=16 -> 0)
// twf: [w128][k8] float2 (fwdW table, fp32)
__global__ __launch_bounds__(256) void k_prep2(const float* __restrict__ skip_w,
                                               const float* __restrict__ agg_w,
                                               u16* __restrict__ swf,
                                               u16* __restrict__ awf,
                                               u16* __restrict__ Tt,
                                               float2* __restrict__ twf) {
  int e = blockIdx.x*256 + threadIdx.x;
  if (e < 32768) {
    int j = e & 7, lane = (e >> 3) & 63, half = (e >> 9) & 1, ks = (e >> 10) & 1;
    int strip = (e >> 11) & 3, layer = e >> 13;
    int co = strip*16 + (lane & 15);
    int ci = ks*32 + (lane >> 4)*8 + j;
    float v = skip_w[((size_t)(layer*64) + co)*64 + ci];
    swf[e] = half ? f16b(f16lo(v)) : f16b(v);
  } else if (e < 32768 + 81920) {
    int ee = e - 32768;
    int j = ee & 7, lane = (ee >> 3) & 63;
    int v9 = ee >> 9;
    int half = v9 & 1; v9 >>= 1;
    int ks = v9 & 1; v9 >>= 1;
    int t = v9 % 10, strip = v9 / 10;
    int co = strip*16 + (lane & 15);
    int ci = ks*32 + (lane >> 4)*8 + j;
    float v = agg_w[((size_t)co*64 + ci)*10 + t];
    awf[ee] = half ? f16b(f16lo(v)) : f16b(v);
  } else if (e < 32768 + 81920 + 8192) {
    int ee = e - (32768 + 81920);
    int half = ee >> 12, r = ee & 4095, w = r >> 5, kk = r & 31;
    int m = kk >> 1;
    float val;
    if (kk >= 16) val = 0.f;
    else if (kk == 0) val = 1.f;
    else if (kk == 1) val = 0.f;
    else {
      float th = TWO_PI * (float)m * (float)w / 128.0f;
      val = (kk & 1) ? (-2.f*sinf(th)) : (2.f*cosf(th));
    }
    Tt[ee] = half ? f16b(f16lo(val)) : f16b(val);
  } else if (e < 32768 + 81920 + 8192 + 1024) {
    int ee = e - (32768 + 81920 + 8192);
    int w = ee >> 3, k = ee & 7;
    float th = TWO_PI * (float)k * (float)w / 128.0f;
    twf[ee] = make_float2(cosf(th), -sinf(th));
  }
}

// ---------------- lift (writes fp16 xT) ----------------
__global__ __launch_bounds__(128) void k_liftT(const float* __restrict__ frames,
                                               const float* __restrict__ times,
                                               const float* __restrict__ lift_w,
                                               const float* __restrict__ lift_b,
                                               u16* __restrict__ xT) {
  __shared__ float fr[128];
  __shared__ float lw0[64], lw1a[64];
  int bth = blockIdx.x;
  int h = bth & 127; int bt = bth >> 7; int t = bt % 10, b = bt / 10;
  int tid = threadIdx.x;
  float tv = times[b*10 + t];
  fr[tid] = frames[((size_t)(b*10 + t)*128 + h)*128 + tid];
  if (tid < 64) { lw0[tid] = lift_w[2*tid]; lw1a[tid] = lift_w[2*tid+1]*tv + lift_b[tid]; }
  __syncthreads();
  int w = tid;
  float f = fr[w];
  unsigned pk[32];
  #pragma unroll
  for (int q = 0; q < 32; ++q) {
    float v0 = f*lw0[2*q] + lw1a[2*q];
    float v1 = f*lw0[2*q+1] + lw1a[2*q+1];
    pk[q] = (unsigned)f16b(v0) | ((unsigned)f16b(v1) << 16);
  }
  uint4* d4 = (uint4*)(xT + (size_t)bth*8192 + w*64);
  #pragma unroll
  for (int q = 0; q < 8; ++q)
    d4[q] = make_uint4(pk[4*q], pk[4*q+1], pk[4*q+2], pk[4*q+3]);
}

// ---------------- forward W-stage from fp16 xT ----------------
__global__ __launch_bounds__(256) void k_fwdWT(const u16* __restrict__ xT,
                                               const float2* __restrict__ twf,
                                               float2* __restrict__ xw) {
  __shared__ float2 tw[128][8];
  int tid = threadIdx.x;
  for (int i = tid; i < 1024; i += 256) tw[i >> 3][i & 7] = twf[i];
  __syncthreads();
  int bth = blockIdx.x*4 + (tid >> 6);
  int lane = tid & 63;
  int h = bth & 127; int bt = bth >> 7; int t = bt % 10, b = bt / 10;
  const f16* src = (const f16*)xT + (size_t)bth*8192 + lane;
  float ar[8], ai[8];
  #pragma unroll
  for (int k = 0; k < 8; ++k) { ar[k] = 0.f; ai[k] = 0.f; }
  for (int w = 0; w < 128; ++w) {
    float xu = (float)src[w*64];
    ar[0] += xu;
    #pragma unroll
    for (int k = 1; k < 8; ++k) {
      float2 ew = tw[w][k];
      ar[k] += xu*ew.x; ai[k] += xu*ew.y;
    }
  }
  size_t row = ((size_t)(b*64 + lane)*10 + t)*128 + h;
  float4* dst = (float4*)(xw + row*8);
  #pragma unroll
  for (int q = 0; q < 4; ++q)
    dst[q] = make_float4(ar[2*q], ai[2*q], ar[2*q+1], ai[2*q+1]);
}

// ---------------- forward H-stage: 128h -> 16 modes ----------------
__global__ __launch_bounds__(128) void k_fwdH(const float2* __restrict__ xw,
                                              float2* __restrict__ xh) {
  __shared__ float2 tile[1024];
  int bct = blockIdx.x;
  const float2* src = xw + (size_t)bct*1024;
  for (int i = threadIdx.x; i < 1024; i += 128) tile[i] = src[i];
  __syncthreads();
  int j = threadIdx.x;
  int khi = j >> 3, kwi = j & 7;
  int kh = (khi < 8) ? khi : (112 + khi);
  float th = -TWO_PI * (float)kh / 128.0f;
  float c, s; sincosf(th, &s, &c);
  float tr = 1.f, ti = 0.f, accr = 0.f, acci = 0.f;
  for (int h = 0; h < 128; ++h) {
    float2 v = tile[h*8 + kwi];
    accr += v.x*tr - v.y*ti;
    acci += v.x*ti + v.y*tr;
    float nr = tr*c - ti*s; ti = tr*s + ti*c; tr = nr;
  }
  xh[(size_t)bct*128 + j] = make_float2(accr, acci);
}

// ---------------- forward T-stage ----------------
__global__ __launch_bounds__(256) void k_fwdT(const float2* __restrict__ xh,
                                              float2* __restrict__ xf) {
  int o = blockIdx.x*256 + threadIdx.x;
  int kmode = o & 127;
  int kti = (o >> 7) & 7;
  int c = (o >> 10) & 63;
  int b = o >> 16;
  int kt = (kti < 4) ? kti : (kti + 2);
  const float2* src = xh + (size_t)(b*64 + c)*1280 + kmode;
  float th = -TWO_PI * (float)kt / 10.0f;
  float cc, ss; sincosf(th, &ss, &cc);
  float tr = 1.f, ti = 0.f, accr = 0.f, acci = 0.f;
  #pragma unroll
  for (int t = 0; t < 10; ++t) {
    float2 v = src[t*128];
    accr += v.x*tr - v.y*ti;
    acci += v.x*ti + v.y*tr;
    float nr = tr*cc - ti*ss; ti = tr*ss + ti*cc; tr = nr;
  }
  xf[((size_t)b*1024 + kti*128 + kmode)*64 + c] = make_float2(accr*ORTHO_SC, acci*ORTHO_SC);
}

// ---------------- prep: transpose one layer's spec_w ----------------
__global__ __launch_bounds__(256) void k_prep_w(const float* __restrict__ spec_w_l,
                                                float2* __restrict__ wT) {
  __shared__ float2 tile[64][65];
  int blk = blockIdx.x;
  int mc = blk & 3, ci = (blk >> 2) & 63, q = blk >> 8;
  const float2* in = (const float2*)spec_w_l + (((size_t)q*64 + ci)*64)*256 + mc*64;
  for (int i = threadIdx.x; i < 4096; i += 256) {
    int co = i >> 6, mm = i & 63;
    tile[co][mm] = in[(size_t)co*256 + mm];
  }
  __syncthreads();
  float2* out = wT + ((size_t)q*256 + mc*64)*4096 + (size_t)ci*64;
  for (int i = threadIdx.x; i < 4096; i += 256) {
    int mm = i >> 6, co = i & 63;
    out[(size_t)mm*4096 + co] = tile[co][mm];
  }
}

// ---------------- channel mix ----------------
__global__ __launch_bounds__(256) void k_mix(const float2* __restrict__ xf,
                                             const float2* __restrict__ wTl,
                                             float2* __restrict__ yf) {
  __shared__ float2 xfs[8][4][64];
  int m0 = blockIdx.x * 4;
  for (int i = threadIdx.x; i < 2048; i += 256) {
    int bb = i >> 8, mi = (i >> 6) & 3, ci = i & 63;
    xfs[bb][mi][ci] = xf[((size_t)bb*1024 + m0 + mi)*64 + ci];
  }
  __syncthreads();
  int co = threadIdx.x & 63, mi = threadIdx.x >> 6;
  int m = m0 + mi;
  int kti = m >> 7, khi = (m >> 3) & 15, kwi = m & 7;
  int q = ((kti >= 4) ? 2 : 0) + ((khi >= 8) ? 1 : 0);
  int modeidx = ((kti & 3)*8 + (khi & 7))*8 + kwi;
  const float2* wp = wTl + ((size_t)q*256 + modeidx)*4096 + co;
  float accr[8], acci[8];
  #pragma unroll
  for (int bb = 0; bb < 8; ++bb) { accr[bb] = 0.f; acci[bb] = 0.f; }
  for (int ci = 0; ci < 64; ++ci) {
    float2 wv = wp[(size_t)ci*64];
    #pragma unroll
    for (int bb = 0; bb < 8; ++bb) {
      float2 xv = xfs[bb][mi][ci];
      accr[bb] += xv.x*wv.x - xv.y*wv.y;
      acci[bb] += xv.x*wv.y + xv.y*wv.x;
    }
  }
  #pragma unroll
  for (int bb = 0; bb < 8; ++bb)
    yf[((size_t)bb*64 + co)*1024 + m] = make_float2(accr[bb], acci[bb]);
}

// ---------------- inverse T-stage ----------------
__global__ __launch_bounds__(256) void k_invT(const float2* __restrict__ yf,
                                              float2* __restrict__ zt) {
  int o = blockIdx.x*256 + threadIdx.x;
  int kmode = o & 127;
  int t = (o >> 7) % 10;
  int bc = o / 1280;
  const float2* src = yf + (size_t)bc*1024 + kmode;
  float th = TWO_PI * (float)t / 10.0f;
  float cc, ss; sincosf(th, &ss, &cc);
  float tr = 1.f, ti = 0.f, accr = 0.f, acci = 0.f;
  #pragma unroll
  for (int k = 0; k < 10; ++k) {
    if (k < 4 || k >= 6) {
      int kti = (k < 4) ? k : (k - 2);
      float2 v = src[kti*128];
      accr += v.x*tr - v.y*ti;
      acci += v.x*ti + v.y*tr;
    }
    float nr = tr*cc - ti*ss; ti = tr*ss + ti*cc; tr = nr;
  }
  zt[o] = make_float2(accr*ORTHO_SC, acci*ORTHO_SC);
}

// ---------------- inverse H-stage ----------------
__global__ __launch_bounds__(256) void k_invH(const float2* __restrict__ zt,
                                              float2* __restrict__ zh) {
  __shared__ float2 zs[128];
  int bct = blockIdx.x;
  int t = bct % 10;
  int c = (bct / 10) & 63;
  int b = bct / 640;
  if (threadIdx.x < 128) zs[threadIdx.x] = zt[(size_t)bct*128 + threadIdx.x];
  __syncthreads();
  int h = threadIdx.x & 127;
  int half = threadIdx.x >> 7;
  float th = TWO_PI * (float)h / 128.0f;
  float cc, ss; sincosf(th, &ss, &cc);
  float pwr[9], pwi[9];
  pwr[0] = 1.f; pwi[0] = 0.f;
  #pragma unroll
  for (int k = 1; k < 9; ++k) {
    pwr[k] = pwr[k-1]*cc - pwi[k-1]*ss;
    pwi[k] = pwr[k-1]*ss + pwi[k-1]*cc;
  }
  float ar[4] = {0,0,0,0}, ai[4] = {0,0,0,0};
  #pragma unroll
  for (int khi = 0; khi < 16; ++khi) {
    float tr = (khi < 8) ? pwr[khi] : pwr[16-khi];
    float ti = (khi < 8) ? pwi[khi] : -pwi[16-khi];
    #pragma unroll
    for (int kk = 0; kk < 4; ++kk) {
      float2 v = zs[khi*8 + half*4 + kk];
      ar[kk] += v.x*tr - v.y*ti;
      ai[kk] += v.x*ti + v.y*tr;
    }
  }
  float2* dst = zh + ((((size_t)(b*10 + t)*128 + h)*64 + c)*8 + half*4);
  #pragma unroll
  for (int kk = 0; kk < 4; ++kk) dst[kk] = make_float2(ar[kk], ai[kk]);
}

// ---------------- fused inverse-W + skip as fp16 MFMA (exact B) ----------------
// block per (b,t,h); 256 thr = 4 waves; C[64co][128w].
// Wave wq owns w-quarter, all 64 co. B row [136]: 0..63 x, 64..95 Th, 96..127 Tl.
__global__ __launch_bounds__(256) void k_invW_mfma(const u16* __restrict__ xTin,
                                                   const float2* __restrict__ zh,
                                                   const u16* __restrict__ swf_l,
                                                   const u16* __restrict__ Tt,
                                                   const float* __restrict__ skb,
                                                   u16* __restrict__ xTo) {
  __shared__ __align__(16) char smem[38912];
  u16* B = (u16*)smem;              // [128][136]
  u16* zAh = (u16*)(smem + 34816);  // [64][16]
  u16* zAl = (u16*)(smem + 36864);  // [64][16]
  int tid = threadIdx.x;
  int bth = blockIdx.x;
  // stage x (copy, fp16 exact)
  {
    const uint4* xsrc = (const uint4*)(xTin + (size_t)bth*8192);
    for (int u = tid; u < 1024; u += 256) {
      int w = u >> 3, c = u & 7;
      ((uint4*)(B + w*136))[c] = xsrc[u];
    }
  }
  // stage T rows (hi at 64.., lo at 96..)
  if (tid < 256) {
    int w = tid >> 1, half = tid & 1;
    const uint4* sh = (const uint4*)(Tt + w*32 + half*16);
    const uint4* sl = (const uint4*)(Tt + 4096 + w*32 + half*16);
    uint4* dh = (uint4*)(B + w*136 + 64 + half*16);
    uint4* dl = (uint4*)(B + w*136 + 96 + half*16);
    dh[0] = sh[0]; dh[1] = sh[1];
    dl[0] = sl[0]; dl[1] = sl[1];
  }
  // stage z (split fp16 hi/lo)
  {
    const float2* zsrc = zh + (size_t)bth*512;
    for (int u = tid; u < 512; u += 256) {
      int co = u >> 3, m = u & 7;
      float2 v = zsrc[u];
      *(unsigned*)(zAh + co*16 + 2*m) =
          (unsigned)f16b(v.x) | ((unsigned)f16b(v.y) << 16);
      *(unsigned*)(zAl + co*16 + 2*m) =
          (unsigned)f16b(f16lo(v.x)) | ((unsigned)f16b(f16lo(v.y)) << 16);
    }
  }
  __syncthreads();

  int lane = tid & 63;
  int wq = tid >> 6;
  int cL = lane & 15;
  int g = lane >> 4;

  f32x4 acc[4][2];
  #pragma unroll
  for (int s = 0; s < 4; ++s)
    #pragma unroll
    for (int t2 = 0; t2 < 2; ++t2) acc[s][t2] = (f32x4){0.f,0.f,0.f,0.f};

  #pragma unroll
  for (int kb = 0; kb < 2; ++kb) {
    f16x8 Ah[4], Al[4];
    #pragma unroll
    for (int s = 0; s < 4; ++s) {
      Ah[s] = *(const f16x8*)(swf_l + (size_t)(s*2048 + kb*1024 + lane*8));
      Al[s] = *(const f16x8*)(swf_l + (size_t)(s*2048 + kb*1024 + 512 + lane*8));
    }
    #pragma unroll
    for (int t2 = 0; t2 < 2; ++t2) {
      int wrow = wq*32 + t2*16 + cL;
      f16x8 bh = *(const f16x8*)(B + wrow*136 + kb*32 + g*8);
      #pragma unroll
      for (int s = 0; s < 4; ++s) {
        MFMAH(acc[s][t2], Ah[s], bh);
        MFMAH(acc[s][t2], Al[s], bh);
      }
    }
  }
  // T block: out += z * T  (3-product split)
  {
    f16x8 Azh[4], Azl[4];
    f16x8 zero8 = {0,0,0,0,0,0,0,0};
    #pragma unroll
    for (int s = 0; s < 4; ++s) {
      if (g < 2) {
        Azh[s] = *(const f16x8*)(zAh + (s*16 + cL)*16 + g*8);
        Azl[s] = *(const f16x8*)(zAl + (s*16 + cL)*16 + g*8);
      } else { Azh[s] = zero8; Azl[s] = zero8; }
    }
    #pragma unroll
    for (int t2 = 0; t2 < 2; ++t2) {
      int wrow = wq*32 + t2*16 + cL;
      f16x8 th = *(const f16x8*)(B + wrow*136 + 64 + g*8);
      f16x8 tl = *(const f16x8*)(B + wrow*136 + 96 + g*8);
      #pragma unroll
      for (int s = 0; s < 4; ++s) {
        MFMAH(acc[s][t2], Azh[s], th);
        MFMAH(acc[s][t2], Azl[s], th);
        MFMAH(acc[s][t2], Azh[s], tl);
      }
    }
  }

  __syncthreads();
  unsigned* out32 = (unsigned*)smem;  // [32 co2][129 w]
  #pragma unroll
  for (int s = 0; s < 4; ++s) {
    float4 b4 = *(const float4*)(skb + s*16 + g*4);
    float bb[4] = {b4.x, b4.y, b4.z, b4.w};
    #pragma unroll
    for (int t2 = 0; t2 < 2; ++t2) {
      int w = wq*32 + t2*16 + cL;
      float ge[4];
      #pragma unroll
      for (int r = 0; r < 4; ++r) {
        float val = acc[s][t2][r] + bb[r];
        ge[r] = 0.5f*val*(1.0f + erff(val*0.70710678118654752f));
      }
      out32[(s*8 + g*2 + 0)*129 + w] = (unsigned)f16b(ge[0]) | ((unsigned)f16b(ge[1]) << 16);
      out32[(s*8 + g*2 + 1)*129 + w] = (unsigned)f16b(ge[2]) | ((unsigned)f16b(ge[3]) << 16);
    }
  }
  __syncthreads();
  {
    uint4* xdst = (uint4*)(xTo + (size_t)bth*8192);
    for (int u = tid; u < 1024; u += 256) {
      int w = u >> 3, c = u & 7;
      unsigned r0 = out32[(c*4 + 0)*129 + w];
      unsigned r1 = out32[(c*4 + 1)*129 + w];
      unsigned r2 = out32[(c*4 + 2)*129 + w];
      unsigned r3 = out32[(c*4 + 3)*129 + w];
      xdst[u] = make_uint4(r0, r1, r2, r3);
    }
  }
}

// ---------------- aggregation (K=640) as fp16 MFMA (exact B) ----------------
__global__ __launch_bounds__(256) void k_agg_mfma(const u16* __restrict__ xT,
                                                  const u16* __restrict__ awf,
                                                  const float* __restrict__ agg_b,
                                                  float* __restrict__ xa) {
  __shared__ __align__(16) char smem[36864];
  u16* B = (u16*)smem;              // [128][72]
  int tid = threadIdx.x;
  int bid = blockIdx.x;
  int h = bid & 127, b = bid >> 7;
  int lane = tid & 63;
  int wq = tid >> 6;
  int cL = lane & 15;
  int g = lane >> 4;

  f32x4 acc[4][2];
  #pragma unroll
  for (int s = 0; s < 4; ++s)
    #pragma unroll
    for (int t2 = 0; t2 < 2; ++t2) acc[s][t2] = (f32x4){0.f,0.f,0.f,0.f};

  for (int t = 0; t < 10; ++t) {
    __syncthreads();
    {
      const uint4* xsrc = (const uint4*)(xT + ((size_t)(b*10 + t)*128 + h)*8192);
      for (int u = tid; u < 1024; u += 256) {
        int w = u >> 3, c = u & 7;
        ((uint4*)(B + w*72))[c] = xsrc[u];
      }
    }
    __syncthreads();
    #pragma unroll
    for (int kc = 0; kc < 2; ++kc) {
      f16x8 Ah[4], Al[4];
      #pragma unroll
      for (int s = 0; s < 4; ++s) {
        const u16* af = awf + (size_t)((s*10 + t)*4 + kc*2)*512;
        Ah[s] = *(const f16x8*)(af + lane*8);
        Al[s] = *(const f16x8*)(af + 512 + lane*8);
      }
      #pragma unroll
      for (int t2 = 0; t2 < 2; ++t2) {
        int wrow = wq*32 + t2*16 + cL;
        f16x8 bh = *(const f16x8*)(B + wrow*72 + kc*32 + g*8);
        #pragma unroll
        for (int s = 0; s < 4; ++s) {
          MFMAH(acc[s][t2], Ah[s], bh);
          MFMAH(acc[s][t2], Al[s], bh);
        }
      }
    }
  }

  __syncthreads();
  float* outT = (float*)smem;  // [64][132]
  #pragma unroll
  for (int s = 0; s < 4; ++s) {
    float4 b4 = *(const float4*)(agg_b + s*16 + g*4);
    float bb[4] = {b4.x, b4.y, b4.z, b4.w};
    #pragma unroll
    for (int t2 = 0; t2 < 2; ++t2) {
      int w = wq*32 + t2*16 + cL;
      #pragma unroll
      for (int r = 0; r < 4; ++r) {
        int co = s*16 + g*4 + r;
        outT[co*132 + w] = acc[s][t2][r] + bb[r];
      }
    }
  }
  __syncthreads();
  for (int u = tid; u < 256; u += 256) {
    int co = u >> 2, c32 = u & 3;
    float* dst = xa + ((size_t)(b*64 + co)*128 + h)*128 + c32*32;
    #pragma unroll
    for (int q = 0; q < 8; ++q) {
      float4 vv = make_float4(outT[co*132 + c32*32 + 4*q],
                              outT[co*132 + c32*32 + 4*q + 1],
                              outT[co*132 + c32*32 + 4*q + 2],
                              outT[co*132 + c32*32 + 4*q + 3]);
      ((float4*)dst)[q] = vv;
    }
  }
}

// ---------------- MLP head (weights staged in LDS) ----------------
__global__ __launch_bounds__(128) void k_head(const float* __restrict__ xa,
                                              const float* __restrict__ fc1_w,
                                              const float* __restrict__ fc1_b,
                                              const float* __restrict__ fc2_w,
                                              const float* __restrict__ fc2_b,
                                              float* __restrict__ out) {
  __shared__ float w1[66*128];
  __shared__ float w2[128*10];
  __shared__ float b1s[128];
  __shared__ float b2s[16];
  int bid = blockIdx.x;
  int h = bid & 127, b = bid >> 7;
  int tid = threadIdx.x;
  for (int i = tid; i < 66*128; i += 128) w1[i] = fc1_w[i];
  for (int i = tid; i < 1280; i += 128) w2[i] = fc2_w[i];
  b1s[tid] = fc1_b[tid];
  if (tid < 10) b2s[tid] = fc2_b[tid];
  float v[64];
  #pragma unroll
  for (int c = 0; c < 64; ++c)
    v[c] = xa[((size_t)(b*64 + c)*128 + h)*128 + tid];
  __syncthreads();
  float gx = -1.f + 2.f*(float)tid/127.f;
  float gy = -1.f + 2.f*(float)h/127.f;
  float o2[10];
  #pragma unroll
  for (int j = 0; j < 10; ++j) o2[j] = b2s[j];
  for (int o = 0; o < 128; ++o) {
    float a = b1s[o];
    #pragma unroll
    for (int i = 0; i < 64; ++i) a += v[i]*w1[i*128 + o];
    a += gx*w1[64*128 + o] + gy*w1[65*128 + o];
    float g = 0.5f*a*(1.0f + erff(a*0.70710678118654752f));
    #pragma unroll
    for (int j = 0; j < 10; ++j) o2[j] += g*w2[o*10 + j];
  }
  float* dst = out + ((size_t)bid*128 + tid)*10;
  #pragma unroll
  for (int k = 0; k < 5; ++k) dst[k] = o2[2*k];
  #pragma unroll
  for (int k = 0; k < 5; ++k) {
    float sv = o2[2*k+1];
    float sp = fmaxf(sv, 0.f) + log1pf(expf(-fabsf(sv)));
    dst[5 + k] = sp + 1e-4f;
  }
}

extern "C" void kernel_launch(void* const* d_in, const int* in_sizes, int n_in,
                              void* d_out, int out_size, void* d_ws, size_t ws_size,
                              hipStream_t stream) {
  const float* frames = (const float*)d_in[0];
  const float* times  = (const float*)d_in[1];
  const float* lift_w = (const float*)d_in[2];
  const float* lift_b = (const float*)d_in[3];
  const float* spec_w = (const float*)d_in[4];
  const float* skip_w = (const float*)d_in[5];
  const float* skip_b = (const float*)d_in[6];
  const float* agg_w  = (const float*)d_in[7];
  const float* agg_b  = (const float*)d_in[8];
  const float* fc1_w  = (const float*)d_in[9];
  const float* fc1_b  = (const float*)d_in[10];
  const float* fc2_w  = (const float*)d_in[11];
  const float* fc2_b  = (const float*)d_in[12];
  float* out = (float*)d_out;
  char* ws = (char*)d_ws;

  size_t off = 0;
  u16*    xT  = (u16*)(ws + off);    off += (size_t)10240*8192*2;           // 167,772,160
  float2* xw  = (float2*)(ws + off); off += (size_t)8*64*10*128*8*8;        // 41,943,040
  float2* xh  = (float2*)(ws + off); off += (size_t)8*64*10*16*8*8;         // 5,242,880
  float2* xf  = (float2*)(ws + off); off += (size_t)8*1024*64*8;            // 4,194,304
  float2* yf  = (float2*)(ws + off); off += (size_t)8*1024*64*8;            // 4,194,304
  float*  xa  = (float*)(ws + off);  off += (size_t)8*64*128*128*4;         // 33,554,432
  float2* wT  = (float2*)(ws + off); off += (size_t)4*256*64*64*8;          // 33,554,432
  u16*    swf = (u16*)(ws + off);    off += (size_t)32768*2;                // 65,536
  u16*    awf = (u16*)(ws + off);    off += (size_t)81920*2;                // 163,840
  u16*    Tt  = (u16*)(ws + off);    off += (size_t)8192*2;                 // 16,384
  float2* twf = (float2*)(ws + off); off += (size_t)1024*8;                 // 8,192
  float2* zt = xh;
  float2* zh = xw;

  k_prep2<<<484, 256, 0, stream>>>(skip_w, agg_w, swf, awf, Tt, twf);
  k_liftT<<<10240, 128, 0, stream>>>(frames, times, lift_w, lift_b, xT);

  for (int l = 0; l < 4; ++l) {
    k_fwdWT<<<2560, 256, 0, stream>>>(xT, twf, (float2*)xw);
    k_fwdH<<<5120, 128, 0, stream>>>((const float2*)xw, xh);
    k_fwdT<<<2048, 256, 0, stream>>>(xh, xf);
    k_prep_w<<<1024, 256, 0, stream>>>(spec_w + (size_t)l*4*64*64*256*2, wT);
    k_mix<<<256, 256, 0, stream>>>(xf, wT, yf);
    k_invT<<<2560, 256, 0, stream>>>(yf, zt);
    k_invH<<<5120, 256, 0, stream>>>(zt, zh);
    k_invW_mfma<<<10240, 256, 0, stream>>>(xT, zh, swf + (size_t)l*8192, Tt,
                                           skip_b + l*64, xT);
  }
  k_agg_mfma<<<1024, 256, 0, stream>>>(xT, awf, agg_b, xa);
  k_head<<<1024, 128, 0, stream>>>(xa, fc1_w, fc1_b, fc2_w, fc2_b, out);
}

// Round 7
// 1186.190 us; speedup vs baseline: 3.2036x; 1.0833x over previous
//
#include <hip/hip_runtime.h>
#include <math.h>

// FNO3d forward. B=8,T=10,H=128,W=128, C=64, NL=4, modes kt8 kh16 kw8.
// x stored FP16, layout xT[(b*10+t)*128+h][w][ci].
// Round 7: fwdW-DFT fused into invW epilogue (layers 1-3); fwdH+fwdT fused;
// invT+invH fused; all-layer prep_w. zh no longer aliases xw.

#define TWO_PI 6.2831853071795864769f
#define ORTHO_SC 2.4705294220065465e-3f  // 1/sqrt(10*128*128)

typedef unsigned short u16;
typedef _Float16 f16;
typedef __attribute__((ext_vector_type(8))) _Float16 f16x8;
typedef __attribute__((ext_vector_type(4))) float f32x4;

#define MFMAH(acc, a, b) acc = __builtin_amdgcn_mfma_f32_16x16x32_f16(a, b, acc, 0, 0, 0)

__device__ __forceinline__ u16 f16b(float v) {
  f16 h = (f16)v;
  return __builtin_bit_cast(u16, h);
}
__device__ __forceinline__ float f16lo(float v) {  // v - fp16(v)
  f16 h = (f16)v;
  return v - (float)h;
}

// ---------------- prep: A-fragments (split fp16) + twiddle tables ----------------
// swf: [layer4][strip4][kb2][hl2][lane64][8]
// awf: [strip4][t10][kc2][hl2][lane64][8]
// Tt : [hl2][w128][kk32] (kk>=16 -> 0)   (inverse-W K-extension rows)
// twf: [w128][k8] float2 (fwdW fp32 table, layer-0 fwdWT)
// Ef : [hl2][kc4][lane64][8]  (fwdW DFT B-fragments, split fp16)
__global__ __launch_bounds__(256) void k_prep2(const float* __restrict__ skip_w,
                                               const float* __restrict__ agg_w,
                                               u16* __restrict__ swf,
                                               u16* __restrict__ awf,
                                               u16* __restrict__ Tt,
                                               float2* __restrict__ twf,
                                               u16* __restrict__ Ef) {
  int e = blockIdx.x*256 + threadIdx.x;
  if (e < 32768) {
    int j = e & 7, lane = (e >> 3) & 63, half = (e >> 9) & 1, ks = (e >> 10) & 1;
    int strip = (e >> 11) & 3, layer = e >> 13;
    int co = strip*16 + (lane & 15);
    int ci = ks*32 + (lane >> 4)*8 + j;
    float v = skip_w[((size_t)(layer*64) + co)*64 + ci];
    swf[e] = half ? f16b(f16lo(v)) : f16b(v);
  } else if (e < 114688) {
    int ee = e - 32768;
    int j = ee & 7, lane = (ee >> 3) & 63;
    int v9 = ee >> 9;
    int half = v9 & 1; v9 >>= 1;
    int ks = v9 & 1; v9 >>= 1;
    int t = v9 % 10, strip = v9 / 10;
    int co = strip*16 + (lane & 15);
    int ci = ks*32 + (lane >> 4)*8 + j;
    float v = agg_w[((size_t)co*64 + ci)*10 + t];
    awf[ee] = half ? f16b(f16lo(v)) : f16b(v);
  } else if (e < 122880) {
    int ee = e - 114688;
    int half = ee >> 12, r = ee & 4095, w = r >> 5, kk = r & 31;
    int m = kk >> 1;
    float val;
    if (kk >= 16) val = 0.f;
    else if (kk == 0) val = 1.f;
    else if (kk == 1) val = 0.f;
    else {
      float th = TWO_PI * (float)m * (float)w / 128.0f;
      val = (kk & 1) ? (-2.f*sinf(th)) : (2.f*cosf(th));
    }
    Tt[ee] = half ? f16b(f16lo(val)) : f16b(val);
  } else if (e < 123904) {
    int ee = e - 122880;
    int w = ee >> 3, k = ee & 7;
    float th = TWO_PI * (float)k * (float)w / 128.0f;
    twf[ee] = make_float2(cosf(th), -sinf(th));
  } else if (e < 125952) {
    int ee = e - 123904;
    int j = ee & 7, lane = (ee >> 3) & 63, kc = ee >> 9;
    int n = lane & 15, g = lane >> 4;
    int w = kc*32 + g*8 + j;
    int k = n >> 1;
    float th = TWO_PI * (float)k * (float)w / 128.0f;
    float val = (n & 1) ? (-sinf(th)) : cosf(th);
    Ef[ee] = f16b(val);
    Ef[2048 + ee] = f16b(f16lo(val));
  }
}

// ---------------- lift (writes fp16 xT) ----------------
__global__ __launch_bounds__(128) void k_liftT(const float* __restrict__ frames,
                                               const float* __restrict__ times,
                                               const float* __restrict__ lift_w,
                                               const float* __restrict__ lift_b,
                                               u16* __restrict__ xT) {
  __shared__ float fr[128];
  __shared__ float lw0[64], lw1a[64];
  int bth = blockIdx.x;
  int h = bth & 127; int bt = bth >> 7; int t = bt % 10, b = bt / 10;
  int tid = threadIdx.x;
  float tv = times[b*10 + t];
  fr[tid] = frames[((size_t)(b*10 + t)*128 + h)*128 + tid];
  if (tid < 64) { lw0[tid] = lift_w[2*tid]; lw1a[tid] = lift_w[2*tid+1]*tv + lift_b[tid]; }
  __syncthreads();
  int w = tid;
  float f = fr[w];
  unsigned pk[32];
  #pragma unroll
  for (int q = 0; q < 32; ++q) {
    float v0 = f*lw0[2*q] + lw1a[2*q];
    float v1 = f*lw0[2*q+1] + lw1a[2*q+1];
    pk[q] = (unsigned)f16b(v0) | ((unsigned)f16b(v1) << 16);
  }
  uint4* d4 = (uint4*)(xT + (size_t)bth*8192 + w*64);
  #pragma unroll
  for (int q = 0; q < 8; ++q)
    d4[q] = make_uint4(pk[4*q], pk[4*q+1], pk[4*q+2], pk[4*q+3]);
}

// ---------------- forward W-stage from fp16 xT (layer 0 only) ----------------
__global__ __launch_bounds__(256) void k_fwdWT(const u16* __restrict__ xT,
                                               const float2* __restrict__ twf,
                                               float2* __restrict__ xw) {
  __shared__ float2 tw[128][8];
  int tid = threadIdx.x;
  for (int i = tid; i < 1024; i += 256) tw[i >> 3][i & 7] = twf[i];
  __syncthreads();
  int bth = blockIdx.x*4 + (tid >> 6);
  int lane = tid & 63;
  int h = bth & 127; int bt = bth >> 7; int t = bt % 10, b = bt / 10;
  const f16* src = (const f16*)xT + (size_t)bth*8192 + lane;
  float ar[8], ai[8];
  #pragma unroll
  for (int k = 0; k < 8; ++k) { ar[k] = 0.f; ai[k] = 0.f; }
  for (int w = 0; w < 128; ++w) {
    float xu = (float)src[w*64];
    ar[0] += xu;
    #pragma unroll
    for (int k = 1; k < 8; ++k) {
      float2 ew = tw[w][k];
      ar[k] += xu*ew.x; ai[k] += xu*ew.y;
    }
  }
  size_t row = ((size_t)(b*64 + lane)*10 + t)*128 + h;
  float4* dst = (float4*)(xw + row*8);
  #pragma unroll
  for (int q = 0; q < 4; ++q)
    dst[q] = make_float4(ar[2*q], ai[2*q], ar[2*q+1], ai[2*q+1]);
}

// ---------------- fused forward H+T stages ----------------
// block per (b,c); 256 thr = 2 t-groups x 128 modes
__global__ __launch_bounds__(256) void k_fwdHT(const float2* __restrict__ xw,
                                               float2* __restrict__ xf) {
  __shared__ float2 tile[2][1024];   // 16 KB
  __shared__ float2 tw128[128];
  int bc = blockIdx.x;
  int b = bc >> 6, c = bc & 63;
  int tid = threadIdx.x;
  if (tid < 128) {
    float s, co; sincosf(TWO_PI * (float)tid / 128.0f, &s, &co);
    tw128[tid] = make_float2(co, -s);   // e^{-2pi i tid/128}
  }
  int tpar = tid >> 7, j = tid & 127;
  int khi = j >> 3, kwi = j & 7;
  int kh = (khi < 8) ? khi : (112 + khi);
  float accr[8], acci[8];
  #pragma unroll
  for (int k = 0; k < 8; ++k) { accr[k] = 0.f; acci[k] = 0.f; }
  for (int tt = 0; tt < 5; ++tt) {
    __syncthreads();
    for (int u = tid; u < 2048; u += 256) {
      int tg = u >> 10, idx = u & 1023;
      tile[tg][idx] = xw[((size_t)bc*10 + tg*5 + tt)*1024 + idx];
    }
    __syncthreads();
    float xr = 0.f, xi = 0.f;
    for (int h = 0; h < 128; ++h) {
      float2 v = tile[tpar][h*8 + kwi];
      float2 tw = tw128[(h*kh) & 127];
      xr += v.x*tw.x - v.y*tw.y;
      xi += v.x*tw.y + v.y*tw.x;
    }
    int t = tpar*5 + tt;
    float sb, cb; sincosf(TWO_PI * (float)t / 10.0f, &sb, &cb);
    float p_r[10], p_i[10];   // powers of e^{-2pi i t/10}
    p_r[0] = 1.f; p_i[0] = 0.f; p_r[1] = cb; p_i[1] = -sb;
    #pragma unroll
    for (int k = 2; k < 10; ++k) {
      p_r[k] = p_r[k-1]*p_r[1] - p_i[k-1]*p_i[1];
      p_i[k] = p_r[k-1]*p_i[1] + p_i[k-1]*p_r[1];
    }
    #pragma unroll
    for (int kti = 0; kti < 8; ++kti) {
      int kt = (kti < 4) ? kti : kti + 2;
      accr[kti] += xr*p_r[kt] - xi*p_i[kt];
      acci[kti] += xr*p_i[kt] + xi*p_r[kt];
    }
  }
  __syncthreads();
  float2* parts = &tile[0][0];
  #pragma unroll
  for (int kti = 0; kti < 8; ++kti)
    parts[tpar*1024 + j*8 + kti] = make_float2(accr[kti], acci[kti]);
  __syncthreads();
  if (tpar == 0) {
    #pragma unroll
    for (int kti = 0; kti < 8; ++kti) {
      float2 a = parts[j*8 + kti], bq = parts[1024 + j*8 + kti];
      xf[((size_t)b*1024 + kti*128 + j)*64 + c] =
          make_float2((a.x + bq.x)*ORTHO_SC, (a.y + bq.y)*ORTHO_SC);
    }
  }
}

// ---------------- prep: transpose ALL layers' spec_w ----------------
__global__ __launch_bounds__(256) void k_prep_w4(const float* __restrict__ spec_w,
                                                 float2* __restrict__ wT4) {
  __shared__ float2 tile[64][65];
  int blk = blockIdx.x;
  int l = blk >> 10;
  int inner = blk & 1023;
  int mc = inner & 3, ci = (inner >> 2) & 63, q = inner >> 8;
  const float2* in = (const float2*)spec_w + (size_t)l*4194304
                     + (((size_t)q*64 + ci)*64)*256 + mc*64;
  for (int i = threadIdx.x; i < 4096; i += 256) {
    int co = i >> 6, mm = i & 63;
    tile[co][mm] = in[(size_t)co*256 + mm];
  }
  __syncthreads();
  float2* out = wT4 + (size_t)l*4194304 + ((size_t)q*256 + mc*64)*4096 + (size_t)ci*64;
  for (int i = threadIdx.x; i < 4096; i += 256) {
    int mm = i >> 6, co = i & 63;
    out[(size_t)mm*4096 + co] = tile[co][mm];
  }
}

// ---------------- channel mix ----------------
__global__ __launch_bounds__(256) void k_mix(const float2* __restrict__ xf,
                                             const float2* __restrict__ wTl,
                                             float2* __restrict__ yf) {
  __shared__ float2 xfs[8][4][64];
  int m0 = blockIdx.x * 4;
  for (int i = threadIdx.x; i < 2048; i += 256) {
    int bb = i >> 8, mi = (i >> 6) & 3, ci = i & 63;
    xfs[bb][mi][ci] = xf[((size_t)bb*1024 + m0 + mi)*64 + ci];
  }
  __syncthreads();
  int co = threadIdx.x & 63, mi = threadIdx.x >> 6;
  int m = m0 + mi;
  int kti = m >> 7, khi = (m >> 3) & 15, kwi = m & 7;
  int q = ((kti >= 4) ? 2 : 0) + ((khi >= 8) ? 1 : 0);
  int modeidx = ((kti & 3)*8 + (khi & 7))*8 + kwi;
  const float2* wp = wTl + ((size_t)q*256 + modeidx)*4096 + co;
  float accr[8], acci[8];
  #pragma unroll
  for (int bb = 0; bb < 8; ++bb) { accr[bb] = 0.f; acci[bb] = 0.f; }
  for (int ci = 0; ci < 64; ++ci) {
    float2 wv = wp[(size_t)ci*64];
    #pragma unroll
    for (int bb = 0; bb < 8; ++bb) {
      float2 xv = xfs[bb][mi][ci];
      accr[bb] += xv.x*wv.x - xv.y*wv.y;
      acci[bb] += xv.x*wv.y + xv.y*wv.x;
    }
  }
  #pragma unroll
  for (int bb = 0; bb < 8; ++bb)
    yf[((size_t)bb*64 + co)*1024 + m] = make_float2(accr[bb], acci[bb]);
}

// ---------------- fused inverse T+H stages ----------------
// block per (b,c); 256 thr = 2 t-par x 128
__global__ __launch_bounds__(256) void k_invTH(const float2* __restrict__ yf,
                                               float2* __restrict__ zh) {
  __shared__ float2 ybuf[1024];      // 8 KB
  __shared__ float2 ztb[2][128];
  __shared__ float2 tw128[128];
  int bc = blockIdx.x;
  int b = bc >> 6, c = bc & 63;
  int tid = threadIdx.x;
  for (int u = tid; u < 1024; u += 256) ybuf[u] = yf[(size_t)bc*1024 + u];
  if (tid < 128) {
    float s, co; sincosf(TWO_PI * (float)tid / 128.0f, &s, &co);
    tw128[tid] = make_float2(co, s);   // e^{+2pi i tid/128}
  }
  int tpar = tid >> 7, j = tid & 127;
  __syncthreads();
  for (int tt = 0; tt < 5; ++tt) {
    int t = tt*2 + tpar;
    {
      float sb, cb; sincosf(TWO_PI * (float)t / 10.0f, &sb, &cb);
      float p_r[10], p_i[10];   // powers of e^{+2pi i t/10}
      p_r[0] = 1.f; p_i[0] = 0.f; p_r[1] = cb; p_i[1] = sb;
      #pragma unroll
      for (int k = 2; k < 10; ++k) {
        p_r[k] = p_r[k-1]*p_r[1] - p_i[k-1]*p_i[1];
        p_i[k] = p_r[k-1]*p_i[1] + p_i[k-1]*p_r[1];
      }
      float zr = 0.f, zi = 0.f;
      #pragma unroll
      for (int kti = 0; kti < 8; ++kti) {
        int kt = (kti < 4) ? kti : kti + 2;
        float2 v = ybuf[kti*128 + j];
        zr += v.x*p_r[kt] - v.y*p_i[kt];
        zi += v.x*p_i[kt] + v.y*p_r[kt];
      }
      ztb[tpar][j] = make_float2(zr*ORTHO_SC, zi*ORTHO_SC);
    }
    __syncthreads();
    {
      int h = j;
      float ar[8], ai[8];
      #pragma unroll
      for (int kw = 0; kw < 8; ++kw) { ar[kw] = 0.f; ai[kw] = 0.f; }
      #pragma unroll
      for (int khi = 0; khi < 16; ++khi) {
        int kh = (khi < 8) ? khi : (112 + khi);
        float2 tw = tw128[(h*kh) & 127];
        #pragma unroll
        for (int kw = 0; kw < 8; ++kw) {
          float2 v = ztb[tpar][khi*8 + kw];
          ar[kw] += v.x*tw.x - v.y*tw.y;
          ai[kw] += v.x*tw.y + v.y*tw.x;
        }
      }
      float2* dst = zh + (((size_t)(b*10 + t)*128 + h)*64 + c)*8;
      #pragma unroll
      for (int kw = 0; kw < 8; ++kw) dst[kw] = make_float2(ar[kw], ai[kw]);
    }
    __syncthreads();
  }
}

// ---------------- fused inverse-W + skip + GELU (+ next-layer fwdW DFT) ----------------
// block per (b,t,h); 256 thr = 4 waves; wave wq owns w-quarter, all 64 co.
__global__ __launch_bounds__(256) void k_invW_mfma(const u16* __restrict__ xTin,
                                                   const float2* __restrict__ zh,
                                                   const u16* __restrict__ swf_l,
                                                   const u16* __restrict__ Tt,
                                                   const u16* __restrict__ Ef,
                                                   const float* __restrict__ skb,
                                                   u16* __restrict__ xTo,
                                                   float* __restrict__ xw,
                                                   int do_dft) {
  __shared__ __align__(16) char smem[38912];
  u16* B = (u16*)smem;              // [128][136]
  u16* zAh = (u16*)(smem + 34816);  // [64][16]
  u16* zAl = (u16*)(smem + 36864);  // [64][16]
  int tid = threadIdx.x;
  int bth = blockIdx.x;
  {
    const uint4* xsrc = (const uint4*)(xTin + (size_t)bth*8192);
    for (int u = tid; u < 1024; u += 256) {
      int w = u >> 3, c = u & 7;
      ((uint4*)(B + w*136))[c] = xsrc[u];
    }
  }
  if (tid < 256) {
    int w = tid >> 1, half = tid & 1;
    const uint4* sh = (const uint4*)(Tt + w*32 + half*16);
    const uint4* sl = (const uint4*)(Tt + 4096 + w*32 + half*16);
    uint4* dh = (uint4*)(B + w*136 + 64 + half*16);
    uint4* dl = (uint4*)(B + w*136 + 96 + half*16);
    dh[0] = sh[0]; dh[1] = sh[1];
    dl[0] = sl[0]; dl[1] = sl[1];
  }
  {
    const float2* zsrc = zh + (size_t)bth*512;
    for (int u = tid; u < 512; u += 256) {
      int co = u >> 3, m = u & 7;
      float2 v = zsrc[u];
      *(unsigned*)(zAh + co*16 + 2*m) =
          (unsigned)f16b(v.x) | ((unsigned)f16b(v.y) << 16);
      *(unsigned*)(zAl + co*16 + 2*m) =
          (unsigned)f16b(f16lo(v.x)) | ((unsigned)f16b(f16lo(v.y)) << 16);
    }
  }
  __syncthreads();

  int lane = tid & 63;
  int wq = tid >> 6;
  int cL = lane & 15;
  int g = lane >> 4;

  f32x4 acc[4][2];
  #pragma unroll
  for (int s = 0; s < 4; ++s)
    #pragma unroll
    for (int t2 = 0; t2 < 2; ++t2) acc[s][t2] = (f32x4){0.f,0.f,0.f,0.f};

  #pragma unroll
  for (int kb = 0; kb < 2; ++kb) {
    f16x8 Ah[4], Al[4];
    #pragma unroll
    for (int s = 0; s < 4; ++s) {
      Ah[s] = *(const f16x8*)(swf_l + (size_t)(s*2048 + kb*1024 + lane*8));
      Al[s] = *(const f16x8*)(swf_l + (size_t)(s*2048 + kb*1024 + 512 + lane*8));
    }
    #pragma unroll
    for (int t2 = 0; t2 < 2; ++t2) {
      int wrow = wq*32 + t2*16 + cL;
      f16x8 bh = *(const f16x8*)(B + wrow*136 + kb*32 + g*8);
      #pragma unroll
      for (int s = 0; s < 4; ++s) {
        MFMAH(acc[s][t2], Ah[s], bh);
        MFMAH(acc[s][t2], Al[s], bh);
      }
    }
  }
  {
    f16x8 Azh[4], Azl[4];
    f16x8 zero8 = {0,0,0,0,0,0,0,0};
    #pragma unroll
    for (int s = 0; s < 4; ++s) {
      if (g < 2) {
        Azh[s] = *(const f16x8*)(zAh + (s*16 + cL)*16 + g*8);
        Azl[s] = *(const f16x8*)(zAl + (s*16 + cL)*16 + g*8);
      } else { Azh[s] = zero8; Azl[s] = zero8; }
    }
    #pragma unroll
    for (int t2 = 0; t2 < 2; ++t2) {
      int wrow = wq*32 + t2*16 + cL;
      f16x8 th = *(const f16x8*)(B + wrow*136 + 64 + g*8);
      f16x8 tl = *(const f16x8*)(B + wrow*136 + 96 + g*8);
      #pragma unroll
      for (int s = 0; s < 4; ++s) {
        MFMAH(acc[s][t2], Azh[s], th);
        MFMAH(acc[s][t2], Azl[s], th);
        MFMAH(acc[s][t2], Azh[s], tl);
      }
    }
  }

  __syncthreads();
  unsigned* out32 = (unsigned*)smem;           // [32][129] u32 (16512 B)
  u16* xg_a = (u16*)(smem + 16512);            // [64][136] u16 (17408 B)
  #pragma unroll
  for (int s = 0; s < 4; ++s) {
    float4 b4 = *(const float4*)(skb + s*16 + g*4);
    float bb[4] = {b4.x, b4.y, b4.z, b4.w};
    #pragma unroll
    for (int t2 = 0; t2 < 2; ++t2) {
      int w = wq*32 + t2*16 + cL;
      float ge[4];
      u16 gb[4];
      #pragma unroll
      for (int r = 0; r < 4; ++r) {
        float val = acc[s][t2][r] + bb[r];
        ge[r] = 0.5f*val*(1.0f + erff(val*0.70710678118654752f));
        gb[r] = f16b(ge[r]);
      }
      out32[(s*8 + g*2 + 0)*129 + w] = (unsigned)gb[0] | ((unsigned)gb[1] << 16);
      out32[(s*8 + g*2 + 1)*129 + w] = (unsigned)gb[2] | ((unsigned)gb[3] << 16);
      if (do_dft) {
        #pragma unroll
        for (int r = 0; r < 4; ++r)
          xg_a[(s*16 + g*4 + r)*136 + w] = gb[r];
      }
    }
  }
  __syncthreads();
  {
    uint4* xdst = (uint4*)(xTo + (size_t)bth*8192);
    for (int u = tid; u < 1024; u += 256) {
      int w = u >> 3, c = u & 7;
      unsigned r0 = out32[(c*4 + 0)*129 + w];
      unsigned r1 = out32[(c*4 + 1)*129 + w];
      unsigned r2 = out32[(c*4 + 2)*129 + w];
      unsigned r3 = out32[(c*4 + 3)*129 + w];
      xdst[u] = make_uint4(r0, r1, r2, r3);
    }
  }
  if (do_dft) {
    f32x4 acc2 = (f32x4){0.f,0.f,0.f,0.f};
    #pragma unroll
    for (int kc = 0; kc < 4; ++kc) {
      f16x8 a = *(const f16x8*)(xg_a + (wq*16 + cL)*136 + kc*32 + g*8);
      f16x8 eh = *(const f16x8*)(Ef + (kc*64 + lane)*8);
      f16x8 el = *(const f16x8*)(Ef + 2048 + (kc*64 + lane)*8);
      MFMAH(acc2, a, eh);
      MFMAH(acc2, a, el);
    }
    int h = bth & 127; int bt = bth >> 7; int t = bt % 10, b = bt / 10;
    #pragma unroll
    for (int r = 0; r < 4; ++r) {
      int co = wq*16 + g*4 + r;
      size_t row = ((size_t)(b*64 + co)*10 + t)*128 + h;
      xw[row*16 + cL] = acc2[r];
    }
  }
}

// ---------------- aggregation (K=640) as fp16 MFMA (exact B) ----------------
__global__ __launch_bounds__(256) void k_agg_mfma(const u16* __restrict__ xT,
                                                  const u16* __restrict__ awf,
                                                  const float* __restrict__ agg_b,
                                                  float* __restrict__ xa) {
  __shared__ __align__(16) char smem[36864];
  u16* B = (u16*)smem;              // [128][72]
  int tid = threadIdx.x;
  int bid = blockIdx.x;
  int h = bid & 127, b = bid >> 7;
  int lane = tid & 63;
  int wq = tid >> 6;
  int cL = lane & 15;
  int g = lane >> 4;

  f32x4 acc[4][2];
  #pragma unroll
  for (int s = 0; s < 4; ++s)
    #pragma unroll
    for (int t2 = 0; t2 < 2; ++t2) acc[s][t2] = (f32x4){0.f,0.f,0.f,0.f};

  for (int t = 0; t < 10; ++t) {
    __syncthreads();
    {
      const uint4* xsrc = (const uint4*)(xT + ((size_t)(b*10 + t)*128 + h)*8192);
      for (int u = tid; u < 1024; u += 256) {
        int w = u >> 3, c = u & 7;
        ((uint4*)(B + w*72))[c] = xsrc[u];
      }
    }
    __syncthreads();
    #pragma unroll
    for (int kc = 0; kc < 2; ++kc) {
      f16x8 Ah[4], Al[4];
      #pragma unroll
      for (int s = 0; s < 4; ++s) {
        const u16* af = awf + (size_t)((s*10 + t)*4 + kc*2)*512;
        Ah[s] = *(const f16x8*)(af + lane*8);
        Al[s] = *(const f16x8*)(af + 512 + lane*8);
      }
      #pragma unroll
      for (int t2 = 0; t2 < 2; ++t2) {
        int wrow = wq*32 + t2*16 + cL;
        f16x8 bh = *(const f16x8*)(B + wrow*72 + kc*32 + g*8);
        #pragma unroll
        for (int s = 0; s < 4; ++s) {
          MFMAH(acc[s][t2], Ah[s], bh);
          MFMAH(acc[s][t2], Al[s], bh);
        }
      }
    }
  }

  __syncthreads();
  float* outT = (float*)smem;  // [64][132]
  #pragma unroll
  for (int s = 0; s < 4; ++s) {
    float4 b4 = *(const float4*)(agg_b + s*16 + g*4);
    float bb[4] = {b4.x, b4.y, b4.z, b4.w};
    #pragma unroll
    for (int t2 = 0; t2 < 2; ++t2) {
      int w = wq*32 + t2*16 + cL;
      #pragma unroll
      for (int r = 0; r < 4; ++r) {
        int co = s*16 + g*4 + r;
        outT[co*132 + w] = acc[s][t2][r] + bb[r];
      }
    }
  }
  __syncthreads();
  for (int u = tid; u < 256; u += 256) {
    int co = u >> 2, c32 = u & 3;
    float* dst = xa + ((size_t)(b*64 + co)*128 + h)*128 + c32*32;
    #pragma unroll
    for (int q = 0; q < 8; ++q) {
      float4 vv = make_float4(outT[co*132 + c32*32 + 4*q],
                              outT[co*132 + c32*32 + 4*q + 1],
                              outT[co*132 + c32*32 + 4*q + 2],
                              outT[co*132 + c32*32 + 4*q + 3]);
      ((float4*)dst)[q] = vv;
    }
  }
}

// ---------------- MLP head (weights staged in LDS) ----------------
__global__ __launch_bounds__(128) void k_head(const float* __restrict__ xa,
                                              const float* __restrict__ fc1_w,
                                              const float* __restrict__ fc1_b,
                                              const float* __restrict__ fc2_w,
                                              const float* __restrict__ fc2_b,
                                              float* __restrict__ out) {
  __shared__ float w1[66*128];
  __shared__ float w2[128*10];
  __shared__ float b1s[128];
  __shared__ float b2s[16];
  int bid = blockIdx.x;
  int h = bid & 127, b = bid >> 7;
  int tid = threadIdx.x;
  for (int i = tid; i < 66*128; i += 128) w1[i] = fc1_w[i];
  for (int i = tid; i < 1280; i += 128) w2[i] = fc2_w[i];
  b1s[tid] = fc1_b[tid];
  if (tid < 10) b2s[tid] = fc2_b[tid];
  float v[64];
  #pragma unroll
  for (int c = 0; c < 64; ++c)
    v[c] = xa[((size_t)(b*64 + c)*128 + h)*128 + tid];
  __syncthreads();
  float gx = -1.f + 2.f*(float)tid/127.f;
  float gy = -1.f + 2.f*(float)h/127.f;
  float o2[10];
  #pragma unroll
  for (int j = 0; j < 10; ++j) o2[j] = b2s[j];
  for (int o = 0; o < 128; ++o) {
    float a = b1s[o];
    #pragma unroll
    for (int i = 0; i < 64; ++i) a += v[i]*w1[i*128 + o];
    a += gx*w1[64*128 + o] + gy*w1[65*128 + o];
    float g = 0.5f*a*(1.0f + erff(a*0.70710678118654752f));
    #pragma unroll
    for (int j = 0; j < 10; ++j) o2[j] += g*w2[o*10 + j];
  }
  float* dst = out + ((size_t)bid*128 + tid)*10;
  #pragma unroll
  for (int k = 0; k < 5; ++k) dst[k] = o2[2*k];
  #pragma unroll
  for (int k = 0; k < 5; ++k) {
    float sv = o2[2*k+1];
    float sp = fmaxf(sv, 0.f) + log1pf(expf(-fabsf(sv)));
    dst[5 + k] = sp + 1e-4f;
  }
}

extern "C" void kernel_launch(void* const* d_in, const int* in_sizes, int n_in,
                              void* d_out, int out_size, void* d_ws, size_t ws_size,
                              hipStream_t stream) {
  const float* frames = (const float*)d_in[0];
  const float* times  = (const float*)d_in[1];
  const float* lift_w = (const float*)d_in[2];
  const float* lift_b = (const float*)d_in[3];
  const float* spec_w = (const float*)d_in[4];
  const float* skip_w = (const float*)d_in[5];
  const float* skip_b = (const float*)d_in[6];
  const float* agg_w  = (const float*)d_in[7];
  const float* agg_b  = (const float*)d_in[8];
  const float* fc1_w  = (const float*)d_in[9];
  const float* fc1_b  = (const float*)d_in[10];
  const float* fc2_w  = (const float*)d_in[11];
  const float* fc2_b  = (const float*)d_in[12];
  float* out = (float*)d_out;
  char* ws = (char*)d_ws;

  size_t off = 0;
  u16*    xT  = (u16*)(ws + off);    off += (size_t)10240*8192*2;           // 167,772,160
  float*  xw  = (float*)(ws + off);  off += (size_t)655360*16*4;            // 41,943,040
  float2* xf  = (float2*)(ws + off); off += (size_t)8*1024*64*8;            // 4,194,304
  float2* yf  = (float2*)(ws + off); off += (size_t)8*1024*64*8;            // 4,194,304
  float2* zh  = (float2*)(ws + off); off += (size_t)10240*512*8;            // 41,943,040
  float*  xa  = (float*)(ws + off);  off += (size_t)8*64*128*128*4;         // 33,554,432
  float2* wT4 = (float2*)(ws + off); off += (size_t)4*4194304*8;            // 134,217,728
  u16*    swf = (u16*)(ws + off);    off += (size_t)32768*2;                // 65,536
  u16*    awf = (u16*)(ws + off);    off += (size_t)81920*2;                // 163,840
  u16*    Tt  = (u16*)(ws + off);    off += (size_t)8192*2;                 // 16,384
  float2* twf = (float2*)(ws + off); off += (size_t)1024*8;                 // 8,192
  u16*    Ef  = (u16*)(ws + off);    off += (size_t)4096*2;                 // 8,192

  k_prep2<<<492, 256, 0, stream>>>(skip_w, agg_w, swf, awf, Tt, twf, Ef);
  k_prep_w4<<<4096, 256, 0, stream>>>(spec_w, wT4);
  k_liftT<<<10240, 128, 0, stream>>>(frames, times, lift_w, lift_b, xT);
  k_fwdWT<<<2560, 256, 0, stream>>>(xT, twf, (float2*)xw);

  for (int l = 0; l < 4; ++l) {
    k_fwdHT<<<512, 256, 0, stream>>>((const float2*)xw, xf);
    k_mix<<<256, 256, 0, stream>>>(xf, wT4 + (size_t)l*4194304, yf);
    k_invTH<<<512, 256, 0, stream>>>(yf, zh);
    k_invW_mfma<<<10240, 256, 0, stream>>>(xT, zh, swf + (size_t)l*8192, Tt, Ef,
                                           skip_b + l*64, xT, xw, (l < 3) ? 1 : 0);
  }
  k_agg_mfma<<<1024, 256, 0, stream>>>(xT, awf, agg_b, xa);
  k_head<<<1024, 128, 0, stream>>>(xa, fc1_w, fc1_b, fc2_w, fc2_b, out);
}

// Round 8
// 1131.577 us; speedup vs baseline: 3.3582x; 1.0483x over previous
//
#include <hip/hip_runtime.h>
#include <math.h>

// FNO3d forward. B=8,T=10,H=128,W=128, C=64, NL=4, modes kt8 kh16 kw8.
// x stored FP16, layout xT[(b*10+t)*128+h][w][ci].
// Round 8: zh packed fp16 (drops Azl MFMAs + staging VALU in invW);
// lift fused with layer-0 fwdW DFT.

#define TWO_PI 6.2831853071795864769f
#define ORTHO_SC 2.4705294220065465e-3f  // 1/sqrt(10*128*128)

typedef unsigned short u16;
typedef _Float16 f16;
typedef __attribute__((ext_vector_type(8))) _Float16 f16x8;
typedef __attribute__((ext_vector_type(4))) float f32x4;

#define MFMAH(acc, a, b) acc = __builtin_amdgcn_mfma_f32_16x16x32_f16(a, b, acc, 0, 0, 0)

__device__ __forceinline__ u16 f16b(float v) {
  f16 h = (f16)v;
  return __builtin_bit_cast(u16, h);
}
__device__ __forceinline__ float f16lo(float v) {  // v - fp16(v)
  f16 h = (f16)v;
  return v - (float)h;
}
__device__ __forceinline__ float f16f(u16 b) {
  return (float)__builtin_bit_cast(f16, b);
}

// ---------------- prep: A-fragments (split fp16) + twiddle tables ----------------
// swf: [layer4][strip4][kb2][hl2][lane64][8]
// awf: [strip4][t10][kc2][hl2][lane64][8]
// Tt : [hl2][w128][kk32] (kk>=16 -> 0)   (inverse-W K-extension rows)
// twf: [w128][k8] float2 (fwdW fp32 table)
// Ef : [hl2][kc4][lane64][8]  (fwdW DFT B-fragments, split fp16)
__global__ __launch_bounds__(256) void k_prep2(const float* __restrict__ skip_w,
                                               const float* __restrict__ agg_w,
                                               u16* __restrict__ swf,
                                               u16* __restrict__ awf,
                                               u16* __restrict__ Tt,
                                               float2* __restrict__ twf,
                                               u16* __restrict__ Ef) {
  int e = blockIdx.x*256 + threadIdx.x;
  if (e < 32768) {
    int j = e & 7, lane = (e >> 3) & 63, half = (e >> 9) & 1, ks = (e >> 10) & 1;
    int strip = (e >> 11) & 3, layer = e >> 13;
    int co = strip*16 + (lane & 15);
    int ci = ks*32 + (lane >> 4)*8 + j;
    float v = skip_w[((size_t)(layer*64) + co)*64 + ci];
    swf[e] = half ? f16b(f16lo(v)) : f16b(v);
  } else if (e < 114688) {
    int ee = e - 32768;
    int j = ee & 7, lane = (ee >> 3) & 63;
    int v9 = ee >> 9;
    int half = v9 & 1; v9 >>= 1;
    int ks = v9 & 1; v9 >>= 1;
    int t = v9 % 10, strip = v9 / 10;
    int co = strip*16 + (lane & 15);
    int ci = ks*32 + (lane >> 4)*8 + j;
    float v = agg_w[((size_t)co*64 + ci)*10 + t];
    awf[ee] = half ? f16b(f16lo(v)) : f16b(v);
  } else if (e < 122880) {
    int ee = e - 114688;
    int half = ee >> 12, r = ee & 4095, w = r >> 5, kk = r & 31;
    int m = kk >> 1;
    float val;
    if (kk >= 16) val = 0.f;
    else if (kk == 0) val = 1.f;
    else if (kk == 1) val = 0.f;
    else {
      float th = TWO_PI * (float)m * (float)w / 128.0f;
      val = (kk & 1) ? (-2.f*sinf(th)) : (2.f*cosf(th));
    }
    Tt[ee] = half ? f16b(f16lo(val)) : f16b(val);
  } else if (e < 123904) {
    int ee = e - 122880;
    int w = ee >> 3, k = ee & 7;
    float th = TWO_PI * (float)k * (float)w / 128.0f;
    twf[ee] = make_float2(cosf(th), -sinf(th));
  } else if (e < 125952) {
    int ee = e - 123904;
    int j = ee & 7, lane = (ee >> 3) & 63, kc = ee >> 9;
    int n = lane & 15, g = lane >> 4;
    int w = kc*32 + g*8 + j;
    int k = n >> 1;
    float th = TWO_PI * (float)k * (float)w / 128.0f;
    float val = (n & 1) ? (-sinf(th)) : cosf(th);
    Ef[ee] = f16b(val);
    Ef[2048 + ee] = f16b(f16lo(val));
  }
}

// ---------------- fused lift + layer-0 forward-W DFT ----------------
// block per bth; 128 threads (2 waves). Lift phase: thread=w. DFT phase:
// lane=ci, wave wv handles modes wv*4..wv*4+3 over all 128 w from LDS.
__global__ __launch_bounds__(128) void k_lift_fwdW(const float* __restrict__ frames,
                                                   const float* __restrict__ times,
                                                   const float* __restrict__ lift_w,
                                                   const float* __restrict__ lift_b,
                                                   const float2* __restrict__ twf,
                                                   u16* __restrict__ xT,
                                                   float* __restrict__ xw) {
  __shared__ u16 xs[64][130];        // [ci][w] fp16, stride 130 (65 dwords, odd)
  __shared__ float2 tws[128][8];
  __shared__ float fr[128];
  __shared__ float lw0[64], lw1a[64];
  int bth = blockIdx.x;
  int h = bth & 127; int bt = bth >> 7; int t = bt % 10, b = bt / 10;
  int tid = threadIdx.x;
  for (int i = tid; i < 1024; i += 128) tws[i >> 3][i & 7] = twf[i];
  float tv = times[b*10 + t];
  fr[tid] = frames[((size_t)(b*10 + t)*128 + h)*128 + tid];
  if (tid < 64) { lw0[tid] = lift_w[2*tid]; lw1a[tid] = lift_w[2*tid+1]*tv + lift_b[tid]; }
  __syncthreads();
  {
    int w = tid;
    float f = fr[w];
    unsigned pk[32];
    #pragma unroll
    for (int q = 0; q < 32; ++q) {
      float v0 = f*lw0[2*q] + lw1a[2*q];
      float v1 = f*lw0[2*q+1] + lw1a[2*q+1];
      u16 h0 = f16b(v0), h1 = f16b(v1);
      xs[2*q][w] = h0; xs[2*q+1][w] = h1;
      pk[q] = (unsigned)h0 | ((unsigned)h1 << 16);
    }
    uint4* d4 = (uint4*)(xT + (size_t)bth*8192 + w*64);
    #pragma unroll
    for (int q = 0; q < 8; ++q)
      d4[q] = make_uint4(pk[4*q], pk[4*q+1], pk[4*q+2], pk[4*q+3]);
  }
  __syncthreads();
  {
    int lane = tid & 63, wv = tid >> 6;
    float ar[4] = {0,0,0,0}, ai[4] = {0,0,0,0};
    for (int w2 = 0; w2 < 128; ++w2) {
      float xu = f16f(xs[lane][w2]);
      #pragma unroll
      for (int kk = 0; kk < 4; ++kk) {
        float2 ew = tws[w2][wv*4 + kk];
        ar[kk] += xu*ew.x; ai[kk] += xu*ew.y;
      }
    }
    size_t row = ((size_t)(b*64 + lane)*10 + t)*128 + h;
    float4* dst = (float4*)(xw + row*16 + wv*8);
    dst[0] = make_float4(ar[0], ai[0], ar[1], ai[1]);
    dst[1] = make_float4(ar[2], ai[2], ar[3], ai[3]);
  }
}

// ---------------- fused forward H+T stages ----------------
__global__ __launch_bounds__(256) void k_fwdHT(const float2* __restrict__ xw,
                                               float2* __restrict__ xf) {
  __shared__ float2 tile[2][1024];   // 16 KB
  __shared__ float2 tw128[128];
  int bc = blockIdx.x;
  int b = bc >> 6, c = bc & 63;
  int tid = threadIdx.x;
  if (tid < 128) {
    float s, co; sincosf(TWO_PI * (float)tid / 128.0f, &s, &co);
    tw128[tid] = make_float2(co, -s);
  }
  int tpar = tid >> 7, j = tid & 127;
  int khi = j >> 3, kwi = j & 7;
  int kh = (khi < 8) ? khi : (112 + khi);
  float accr[8], acci[8];
  #pragma unroll
  for (int k = 0; k < 8; ++k) { accr[k] = 0.f; acci[k] = 0.f; }
  for (int tt = 0; tt < 5; ++tt) {
    __syncthreads();
    for (int u = tid; u < 2048; u += 256) {
      int tg = u >> 10, idx = u & 1023;
      tile[tg][idx] = xw[((size_t)bc*10 + tg*5 + tt)*1024 + idx];
    }
    __syncthreads();
    float xr = 0.f, xi = 0.f;
    for (int h = 0; h < 128; ++h) {
      float2 v = tile[tpar][h*8 + kwi];
      float2 tw = tw128[(h*kh) & 127];
      xr += v.x*tw.x - v.y*tw.y;
      xi += v.x*tw.y + v.y*tw.x;
    }
    int t = tpar*5 + tt;
    float sb, cb; sincosf(TWO_PI * (float)t / 10.0f, &sb, &cb);
    float p_r[10], p_i[10];
    p_r[0] = 1.f; p_i[0] = 0.f; p_r[1] = cb; p_i[1] = -sb;
    #pragma unroll
    for (int k = 2; k < 10; ++k) {
      p_r[k] = p_r[k-1]*p_r[1] - p_i[k-1]*p_i[1];
      p_i[k] = p_r[k-1]*p_i[1] + p_i[k-1]*p_r[1];
    }
    #pragma unroll
    for (int kti = 0; kti < 8; ++kti) {
      int kt = (kti < 4) ? kti : kti + 2;
      accr[kti] += xr*p_r[kt] - xi*p_i[kt];
      acci[kti] += xr*p_i[kt] + xi*p_r[kt];
    }
  }
  __syncthreads();
  float2* parts = &tile[0][0];
  #pragma unroll
  for (int kti = 0; kti < 8; ++kti)
    parts[tpar*1024 + j*8 + kti] = make_float2(accr[kti], acci[kti]);
  __syncthreads();
  if (tpar == 0) {
    #pragma unroll
    for (int kti = 0; kti < 8; ++kti) {
      float2 a = parts[j*8 + kti], bq = parts[1024 + j*8 + kti];
      xf[((size_t)b*1024 + kti*128 + j)*64 + c] =
          make_float2((a.x + bq.x)*ORTHO_SC, (a.y + bq.y)*ORTHO_SC);
    }
  }
}

// ---------------- prep: transpose ALL layers' spec_w ----------------
__global__ __launch_bounds__(256) void k_prep_w4(const float* __restrict__ spec_w,
                                                 float2* __restrict__ wT4) {
  __shared__ float2 tile[64][65];
  int blk = blockIdx.x;
  int l = blk >> 10;
  int inner = blk & 1023;
  int mc = inner & 3, ci = (inner >> 2) & 63, q = inner >> 8;
  const float2* in = (const float2*)spec_w + (size_t)l*4194304
                     + (((size_t)q*64 + ci)*64)*256 + mc*64;
  for (int i = threadIdx.x; i < 4096; i += 256) {
    int co = i >> 6, mm = i & 63;
    tile[co][mm] = in[(size_t)co*256 + mm];
  }
  __syncthreads();
  float2* out = wT4 + (size_t)l*4194304 + ((size_t)q*256 + mc*64)*4096 + (size_t)ci*64;
  for (int i = threadIdx.x; i < 4096; i += 256) {
    int mm = i >> 6, co = i & 63;
    out[(size_t)mm*4096 + co] = tile[co][mm];
  }
}

// ---------------- channel mix ----------------
__global__ __launch_bounds__(256) void k_mix(const float2* __restrict__ xf,
                                             const float2* __restrict__ wTl,
                                             float2* __restrict__ yf) {
  __shared__ float2 xfs[8][4][64];
  int m0 = blockIdx.x * 4;
  for (int i = threadIdx.x; i < 2048; i += 256) {
    int bb = i >> 8, mi = (i >> 6) & 3, ci = i & 63;
    xfs[bb][mi][ci] = xf[((size_t)bb*1024 + m0 + mi)*64 + ci];
  }
  __syncthreads();
  int co = threadIdx.x & 63, mi = threadIdx.x >> 6;
  int m = m0 + mi;
  int kti = m >> 7, khi = (m >> 3) & 15, kwi = m & 7;
  int q = ((kti >= 4) ? 2 : 0) + ((khi >= 8) ? 1 : 0);
  int modeidx = ((kti & 3)*8 + (khi & 7))*8 + kwi;
  const float2* wp = wTl + ((size_t)q*256 + modeidx)*4096 + co;
  float accr[8], acci[8];
  #pragma unroll
  for (int bb = 0; bb < 8; ++bb) { accr[bb] = 0.f; acci[bb] = 0.f; }
  for (int ci = 0; ci < 64; ++ci) {
    float2 wv = wp[(size_t)ci*64];
    #pragma unroll
    for (int bb = 0; bb < 8; ++bb) {
      float2 xv = xfs[bb][mi][ci];
      accr[bb] += xv.x*wv.x - xv.y*wv.y;
      acci[bb] += xv.x*wv.y + xv.y*wv.x;
    }
  }
  #pragma unroll
  for (int bb = 0; bb < 8; ++bb)
    yf[((size_t)bb*64 + co)*1024 + m] = make_float2(accr[bb], acci[bb]);
}

// ---------------- fused inverse T+H stages (fp16-packed output) ----------------
__global__ __launch_bounds__(256) void k_invTH(const float2* __restrict__ yf,
                                               unsigned* __restrict__ zh16) {
  __shared__ float2 ybuf[1024];
  __shared__ float2 ztb[2][128];
  __shared__ float2 tw128[128];
  int bc = blockIdx.x;
  int b = bc >> 6, c = bc & 63;
  int tid = threadIdx.x;
  for (int u = tid; u < 1024; u += 256) ybuf[u] = yf[(size_t)bc*1024 + u];
  if (tid < 128) {
    float s, co; sincosf(TWO_PI * (float)tid / 128.0f, &s, &co);
    tw128[tid] = make_float2(co, s);
  }
  int tpar = tid >> 7, j = tid & 127;
  __syncthreads();
  for (int tt = 0; tt < 5; ++tt) {
    int t = tt*2 + tpar;
    {
      float sb, cb; sincosf(TWO_PI * (float)t / 10.0f, &sb, &cb);
      float p_r[10], p_i[10];
      p_r[0] = 1.f; p_i[0] = 0.f; p_r[1] = cb; p_i[1] = sb;
      #pragma unroll
      for (int k = 2; k < 10; ++k) {
        p_r[k] = p_r[k-1]*p_r[1] - p_i[k-1]*p_i[1];
        p_i[k] = p_r[k-1]*p_i[1] + p_i[k-1]*p_r[1];
      }
      float zr = 0.f, zi = 0.f;
      #pragma unroll
      for (int kti = 0; kti < 8; ++kti) {
        int kt = (kti < 4) ? kti : kti + 2;
        float2 v = ybuf[kti*128 + j];
        zr += v.x*p_r[kt] - v.y*p_i[kt];
        zi += v.x*p_i[kt] + v.y*p_r[kt];
      }
      ztb[tpar][j] = make_float2(zr*ORTHO_SC, zi*ORTHO_SC);
    }
    __syncthreads();
    {
      int h = j;
      float ar[8], ai[8];
      #pragma unroll
      for (int kw = 0; kw < 8; ++kw) { ar[kw] = 0.f; ai[kw] = 0.f; }
      #pragma unroll
      for (int khi = 0; khi < 16; ++khi) {
        int kh = (khi < 8) ? khi : (112 + khi);
        float2 tw = tw128[(h*kh) & 127];
        #pragma unroll
        for (int kw = 0; kw < 8; ++kw) {
          float2 v = ztb[tpar][khi*8 + kw];
          ar[kw] += v.x*tw.x - v.y*tw.y;
          ai[kw] += v.x*tw.y + v.y*tw.x;
        }
      }
      unsigned* dst = zh16 + (((size_t)(b*10 + t)*128 + h)*64 + c)*8;
      #pragma unroll
      for (int kw = 0; kw < 8; ++kw)
        dst[kw] = (unsigned)f16b(ar[kw]) | ((unsigned)f16b(ai[kw]) << 16);
    }
    __syncthreads();
  }
}

// ---------------- fused inverse-W + skip + GELU (+ next-layer fwdW DFT) ----------------
// block per (b,t,h); 256 thr = 4 waves; wave wq owns w-quarter, all 64 co.
__global__ __launch_bounds__(256) void k_invW_mfma(const u16* __restrict__ xTin,
                                                   const unsigned* __restrict__ zh16,
                                                   const u16* __restrict__ swf_l,
                                                   const u16* __restrict__ Tt,
                                                   const u16* __restrict__ Ef,
                                                   const float* __restrict__ skb,
                                                   u16* __restrict__ xTo,
                                                   float* __restrict__ xw,
                                                   int do_dft) {
  __shared__ __align__(16) char smem[36864];
  u16* B = (u16*)smem;              // [128][136]
  u16* zAh = (u16*)(smem + 34816);  // [64][16]
  int tid = threadIdx.x;
  int bth = blockIdx.x;
  {
    const uint4* xsrc = (const uint4*)(xTin + (size_t)bth*8192);
    for (int u = tid; u < 1024; u += 256) {
      int w = u >> 3, c = u & 7;
      ((uint4*)(B + w*136))[c] = xsrc[u];
    }
  }
  if (tid < 256) {
    int w = tid >> 1, half = tid & 1;
    const uint4* sh = (const uint4*)(Tt + w*32 + half*16);
    const uint4* sl = (const uint4*)(Tt + 4096 + w*32 + half*16);
    uint4* dh = (uint4*)(B + w*136 + 64 + half*16);
    uint4* dl = (uint4*)(B + w*136 + 96 + half*16);
    dh[0] = sh[0]; dh[1] = sh[1];
    dl[0] = sl[0]; dl[1] = sl[1];
  }
  {
    const unsigned* zsrc = zh16 + (size_t)bth*512;
    for (int u = tid; u < 512; u += 256) {
      int co = u >> 3, m = u & 7;
      *(unsigned*)(zAh + co*16 + 2*m) = zsrc[u];
    }
  }
  __syncthreads();

  int lane = tid & 63;
  int wq = tid >> 6;
  int cL = lane & 15;
  int g = lane >> 4;

  f32x4 acc[4][2];
  #pragma unroll
  for (int s = 0; s < 4; ++s)
    #pragma unroll
    for (int t2 = 0; t2 < 2; ++t2) acc[s][t2] = (f32x4){0.f,0.f,0.f,0.f};

  #pragma unroll
  for (int kb = 0; kb < 2; ++kb) {
    f16x8 Ah[4], Al[4];
    #pragma unroll
    for (int s = 0; s < 4; ++s) {
      Ah[s] = *(const f16x8*)(swf_l + (size_t)(s*2048 + kb*1024 + lane*8));
      Al[s] = *(const f16x8*)(swf_l + (size_t)(s*2048 + kb*1024 + 512 + lane*8));
    }
    #pragma unroll
    for (int t2 = 0; t2 < 2; ++t2) {
      int wrow = wq*32 + t2*16 + cL;
      f16x8 bh = *(const f16x8*)(B + wrow*136 + kb*32 + g*8);
      #pragma unroll
      for (int s = 0; s < 4; ++s) {
        MFMAH(acc[s][t2], Ah[s], bh);
        MFMAH(acc[s][t2], Al[s], bh);
      }
    }
  }
  {
    f16x8 Azh[4];
    f16x8 zero8 = {0,0,0,0,0,0,0,0};
    #pragma unroll
    for (int s = 0; s < 4; ++s)
      Azh[s] = (g < 2) ? *(const f16x8*)(zAh + (s*16 + cL)*16 + g*8) : zero8;
    #pragma unroll
    for (int t2 = 0; t2 < 2; ++t2) {
      int wrow = wq*32 + t2*16 + cL;
      f16x8 th = *(const f16x8*)(B + wrow*136 + 64 + g*8);
      f16x8 tl = *(const f16x8*)(B + wrow*136 + 96 + g*8);
      #pragma unroll
      for (int s = 0; s < 4; ++s) {
        MFMAH(acc[s][t2], Azh[s], th);
        MFMAH(acc[s][t2], Azh[s], tl);
      }
    }
  }

  __syncthreads();
  unsigned* out32 = (unsigned*)smem;           // [32][129] u32 (16512 B)
  u16* xg_a = (u16*)(smem + 16512);            // [64][136] u16 (17408 B)
  #pragma unroll
  for (int s = 0; s < 4; ++s) {
    float4 b4 = *(const float4*)(skb + s*16 + g*4);
    float bb[4] = {b4.x, b4.y, b4.z, b4.w};
    #pragma unroll
    for (int t2 = 0; t2 < 2; ++t2) {
      int w = wq*32 + t2*16 + cL;
      float ge[4];
      u16 gb[4];
      #pragma unroll
      for (int r = 0; r < 4; ++r) {
        float val = acc[s][t2][r] + bb[r];
        ge[r] = 0.5f*val*(1.0f + erff(val*0.70710678118654752f));
        gb[r] = f16b(ge[r]);
      }
      out32[(s*8 + g*2 + 0)*129 + w] = (unsigned)gb[0] | ((unsigned)gb[1] << 16);
      out32[(s*8 + g*2 + 1)*129 + w] = (unsigned)gb[2] | ((unsigned)gb[3] << 16);
      if (do_dft) {
        #pragma unroll
        for (int r = 0; r < 4; ++r)
          xg_a[(s*16 + g*4 + r)*136 + w] = gb[r];
      }
    }
  }
  __syncthreads();
  {
    uint4* xdst = (uint4*)(xTo + (size_t)bth*8192);
    for (int u = tid; u < 1024; u += 256) {
      int w = u >> 3, c = u & 7;
      unsigned r0 = out32[(c*4 + 0)*129 + w];
      unsigned r1 = out32[(c*4 + 1)*129 + w];
      unsigned r2 = out32[(c*4 + 2)*129 + w];
      unsigned r3 = out32[(c*4 + 3)*129 + w];
      xdst[u] = make_uint4(r0, r1, r2, r3);
    }
  }
  if (do_dft) {
    f32x4 acc2 = (f32x4){0.f,0.f,0.f,0.f};
    #pragma unroll
    for (int kc = 0; kc < 4; ++kc) {
      f16x8 a = *(const f16x8*)(xg_a + (wq*16 + cL)*136 + kc*32 + g*8);
      f16x8 eh = *(const f16x8*)(Ef + (kc*64 + lane)*8);
      f16x8 el = *(const f16x8*)(Ef + 2048 + (kc*64 + lane)*8);
      MFMAH(acc2, a, eh);
      MFMAH(acc2, a, el);
    }
    int h = bth & 127; int bt = bth >> 7; int t = bt % 10, b = bt / 10;
    #pragma unroll
    for (int r = 0; r < 4; ++r) {
      int co = wq*16 + g*4 + r;
      size_t row = ((size_t)(b*64 + co)*10 + t)*128 + h;
      xw[row*16 + cL] = acc2[r];
    }
  }
}

// ---------------- aggregation (K=640) as fp16 MFMA (exact B) ----------------
__global__ __launch_bounds__(256) void k_agg_mfma(const u16* __restrict__ xT,
                                                  const u16* __restrict__ awf,
                                                  const float* __restrict__ agg_b,
                                                  float* __restrict__ xa) {
  __shared__ __align__(16) char smem[36864];
  u16* B = (u16*)smem;              // [128][72]
  int tid = threadIdx.x;
  int bid = blockIdx.x;
  int h = bid & 127, b = bid >> 7;
  int lane = tid & 63;
  int wq = tid >> 6;
  int cL = lane & 15;
  int g = lane >> 4;

  f32x4 acc[4][2];
  #pragma unroll
  for (int s = 0; s < 4; ++s)
    #pragma unroll
    for (int t2 = 0; t2 < 2; ++t2) acc[s][t2] = (f32x4){0.f,0.f,0.f,0.f};

  for (int t = 0; t < 10; ++t) {
    __syncthreads();
    {
      const uint4* xsrc = (const uint4*)(xT + ((size_t)(b*10 + t)*128 + h)*8192);
      for (int u = tid; u < 1024; u += 256) {
        int w = u >> 3, c = u & 7;
        ((uint4*)(B + w*72))[c] = xsrc[u];
      }
    }
    __syncthreads();
    #pragma unroll
    for (int kc = 0; kc < 2; ++kc) {
      f16x8 Ah[4], Al[4];
      #pragma unroll
      for (int s = 0; s < 4; ++s) {
        const u16* af = awf + (size_t)((s*10 + t)*4 + kc*2)*512;
        Ah[s] = *(const f16x8*)(af + lane*8);
        Al[s] = *(const f16x8*)(af + 512 + lane*8);
      }
      #pragma unroll
      for (int t2 = 0; t2 < 2; ++t2) {
        int wrow = wq*32 + t2*16 + cL;
        f16x8 bh = *(const f16x8*)(B + wrow*72 + kc*32 + g*8);
        #pragma unroll
        for (int s = 0; s < 4; ++s) {
          MFMAH(acc[s][t2], Ah[s], bh);
          MFMAH(acc[s][t2], Al[s], bh);
        }
      }
    }
  }

  __syncthreads();
  float* outT = (float*)smem;  // [64][132]
  #pragma unroll
  for (int s = 0; s < 4; ++s) {
    float4 b4 = *(const float4*)(agg_b + s*16 + g*4);
    float bb[4] = {b4.x, b4.y, b4.z, b4.w};
    #pragma unroll
    for (int t2 = 0; t2 < 2; ++t2) {
      int w = wq*32 + t2*16 + cL;
      #pragma unroll
      for (int r = 0; r < 4; ++r) {
        int co = s*16 + g*4 + r;
        outT[co*132 + w] = acc[s][t2][r] + bb[r];
      }
    }
  }
  __syncthreads();
  for (int u = tid; u < 256; u += 256) {
    int co = u >> 2, c32 = u & 3;
    float* dst = xa + ((size_t)(b*64 + co)*128 + h)*128 + c32*32;
    #pragma unroll
    for (int q = 0; q < 8; ++q) {
      float4 vv = make_float4(outT[co*132 + c32*32 + 4*q],
                              outT[co*132 + c32*32 + 4*q + 1],
                              outT[co*132 + c32*32 + 4*q + 2],
                              outT[co*132 + c32*32 + 4*q + 3]);
      ((float4*)dst)[q] = vv;
    }
  }
}

// ---------------- MLP head (weights staged in LDS) ----------------
__global__ __launch_bounds__(128) void k_head(const float* __restrict__ xa,
                                              const float* __restrict__ fc1_w,
                                              const float* __restrict__ fc1_b,
                                              const float* __restrict__ fc2_w,
                                              const float* __restrict__ fc2_b,
                                              float* __restrict__ out) {
  __shared__ float w1[66*128];
  __shared__ float w2[128*10];
  __shared__ float b1s[128];
  __shared__ float b2s[16];
  int bid = blockIdx.x;
  int h = bid & 127, b = bid >> 7;
  int tid = threadIdx.x;
  for (int i = tid; i < 66*128; i += 128) w1[i] = fc1_w[i];
  for (int i = tid; i < 1280; i += 128) w2[i] = fc2_w[i];
  b1s[tid] = fc1_b[tid];
  if (tid < 10) b2s[tid] = fc2_b[tid];
  float v[64];
  #pragma unroll
  for (int c = 0; c < 64; ++c)
    v[c] = xa[((size_t)(b*64 + c)*128 + h)*128 + tid];
  __syncthreads();
  float gx = -1.f + 2.f*(float)tid/127.f;
  float gy = -1.f + 2.f*(float)h/127.f;
  float o2[10];
  #pragma unroll
  for (int j = 0; j < 10; ++j) o2[j] = b2s[j];
  for (int o = 0; o < 128; ++o) {
    float a = b1s[o];
    #pragma unroll
    for (int i = 0; i < 64; ++i) a += v[i]*w1[i*128 + o];
    a += gx*w1[64*128 + o] + gy*w1[65*128 + o];
    float g = 0.5f*a*(1.0f + erff(a*0.70710678118654752f));
    #pragma unroll
    for (int j = 0; j < 10; ++j) o2[j] += g*w2[o*10 + j];
  }
  float* dst = out + ((size_t)bid*128 + tid)*10;
  #pragma unroll
  for (int k = 0; k < 5; ++k) dst[k] = o2[2*k];
  #pragma unroll
  for (int k = 0; k < 5; ++k) {
    float sv = o2[2*k+1];
    float sp = fmaxf(sv, 0.f) + log1pf(expf(-fabsf(sv)));
    dst[5 + k] = sp + 1e-4f;
  }
}

extern "C" void kernel_launch(void* const* d_in, const int* in_sizes, int n_in,
                              void* d_out, int out_size, void* d_ws, size_t ws_size,
                              hipStream_t stream) {
  const float* frames = (const float*)d_in[0];
  const float* times  = (const float*)d_in[1];
  const float* lift_w = (const float*)d_in[2];
  const float* lift_b = (const float*)d_in[3];
  const float* spec_w = (const float*)d_in[4];
  const float* skip_w = (const float*)d_in[5];
  const float* skip_b = (const float*)d_in[6];
  const float* agg_w  = (const float*)d_in[7];
  const float* agg_b  = (const float*)d_in[8];
  const float* fc1_w  = (const float*)d_in[9];
  const float* fc1_b  = (const float*)d_in[10];
  const float* fc2_w  = (const float*)d_in[11];
  const float* fc2_b  = (const float*)d_in[12];
  float* out = (float*)d_out;
  char* ws = (char*)d_ws;

  size_t off = 0;
  u16*      xT  = (u16*)(ws + off);      off += (size_t)10240*8192*2;       // 167,772,160
  float*    xw  = (float*)(ws + off);    off += (size_t)655360*16*4;        // 41,943,040
  float2*   xf  = (float2*)(ws + off);   off += (size_t)8*1024*64*8;        // 4,194,304
  float2*   yf  = (float2*)(ws + off);   off += (size_t)8*1024*64*8;        // 4,194,304
  unsigned* zh16= (unsigned*)(ws + off); off += (size_t)10240*512*4;        // 20,971,520
  float*    xa  = (float*)(ws + off);    off += (size_t)8*64*128*128*4;     // 33,554,432
  float2*   wT4 = (float2*)(ws + off);   off += (size_t)4*4194304*8;        // 134,217,728
  u16*      swf = (u16*)(ws + off);      off += (size_t)32768*2;            // 65,536
  u16*      awf = (u16*)(ws + off);      off += (size_t)81920*2;            // 163,840
  u16*      Tt  = (u16*)(ws + off);      off += (size_t)8192*2;             // 16,384
  float2*   twf = (float2*)(ws + off);   off += (size_t)1024*8;             // 8,192
  u16*      Ef  = (u16*)(ws + off);      off += (size_t)4096*2;             // 8,192

  k_prep2<<<492, 256, 0, stream>>>(skip_w, agg_w, swf, awf, Tt, twf, Ef);
  k_prep_w4<<<4096, 256, 0, stream>>>(spec_w, wT4);
  k_lift_fwdW<<<10240, 128, 0, stream>>>(frames, times, lift_w, lift_b, twf, xT, xw);

  for (int l = 0; l < 4; ++l) {
    k_fwdHT<<<512, 256, 0, stream>>>((const float2*)xw, xf);
    k_mix<<<256, 256, 0, stream>>>(xf, wT4 + (size_t)l*4194304, yf);
    k_invTH<<<512, 256, 0, stream>>>(yf, zh16);
    k_invW_mfma<<<10240, 256, 0, stream>>>(xT, zh16, swf + (size_t)l*8192, Tt, Ef,
                                           skip_b + l*64, xT, xw, (l < 3) ? 1 : 0);
  }
  k_agg_mfma<<<1024, 256, 0, stream>>>(xT, awf, agg_b, xa);
  k_head<<<1024, 128, 0, stream>>>(xa, fc1_w, fc1_b, fc2_w, fc2_b, out);
}

// Round 9
// 1126.938 us; speedup vs baseline: 3.3720x; 1.0041x over previous
//
#include <hip/hip_runtime.h>
#include <math.h>

// FNO3d forward. B=8,T=10,H=128,W=128, C=64, NL=4, modes kt8 kh16 kw8.
// x stored FP16, layout xT[(b*10+t)*128+h][w][ci].
// Round 9: exact-erf GELU replaced by exp2-based tanh-GELU (VALU cut) in
// invW epilogue and head. Everything else identical to round 8.

#define TWO_PI 6.2831853071795864769f
#define ORTHO_SC 2.4705294220065465e-3f  // 1/sqrt(10*128*128)

typedef unsigned short u16;
typedef _Float16 f16;
typedef __attribute__((ext_vector_type(8))) _Float16 f16x8;
typedef __attribute__((ext_vector_type(4))) float f32x4;

#define MFMAH(acc, a, b) acc = __builtin_amdgcn_mfma_f32_16x16x32_f16(a, b, acc, 0, 0, 0)

__device__ __forceinline__ u16 f16b(float v) {
  f16 h = (f16)v;
  return __builtin_bit_cast(u16, h);
}
__device__ __forceinline__ float f16lo(float v) {  // v - fp16(v)
  f16 h = (f16)v;
  return v - (float)h;
}
__device__ __forceinline__ float f16f(u16 b) {
  return (float)__builtin_bit_cast(f16, b);
}
// tanh-approx GELU via exp2: gelu(x) = x * e/(e+1), e = exp2(2.885390*u),
// u = 0.7978845608*(x + 0.044715 x^3).  ~9 VALU ops, max err ~1e-3.
__device__ __forceinline__ float gelu_fast(float x) {
  float u = 0.7978845608f * (x + 0.044715f * x * x * x);
  float a = fminf(u * 2.885390082f, 30.0f);   // 2*u*log2(e)
  float e = __builtin_exp2f(a);
  return x * e * __builtin_amdgcn_rcpf(e + 1.0f);
}

// ---------------- prep: A-fragments (split fp16) + twiddle tables ----------------
// swf: [layer4][strip4][kb2][hl2][lane64][8]
// awf: [strip4][t10][kc2][hl2][lane64][8]
// Tt : [hl2][w128][kk32] (kk>=16 -> 0)   (inverse-W K-extension rows)
// twf: [w128][k8] float2 (fwdW fp32 table)
// Ef : [hl2][kc4][lane64][8]  (fwdW DFT B-fragments, split fp16)
__global__ __launch_bounds__(256) void k_prep2(const float* __restrict__ skip_w,
                                               const float* __restrict__ agg_w,
                                               u16* __restrict__ swf,
                                               u16* __restrict__ awf,
                                               u16* __restrict__ Tt,
                                               float2* __restrict__ twf,
                                               u16* __restrict__ Ef) {
  int e = blockIdx.x*256 + threadIdx.x;
  if (e < 32768) {
    int j = e & 7, lane = (e >> 3) & 63, half = (e >> 9) & 1, ks = (e >> 10) & 1;
    int strip = (e >> 11) & 3, layer = e >> 13;
    int co = strip*16 + (lane & 15);
    int ci = ks*32 + (lane >> 4)*8 + j;
    float v = skip_w[((size_t)(layer*64) + co)*64 + ci];
    swf[e] = half ? f16b(f16lo(v)) : f16b(v);
  } else if (e < 114688) {
    int ee = e - 32768;
    int j = ee & 7, lane = (ee >> 3) & 63;
    int v9 = ee >> 9;
    int half = v9 & 1; v9 >>= 1;
    int ks = v9 & 1; v9 >>= 1;
    int t = v9 % 10, strip = v9 / 10;
    int co = strip*16 + (lane & 15);
    int ci = ks*32 + (lane >> 4)*8 + j;
    float v = agg_w[((size_t)co*64 + ci)*10 + t];
    awf[ee] = half ? f16b(f16lo(v)) : f16b(v);
  } else if (e < 122880) {
    int ee = e - 114688;
    int half = ee >> 12, r = ee & 4095, w = r >> 5, kk = r & 31;
    int m = kk >> 1;
    float val;
    if (kk >= 16) val = 0.f;
    else if (kk == 0) val = 1.f;
    else if (kk == 1) val = 0.f;
    else {
      float th = TWO_PI * (float)m * (float)w / 128.0f;
      val = (kk & 1) ? (-2.f*sinf(th)) : (2.f*cosf(th));
    }
    Tt[ee] = half ? f16b(f16lo(val)) : f16b(val);
  } else if (e < 123904) {
    int ee = e - 122880;
    int w = ee >> 3, k = ee & 7;
    float th = TWO_PI * (float)k * (float)w / 128.0f;
    twf[ee] = make_float2(cosf(th), -sinf(th));
  } else if (e < 125952) {
    int ee = e - 123904;
    int j = ee & 7, lane = (ee >> 3) & 63, kc = ee >> 9;
    int n = lane & 15, g = lane >> 4;
    int w = kc*32 + g*8 + j;
    int k = n >> 1;
    float th = TWO_PI * (float)k * (float)w / 128.0f;
    float val = (n & 1) ? (-sinf(th)) : cosf(th);
    Ef[ee] = f16b(val);
    Ef[2048 + ee] = f16b(f16lo(val));
  }
}

// ---------------- fused lift + layer-0 forward-W DFT ----------------
__global__ __launch_bounds__(128) void k_lift_fwdW(const float* __restrict__ frames,
                                                   const float* __restrict__ times,
                                                   const float* __restrict__ lift_w,
                                                   const float* __restrict__ lift_b,
                                                   const float2* __restrict__ twf,
                                                   u16* __restrict__ xT,
                                                   float* __restrict__ xw) {
  __shared__ u16 xs[64][130];
  __shared__ float2 tws[128][8];
  __shared__ float fr[128];
  __shared__ float lw0[64], lw1a[64];
  int bth = blockIdx.x;
  int h = bth & 127; int bt = bth >> 7; int t = bt % 10, b = bt / 10;
  int tid = threadIdx.x;
  for (int i = tid; i < 1024; i += 128) tws[i >> 3][i & 7] = twf[i];
  float tv = times[b*10 + t];
  fr[tid] = frames[((size_t)(b*10 + t)*128 + h)*128 + tid];
  if (tid < 64) { lw0[tid] = lift_w[2*tid]; lw1a[tid] = lift_w[2*tid+1]*tv + lift_b[tid]; }
  __syncthreads();
  {
    int w = tid;
    float f = fr[w];
    unsigned pk[32];
    #pragma unroll
    for (int q = 0; q < 32; ++q) {
      float v0 = f*lw0[2*q] + lw1a[2*q];
      float v1 = f*lw0[2*q+1] + lw1a[2*q+1];
      u16 h0 = f16b(v0), h1 = f16b(v1);
      xs[2*q][w] = h0; xs[2*q+1][w] = h1;
      pk[q] = (unsigned)h0 | ((unsigned)h1 << 16);
    }
    uint4* d4 = (uint4*)(xT + (size_t)bth*8192 + w*64);
    #pragma unroll
    for (int q = 0; q < 8; ++q)
      d4[q] = make_uint4(pk[4*q], pk[4*q+1], pk[4*q+2], pk[4*q+3]);
  }
  __syncthreads();
  {
    int lane = tid & 63, wv = tid >> 6;
    float ar[4] = {0,0,0,0}, ai[4] = {0,0,0,0};
    for (int w2 = 0; w2 < 128; ++w2) {
      float xu = f16f(xs[lane][w2]);
      #pragma unroll
      for (int kk = 0; kk < 4; ++kk) {
        float2 ew = tws[w2][wv*4 + kk];
        ar[kk] += xu*ew.x; ai[kk] += xu*ew.y;
      }
    }
    size_t row = ((size_t)(b*64 + lane)*10 + t)*128 + h;
    float4* dst = (float4*)(xw + row*16 + wv*8);
    dst[0] = make_float4(ar[0], ai[0], ar[1], ai[1]);
    dst[1] = make_float4(ar[2], ai[2], ar[3], ai[3]);
  }
}

// ---------------- fused forward H+T stages ----------------
__global__ __launch_bounds__(256) void k_fwdHT(const float2* __restrict__ xw,
                                               float2* __restrict__ xf) {
  __shared__ float2 tile[2][1024];
  __shared__ float2 tw128[128];
  int bc = blockIdx.x;
  int b = bc >> 6, c = bc & 63;
  int tid = threadIdx.x;
  if (tid < 128) {
    float s, co; sincosf(TWO_PI * (float)tid / 128.0f, &s, &co);
    tw128[tid] = make_float2(co, -s);
  }
  int tpar = tid >> 7, j = tid & 127;
  int khi = j >> 3, kwi = j & 7;
  int kh = (khi < 8) ? khi : (112 + khi);
  float accr[8], acci[8];
  #pragma unroll
  for (int k = 0; k < 8; ++k) { accr[k] = 0.f; acci[k] = 0.f; }
  for (int tt = 0; tt < 5; ++tt) {
    __syncthreads();
    for (int u = tid; u < 2048; u += 256) {
      int tg = u >> 10, idx = u & 1023;
      tile[tg][idx] = xw[((size_t)bc*10 + tg*5 + tt)*1024 + idx];
    }
    __syncthreads();
    float xr = 0.f, xi = 0.f;
    for (int h = 0; h < 128; ++h) {
      float2 v = tile[tpar][h*8 + kwi];
      float2 tw = tw128[(h*kh) & 127];
      xr += v.x*tw.x - v.y*tw.y;
      xi += v.x*tw.y + v.y*tw.x;
    }
    int t = tpar*5 + tt;
    float sb, cb; sincosf(TWO_PI * (float)t / 10.0f, &sb, &cb);
    float p_r[10], p_i[10];
    p_r[0] = 1.f; p_i[0] = 0.f; p_r[1] = cb; p_i[1] = -sb;
    #pragma unroll
    for (int k = 2; k < 10; ++k) {
      p_r[k] = p_r[k-1]*p_r[1] - p_i[k-1]*p_i[1];
      p_i[k] = p_r[k-1]*p_i[1] + p_i[k-1]*p_r[1];
    }
    #pragma unroll
    for (int kti = 0; kti < 8; ++kti) {
      int kt = (kti < 4) ? kti : kti + 2;
      accr[kti] += xr*p_r[kt] - xi*p_i[kt];
      acci[kti] += xr*p_i[kt] + xi*p_r[kt];
    }
  }
  __syncthreads();
  float2* parts = &tile[0][0];
  #pragma unroll
  for (int kti = 0; kti < 8; ++kti)
    parts[tpar*1024 + j*8 + kti] = make_float2(accr[kti], acci[kti]);
  __syncthreads();
  if (tpar == 0) {
    #pragma unroll
    for (int kti = 0; kti < 8; ++kti) {
      float2 a = parts[j*8 + kti], bq = parts[1024 + j*8 + kti];
      xf[((size_t)b*1024 + kti*128 + j)*64 + c] =
          make_float2((a.x + bq.x)*ORTHO_SC, (a.y + bq.y)*ORTHO_SC);
    }
  }
}

// ---------------- prep: transpose ALL layers' spec_w ----------------
__global__ __launch_bounds__(256) void k_prep_w4(const float* __restrict__ spec_w,
                                                 float2* __restrict__ wT4) {
  __shared__ float2 tile[64][65];
  int blk = blockIdx.x;
  int l = blk >> 10;
  int inner = blk & 1023;
  int mc = inner & 3, ci = (inner >> 2) & 63, q = inner >> 8;
  const float2* in = (const float2*)spec_w + (size_t)l*4194304
                     + (((size_t)q*64 + ci)*64)*256 + mc*64;
  for (int i = threadIdx.x; i < 4096; i += 256) {
    int co = i >> 6, mm = i & 63;
    tile[co][mm] = in[(size_t)co*256 + mm];
  }
  __syncthreads();
  float2* out = wT4 + (size_t)l*4194304 + ((size_t)q*256 + mc*64)*4096 + (size_t)ci*64;
  for (int i = threadIdx.x; i < 4096; i += 256) {
    int mm = i >> 6, co = i & 63;
    out[(size_t)mm*4096 + co] = tile[co][mm];
  }
}

// ---------------- channel mix ----------------
__global__ __launch_bounds__(256) void k_mix(const float2* __restrict__ xf,
                                             const float2* __restrict__ wTl,
                                             float2* __restrict__ yf) {
  __shared__ float2 xfs[8][4][64];
  int m0 = blockIdx.x * 4;
  for (int i = threadIdx.x; i < 2048; i += 256) {
    int bb = i >> 8, mi = (i >> 6) & 3, ci = i & 63;
    xfs[bb][mi][ci] = xf[((size_t)bb*1024 + m0 + mi)*64 + ci];
  }
  __syncthreads();
  int co = threadIdx.x & 63, mi = threadIdx.x >> 6;
  int m = m0 + mi;
  int kti = m >> 7, khi = (m >> 3) & 15, kwi = m & 7;
  int q = ((kti >= 4) ? 2 : 0) + ((khi >= 8) ? 1 : 0);
  int modeidx = ((kti & 3)*8 + (khi & 7))*8 + kwi;
  const float2* wp = wTl + ((size_t)q*256 + modeidx)*4096 + co;
  float accr[8], acci[8];
  #pragma unroll
  for (int bb = 0; bb < 8; ++bb) { accr[bb] = 0.f; acci[bb] = 0.f; }
  for (int ci = 0; ci < 64; ++ci) {
    float2 wv = wp[(size_t)ci*64];
    #pragma unroll
    for (int bb = 0; bb < 8; ++bb) {
      float2 xv = xfs[bb][mi][ci];
      accr[bb] += xv.x*wv.x - xv.y*wv.y;
      acci[bb] += xv.x*wv.y + xv.y*wv.x;
    }
  }
  #pragma unroll
  for (int bb = 0; bb < 8; ++bb)
    yf[((size_t)bb*64 + co)*1024 + m] = make_float2(accr[bb], acci[bb]);
}

// ---------------- fused inverse T+H stages (fp16-packed output) ----------------
__global__ __launch_bounds__(256) void k_invTH(const float2* __restrict__ yf,
                                               unsigned* __restrict__ zh16) {
  __shared__ float2 ybuf[1024];
  __shared__ float2 ztb[2][128];
  __shared__ float2 tw128[128];
  int bc = blockIdx.x;
  int b = bc >> 6, c = bc & 63;
  int tid = threadIdx.x;
  for (int u = tid; u < 1024; u += 256) ybuf[u] = yf[(size_t)bc*1024 + u];
  if (tid < 128) {
    float s, co; sincosf(TWO_PI * (float)tid / 128.0f, &s, &co);
    tw128[tid] = make_float2(co, s);
  }
  int tpar = tid >> 7, j = tid & 127;
  __syncthreads();
  for (int tt = 0; tt < 5; ++tt) {
    int t = tt*2 + tpar;
    {
      float sb, cb; sincosf(TWO_PI * (float)t / 10.0f, &sb, &cb);
      float p_r[10], p_i[10];
      p_r[0] = 1.f; p_i[0] = 0.f; p_r[1] = cb; p_i[1] = sb;
      #pragma unroll
      for (int k = 2; k < 10; ++k) {
        p_r[k] = p_r[k-1]*p_r[1] - p_i[k-1]*p_i[1];
        p_i[k] = p_r[k-1]*p_i[1] + p_i[k-1]*p_r[1];
      }
      float zr = 0.f, zi = 0.f;
      #pragma unroll
      for (int kti = 0; kti < 8; ++kti) {
        int kt = (kti < 4) ? kti : kti + 2;
        float2 v = ybuf[kti*128 + j];
        zr += v.x*p_r[kt] - v.y*p_i[kt];
        zi += v.x*p_i[kt] + v.y*p_r[kt];
      }
      ztb[tpar][j] = make_float2(zr*ORTHO_SC, zi*ORTHO_SC);
    }
    __syncthreads();
    {
      int h = j;
      float ar[8], ai[8];
      #pragma unroll
      for (int kw = 0; kw < 8; ++kw) { ar[kw] = 0.f; ai[kw] = 0.f; }
      #pragma unroll
      for (int khi = 0; khi < 16; ++khi) {
        int kh = (khi < 8) ? khi : (112 + khi);
        float2 tw = tw128[(h*kh) & 127];
        #pragma unroll
        for (int kw = 0; kw < 8; ++kw) {
          float2 v = ztb[tpar][khi*8 + kw];
          ar[kw] += v.x*tw.x - v.y*tw.y;
          ai[kw] += v.x*tw.y + v.y*tw.x;
        }
      }
      unsigned* dst = zh16 + (((size_t)(b*10 + t)*128 + h)*64 + c)*8;
      #pragma unroll
      for (int kw = 0; kw < 8; ++kw)
        dst[kw] = (unsigned)f16b(ar[kw]) | ((unsigned)f16b(ai[kw]) << 16);
    }
    __syncthreads();
  }
}

// ---------------- fused inverse-W + skip + GELU (+ next-layer fwdW DFT) ----------------
__global__ __launch_bounds__(256) void k_invW_mfma(const u16* __restrict__ xTin,
                                                   const unsigned* __restrict__ zh16,
                                                   const u16* __restrict__ swf_l,
                                                   const u16* __restrict__ Tt,
                                                   const u16* __restrict__ Ef,
                                                   const float* __restrict__ skb,
                                                   u16* __restrict__ xTo,
                                                   float* __restrict__ xw,
                                                   int do_dft) {
  __shared__ __align__(16) char smem[36864];
  u16* B = (u16*)smem;              // [128][136]
  u16* zAh = (u16*)(smem + 34816);  // [64][16]
  int tid = threadIdx.x;
  int bth = blockIdx.x;
  {
    const uint4* xsrc = (const uint4*)(xTin + (size_t)bth*8192);
    for (int u = tid; u < 1024; u += 256) {
      int w = u >> 3, c = u & 7;
      ((uint4*)(B + w*136))[c] = xsrc[u];
    }
  }
  if (tid < 256) {
    int w = tid >> 1, half = tid & 1;
    const uint4* sh = (const uint4*)(Tt + w*32 + half*16);
    const uint4* sl = (const uint4*)(Tt + 4096 + w*32 + half*16);
    uint4* dh = (uint4*)(B + w*136 + 64 + half*16);
    uint4* dl = (uint4*)(B + w*136 + 96 + half*16);
    dh[0] = sh[0]; dh[1] = sh[1];
    dl[0] = sl[0]; dl[1] = sl[1];
  }
  {
    const unsigned* zsrc = zh16 + (size_t)bth*512;
    for (int u = tid; u < 512; u += 256) {
      int co = u >> 3, m = u & 7;
      *(unsigned*)(zAh + co*16 + 2*m) = zsrc[u];
    }
  }
  __syncthreads();

  int lane = tid & 63;
  int wq = tid >> 6;
  int cL = lane & 15;
  int g = lane >> 4;

  f32x4 acc[4][2];
  #pragma unroll
  for (int s = 0; s < 4; ++s)
    #pragma unroll
    for (int t2 = 0; t2 < 2; ++t2) acc[s][t2] = (f32x4){0.f,0.f,0.f,0.f};

  #pragma unroll
  for (int kb = 0; kb < 2; ++kb) {
    f16x8 Ah[4], Al[4];
    #pragma unroll
    for (int s = 0; s < 4; ++s) {
      Ah[s] = *(const f16x8*)(swf_l + (size_t)(s*2048 + kb*1024 + lane*8));
      Al[s] = *(const f16x8*)(swf_l + (size_t)(s*2048 + kb*1024 + 512 + lane*8));
    }
    #pragma unroll
    for (int t2 = 0; t2 < 2; ++t2) {
      int wrow = wq*32 + t2*16 + cL;
      f16x8 bh = *(const f16x8*)(B + wrow*136 + kb*32 + g*8);
      #pragma unroll
      for (int s = 0; s < 4; ++s) {
        MFMAH(acc[s][t2], Ah[s], bh);
        MFMAH(acc[s][t2], Al[s], bh);
      }
    }
  }
  {
    f16x8 Azh[4];
    f16x8 zero8 = {0,0,0,0,0,0,0,0};
    #pragma unroll
    for (int s = 0; s < 4; ++s)
      Azh[s] = (g < 2) ? *(const f16x8*)(zAh + (s*16 + cL)*16 + g*8) : zero8;
    #pragma unroll
    for (int t2 = 0; t2 < 2; ++t2) {
      int wrow = wq*32 + t2*16 + cL;
      f16x8 th = *(const f16x8*)(B + wrow*136 + 64 + g*8);
      f16x8 tl = *(const f16x8*)(B + wrow*136 + 96 + g*8);
      #pragma unroll
      for (int s = 0; s < 4; ++s) {
        MFMAH(acc[s][t2], Azh[s], th);
        MFMAH(acc[s][t2], Azh[s], tl);
      }
    }
  }

  __syncthreads();
  unsigned* out32 = (unsigned*)smem;           // [32][129] u32 (16512 B)
  u16* xg_a = (u16*)(smem + 16512);            // [64][136] u16 (17408 B)
  #pragma unroll
  for (int s = 0; s < 4; ++s) {
    float4 b4 = *(const float4*)(skb + s*16 + g*4);
    float bb[4] = {b4.x, b4.y, b4.z, b4.w};
    #pragma unroll
    for (int t2 = 0; t2 < 2; ++t2) {
      int w = wq*32 + t2*16 + cL;
      float ge[4];
      u16 gb[4];
      #pragma unroll
      for (int r = 0; r < 4; ++r) {
        float val = acc[s][t2][r] + bb[r];
        ge[r] = gelu_fast(val);
        gb[r] = f16b(ge[r]);
      }
      out32[(s*8 + g*2 + 0)*129 + w] = (unsigned)gb[0] | ((unsigned)gb[1] << 16);
      out32[(s*8 + g*2 + 1)*129 + w] = (unsigned)gb[2] | ((unsigned)gb[3] << 16);
      if (do_dft) {
        #pragma unroll
        for (int r = 0; r < 4; ++r)
          xg_a[(s*16 + g*4 + r)*136 + w] = gb[r];
      }
    }
  }
  __syncthreads();
  {
    uint4* xdst = (uint4*)(xTo + (size_t)bth*8192);
    for (int u = tid; u < 1024; u += 256) {
      int w = u >> 3, c = u & 7;
      unsigned r0 = out32[(c*4 + 0)*129 + w];
      unsigned r1 = out32[(c*4 + 1)*129 + w];
      unsigned r2 = out32[(c*4 + 2)*129 + w];
      unsigned r3 = out32[(c*4 + 3)*129 + w];
      xdst[u] = make_uint4(r0, r1, r2, r3);
    }
  }
  if (do_dft) {
    f32x4 acc2 = (f32x4){0.f,0.f,0.f,0.f};
    #pragma unroll
    for (int kc = 0; kc < 4; ++kc) {
      f16x8 a = *(const f16x8*)(xg_a + (wq*16 + cL)*136 + kc*32 + g*8);
      f16x8 eh = *(const f16x8*)(Ef + (kc*64 + lane)*8);
      f16x8 el = *(const f16x8*)(Ef + 2048 + (kc*64 + lane)*8);
      MFMAH(acc2, a, eh);
      MFMAH(acc2, a, el);
    }
    int h = bth & 127; int bt = bth >> 7; int t = bt % 10, b = bt / 10;
    #pragma unroll
    for (int r = 0; r < 4; ++r) {
      int co = wq*16 + g*4 + r;
      size_t row = ((size_t)(b*64 + co)*10 + t)*128 + h;
      xw[row*16 + cL] = acc2[r];
    }
  }
}

// ---------------- aggregation (K=640) as fp16 MFMA (exact B) ----------------
__global__ __launch_bounds__(256) void k_agg_mfma(const u16* __restrict__ xT,
                                                  const u16* __restrict__ awf,
                                                  const float* __restrict__ agg_b,
                                                  float* __restrict__ xa) {
  __shared__ __align__(16) char smem[36864];
  u16* B = (u16*)smem;              // [128][72]
  int tid = threadIdx.x;
  int bid = blockIdx.x;
  int h = bid & 127, b = bid >> 7;
  int lane = tid & 63;
  int wq = tid >> 6;
  int cL = lane & 15;
  int g = lane >> 4;

  f32x4 acc[4][2];
  #pragma unroll
  for (int s = 0; s < 4; ++s)
    #pragma unroll
    for (int t2 = 0; t2 < 2; ++t2) acc[s][t2] = (f32x4){0.f,0.f,0.f,0.f};

  for (int t = 0; t < 10; ++t) {
    __syncthreads();
    {
      const uint4* xsrc = (const uint4*)(xT + ((size_t)(b*10 + t)*128 + h)*8192);
      for (int u = tid; u < 1024; u += 256) {
        int w = u >> 3, c = u & 7;
        ((uint4*)(B + w*72))[c] = xsrc[u];
      }
    }
    __syncthreads();
    #pragma unroll
    for (int kc = 0; kc < 2; ++kc) {
      f16x8 Ah[4], Al[4];
      #pragma unroll
      for (int s = 0; s < 4; ++s) {
        const u16* af = awf + (size_t)((s*10 + t)*4 + kc*2)*512;
        Ah[s] = *(const f16x8*)(af + lane*8);
        Al[s] = *(const f16x8*)(af + 512 + lane*8);
      }
      #pragma unroll
      for (int t2 = 0; t2 < 2; ++t2) {
        int wrow = wq*32 + t2*16 + cL;
        f16x8 bh = *(const f16x8*)(B + wrow*72 + kc*32 + g*8);
        #pragma unroll
        for (int s = 0; s < 4; ++s) {
          MFMAH(acc[s][t2], Ah[s], bh);
          MFMAH(acc[s][t2], Al[s], bh);
        }
      }
    }
  }

  __syncthreads();
  float* outT = (float*)smem;  // [64][132]
  #pragma unroll
  for (int s = 0; s < 4; ++s) {
    float4 b4 = *(const float4*)(agg_b + s*16 + g*4);
    float bb[4] = {b4.x, b4.y, b4.z, b4.w};
    #pragma unroll
    for (int t2 = 0; t2 < 2; ++t2) {
      int w = wq*32 + t2*16 + cL;
      #pragma unroll
      for (int r = 0; r < 4; ++r) {
        int co = s*16 + g*4 + r;
        outT[co*132 + w] = acc[s][t2][r] + bb[r];
      }
    }
  }
  __syncthreads();
  for (int u = tid; u < 256; u += 256) {
    int co = u >> 2, c32 = u & 3;
    float* dst = xa + ((size_t)(b*64 + co)*128 + h)*128 + c32*32;
    #pragma unroll
    for (int q = 0; q < 8; ++q) {
      float4 vv = make_float4(outT[co*132 + c32*32 + 4*q],
                              outT[co*132 + c32*32 + 4*q + 1],
                              outT[co*132 + c32*32 + 4*q + 2],
                              outT[co*132 + c32*32 + 4*q + 3]);
      ((float4*)dst)[q] = vv;
    }
  }
}

// ---------------- MLP head (weights staged in LDS) ----------------
__global__ __launch_bounds__(128) void k_head(const float* __restrict__ xa,
                                              const float* __restrict__ fc1_w,
                                              const float* __restrict__ fc1_b,
                                              const float* __restrict__ fc2_w,
                                              const float* __restrict__ fc2_b,
                                              float* __restrict__ out) {
  __shared__ float w1[66*128];
  __shared__ float w2[128*10];
  __shared__ float b1s[128];
  __shared__ float b2s[16];
  int bid = blockIdx.x;
  int h = bid & 127, b = bid >> 7;
  int tid = threadIdx.x;
  for (int i = tid; i < 66*128; i += 128) w1[i] = fc1_w[i];
  for (int i = tid; i < 1280; i += 128) w2[i] = fc2_w[i];
  b1s[tid] = fc1_b[tid];
  if (tid < 10) b2s[tid] = fc2_b[tid];
  float v[64];
  #pragma unroll
  for (int c = 0; c < 64; ++c)
    v[c] = xa[((size_t)(b*64 + c)*128 + h)*128 + tid];
  __syncthreads();
  float gx = -1.f + 2.f*(float)tid/127.f;
  float gy = -1.f + 2.f*(float)h/127.f;
  float o2[10];
  #pragma unroll
  for (int j = 0; j < 10; ++j) o2[j] = b2s[j];
  for (int o = 0; o < 128; ++o) {
    float a = b1s[o];
    #pragma unroll
    for (int i = 0; i < 64; ++i) a += v[i]*w1[i*128 + o];
    a += gx*w1[64*128 + o] + gy*w1[65*128 + o];
    float g = gelu_fast(a);
    #pragma unroll
    for (int j = 0; j < 10; ++j) o2[j] += g*w2[o*10 + j];
  }
  float* dst = out + ((size_t)bid*128 + tid)*10;
  #pragma unroll
  for (int k = 0; k < 5; ++k) dst[k] = o2[2*k];
  #pragma unroll
  for (int k = 0; k < 5; ++k) {
    float sv = o2[2*k+1];
    float sp = fmaxf(sv, 0.f) + log1pf(expf(-fabsf(sv)));
    dst[5 + k] = sp + 1e-4f;
  }
}

extern "C" void kernel_launch(void* const* d_in, const int* in_sizes, int n_in,
                              void* d_out, int out_size, void* d_ws, size_t ws_size,
                              hipStream_t stream) {
  const float* frames = (const float*)d_in[0];
  const float* times  = (const float*)d_in[1];
  const float* lift_w = (const float*)d_in[2];
  const float* lift_b = (const float*)d_in[3];
  const float* spec_w = (const float*)d_in[4];
  const float* skip_w = (const float*)d_in[5];
  const float* skip_b = (const float*)d_in[6];
  const float* agg_w  = (const float*)d_in[7];
  const float* agg_b  = (const float*)d_in[8];
  const float* fc1_w  = (const float*)d_in[9];
  const float* fc1_b  = (const float*)d_in[10];
  const float* fc2_w  = (const float*)d_in[11];
  const float* fc2_b  = (const float*)d_in[12];
  float* out = (float*)d_out;
  char* ws = (char*)d_ws;

  size_t off = 0;
  u16*      xT  = (u16*)(ws + off);      off += (size_t)10240*8192*2;       // 167,772,160
  float*    xw  = (float*)(ws + off);    off += (size_t)655360*16*4;        // 41,943,040
  float2*   xf  = (float2*)(ws + off);   off += (size_t)8*1024*64*8;        // 4,194,304
  float2*   yf  = (float2*)(ws + off);   off += (size_t)8*1024*64*8;        // 4,194,304
  unsigned* zh16= (unsigned*)(ws + off); off += (size_t)10240*512*4;        // 20,971,520
  float*    xa  = (float*)(ws + off);    off += (size_t)8*64*128*128*4;     // 33,554,432
  float2*   wT4 = (float2*)(ws + off);   off += (size_t)4*4194304*8;        // 134,217,728
  u16*      swf = (u16*)(ws + off);      off += (size_t)32768*2;            // 65,536
  u16*      awf = (u16*)(ws + off);      off += (size_t)81920*2;            // 163,840
  u16*      Tt  = (u16*)(ws + off);      off += (size_t)8192*2;             // 16,384
  float2*   twf = (float2*)(ws + off);   off += (size_t)1024*8;             // 8,192
  u16*      Ef  = (u16*)(ws + off);      off += (size_t)4096*2;             // 8,192

  k_prep2<<<492, 256, 0, stream>>>(skip_w, agg_w, swf, awf, Tt, twf, Ef);
  k_prep_w4<<<4096, 256, 0, stream>>>(spec_w, wT4);
  k_lift_fwdW<<<10240, 128, 0, stream>>>(frames, times, lift_w, lift_b, twf, xT, xw);

  for (int l = 0; l < 4; ++l) {
    k_fwdHT<<<512, 256, 0, stream>>>((const float2*)xw, xf);
    k_mix<<<256, 256, 0, stream>>>(xf, wT4 + (size_t)l*4194304, yf);
    k_invTH<<<512, 256, 0, stream>>>(yf, zh16);
    k_invW_mfma<<<10240, 256, 0, stream>>>(xT, zh16, swf + (size_t)l*8192, Tt, Ef,
                                           skip_b + l*64, xT, xw, (l < 3) ? 1 : 0);
  }
  k_agg_mfma<<<1024, 256, 0, stream>>>(xT, awf, agg_b, xa);
  k_head<<<1024, 128, 0, stream>>>(xa, fc1_w, fc1_b, fc2_w, fc2_b, out);
}